// Round 4
// baseline (502.738 us; speedup 1.0000x reference)
//
#include <hip/hip_runtime.h>
#include <math.h>

#define BATCH 16
#define NCLS 20
#define TOPK 100
#define NPRE 1000
#define NTOT 2400
#define NBINS 8
#define N0 6400
#define N1 1600
#define NQW 38           // qwords per mask row (2432 bits >= 2400)

// ---- order-preserving float->uint map (ascending) ----
__device__ __forceinline__ unsigned int orderable(float x) {
    unsigned int u = __float_as_uint(x);
    return (u & 0x80000000u) ? ~u : (u | 0x80000000u);
}
__device__ __forceinline__ float unorderable(unsigned int k) {
    return __uint_as_float((k & 0x80000000u) ? (k ^ 0x80000000u) : ~k);
}

// ============================================================
// Kernel 0: per-anchor key = orderable(max_c logit).
// ============================================================
__global__ __launch_bounds__(256) void compute_keys_kernel(
        const float* __restrict__ cls0, const float* __restrict__ cls1,
        unsigned int* __restrict__ keys0, unsigned int* __restrict__ keys1) {
    int tg = blockIdx.x * 256 + threadIdx.x;
    const float* p;
    unsigned int* dst;
    if (tg < BATCH * N0) {
        p = cls0 + (size_t)tg * NCLS;
        dst = keys0 + tg;
    } else {
        int a = tg - BATCH * N0;
        if (a >= BATCH * N1) return;
        p = cls1 + (size_t)a * NCLS;
        dst = keys1 + a;
    }
    const float4* p4 = (const float4*)p;
    float m = -INFINITY;
    #pragma unroll
    for (int q = 0; q < 5; ++q) {
        float4 v = p4[q];
        m = fmaxf(m, fmaxf(fmaxf(v.x, v.y), fmaxf(v.z, v.w)));
    }
    *dst = orderable(m);
}

// ============================================================
// Kernel 1: per (batch, level) exact top-1000 radix select.
// ============================================================
__global__ __launch_bounds__(256) void radix_select_kernel(
        const unsigned int* __restrict__ keys0, const unsigned int* __restrict__ keys1,
        int* __restrict__ sel_idx) {
    int bid = blockIdx.x;            // 0..31
    int b = bid >> 1;
    int lvl = bid & 1;
    int n = (lvl == 0) ? N0 : N1;
    const unsigned int* gk = (lvl == 0 ? keys0 : keys1) + (size_t)b * n;

    __shared__ unsigned int skey[N0];
    __shared__ unsigned int hist[256];
    __shared__ unsigned int sfxA[257], sfxB[257];
    __shared__ int eq[256];
    __shared__ unsigned int s_prefix, s_kk, s_cnt, s_eqcnt;
    int t = threadIdx.x;

    for (int a = t; a < n; a += 256) skey[a] = gk[a];
    if (t == 0) {
        s_kk = NPRE; s_prefix = 0u; s_cnt = 0u; s_eqcnt = 0u;
        sfxA[256] = 0u; sfxB[256] = 0u;
    }
    __syncthreads();

    for (int pass = 0; pass < 4; ++pass) {
        int shift = 24 - 8 * pass;
        hist[t] = 0u;
        __syncthreads();
        unsigned int prefix = s_prefix, kk = s_kk;
        for (int a = t; a < n; a += 256) {
            unsigned int u = skey[a];
            if (pass == 0 || (u >> (shift + 8)) == prefix)
                atomicAdd(&hist[(u >> shift) & 255u], 1u);
        }
        __syncthreads();
        sfxA[t] = hist[t];
        __syncthreads();
        unsigned int* src = sfxA; unsigned int* dst = sfxB;
        #pragma unroll
        for (int step = 1; step < 256; step <<= 1) {
            int idx = t + step; if (idx > 256) idx = 256;
            dst[t] = src[t] + src[idx];
            __syncthreads();
            unsigned int* tmp = src; src = dst; dst = tmp;
        }
        unsigned int Sd = src[t];
        unsigned int Sd1 = src[t + 1];
        if (Sd >= kk && Sd1 < kk) {
            s_prefix = (prefix << 8) | (unsigned int)t;
            s_kk = kk - Sd1;
        }
        __syncthreads();
    }

    unsigned int T = s_prefix;
    int* out = sel_idx + b * 2000 + lvl * 1000;
    for (int a = t; a < n; a += 256) {
        unsigned int u = skey[a];
        if (u > T) {
            unsigned int pos = atomicAdd(&s_cnt, 1u);
            out[pos] = a;
        } else if (u == T) {
            unsigned int p = atomicAdd(&s_eqcnt, 1u);
            if (p < 256u) eq[p] = a;
        }
    }
    __syncthreads();
    if (t == 0) {
        unsigned int pos = s_cnt;
        unsigned int rem = s_kk;
        unsigned int cnt = s_eqcnt;
        if (cnt <= 256u) {
            for (unsigned int i = 1; i < cnt; ++i) {
                int key = eq[i]; int j2 = (int)i - 1;
                while (j2 >= 0 && eq[j2] > key) { eq[j2 + 1] = eq[j2]; --j2; }
                eq[j2 + 1] = key;
            }
            for (unsigned int i = 0; i < rem; ++i) out[pos + i] = eq[i];
        } else {
            for (int a = 0; a < n && rem > 0u; ++a)
                if (skey[a] == T) { out[pos++] = a; --rem; }
        }
    }
}

// ============================================================
// Kernel 2: decode scores (sigmoid, transposed [b][c][j]) + DFL boxes.
// ============================================================
__global__ __launch_bounds__(256) void decode_kernel(
        const float* __restrict__ cls0, const float* __restrict__ cls1, const float* __restrict__ cls2,
        const float* __restrict__ bb0,  const float* __restrict__ bb1,  const float* __restrict__ bb2,
        const int* __restrict__ sel_idx,
        float* __restrict__ boxes_all, float* __restrict__ scores_t) {
    int tg = blockIdx.x * blockDim.x + threadIdx.x;
    if (tg >= BATCH * NTOT) return;
    int b = tg / NTOT, j = tg % NTOT;

    const float* cls; const float* bb; int a, w; float stride;
    if (j < 1000) {
        a = sel_idx[b * 2000 + j]; w = 80; stride = 8.f;
        cls = cls0 + ((size_t)b * N0 + a) * NCLS;
        bb  = bb0  + ((size_t)b * N0 + a) * 32;
    } else if (j < 2000) {
        a = sel_idx[b * 2000 + j]; w = 40; stride = 16.f;
        cls = cls1 + ((size_t)b * N1 + a) * NCLS;
        bb  = bb1  + ((size_t)b * N1 + a) * 32;
    } else {
        a = j - 2000; w = 20; stride = 32.f;
        cls = cls2 + ((size_t)b * 400 + a) * NCLS;
        bb  = bb2  + ((size_t)b * 400 + a) * 32;
    }

    float cl[20];
    {
        const float4* c4 = (const float4*)cls;
        #pragma unroll
        for (int q = 0; q < 5; ++q) *(float4*)&cl[q * 4] = c4[q];
    }
    float bl[32];
    {
        const float4* b4 = (const float4*)bb;
        #pragma unroll
        for (int q = 0; q < 8; ++q) *(float4*)&bl[q * 4] = b4[q];
    }

    #pragma unroll
    for (int c = 0; c < NCLS; ++c)
        scores_t[((size_t)b * NCLS + c) * NTOT + j] = 1.f / (1.f + expf(-cl[c]));

    float d[4];
    #pragma unroll
    for (int s = 0; s < 4; ++s) {
        const float* l = &bl[s * NBINS];
        float m = l[0];
        #pragma unroll
        for (int k = 1; k < NBINS; ++k) m = fmaxf(m, l[k]);
        float e[NBINS], sum = 0.f;
        #pragma unroll
        for (int k = 0; k < NBINS; ++k) { e[k] = expf(l[k] - m); sum += e[k]; }
        float acc = 0.f;
        #pragma unroll
        for (int k = 0; k < NBINS; ++k) acc += (e[k] / sum) * (float)k;
        d[s] = acc * stride;
    }
    float cy = ((float)(a / w) + 0.5f) * stride;
    float cx = ((float)(a % w) + 0.5f) * stride;
    float* bx = boxes_all + ((size_t)b * NTOT + j) * 4;
    bx[0] = fminf(fmaxf(cy - d[0], 0.f), 640.f);   // y1
    bx[1] = fminf(fmaxf(cx - d[1], 0.f), 640.f);   // x1
    bx[2] = fminf(fmaxf(cy + d[2], 0.f), 640.f);   // y2
    bx[3] = fminf(fmaxf(cx + d[3], 0.f), 640.f);   // x2
}

// ============================================================
// Kernel 2b: per-batch all-pairs IoU suppression bitmask.
// Shared across all 20 classes. Row i, qword s, bit t <-> j = 64 s + t.
// grid: 16 batches x 10 row-stripes x 4 qword-ranges.
// ============================================================
__global__ __launch_bounds__(256) void iou_mask_kernel(
        const float* __restrict__ boxes_all, unsigned long long* __restrict__ mask) {
    int bid = blockIdx.x;
    int b = bid / 40;
    int rem = bid % 40;
    int stripe = rem >> 2;
    int r = rem & 3;
    int q0 = (r < 3) ? r * 10 : 29;          // {0,10,20,29}
    int q1 = q0 + ((r >= 2) ? 9 : 10);       // {10,20,29,38}

    __shared__ float4 sbox[NTOT];            // 38400 B
    const float4* bsrc = (const float4*)boxes_all + (size_t)b * NTOT;
    int t = threadIdx.x;
    for (int j = t; j < NTOT; j += 256) sbox[j] = bsrc[j];
    __syncthreads();

    int i = stripe * 256 + t;
    if (i >= NTOT) return;
    float4 bi = sbox[i];
    float a1 = (bi.z - bi.x) * (bi.w - bi.y);
    unsigned long long* row = mask + ((size_t)b * NTOT + i) * NQW;

    for (int qw = q0; qw < q1; ++qw) {
        unsigned long long m = 0ull;
        int jbase = qw * 64;
        for (int tt = 0; tt < 64; ++tt) {
            int j = jbase + tt;
            if (j < NTOT) {
                float4 bj = sbox[j];                       // broadcast (same j all lanes)
                float yy1 = fmaxf(bi.x, bj.x);
                float xx1 = fmaxf(bi.y, bj.y);
                float yy2 = fminf(bi.z, bj.z);
                float xx2 = fminf(bi.w, bj.w);
                float inter = fmaxf(yy2 - yy1, 0.f) * fmaxf(xx2 - xx1, 0.f);
                float a2 = (bj.z - bj.x) * (bj.w - bj.y);
                float iou = inter / (a1 + a2 - inter + 1e-9f);
                if (iou > 0.5f) m |= (1ull << tt);
            }
        }
        row[qw] = m;
    }
}

// ============================================================
// Kernel 3: greedy NMS, ONE WAVE per (batch, class).
// Keys (score|~idx packed u64) in registers; suppression via
// precomputed bitmask (broadcast u64 loads). No LDS, no barriers.
// ============================================================
__global__ __launch_bounds__(64) void nms_wave_kernel(
        const float* __restrict__ scores_t, const unsigned long long* __restrict__ mask,
        float* __restrict__ nms_score, int* __restrict__ nms_idx) {
    int blk = blockIdx.x;
    int b = blk / NCLS, c = blk % NCLS;
    int lane = threadIdx.x;
    const float* ssrc = scores_t + ((size_t)b * NCLS + c) * NTOT;
    const unsigned long long* mbase = mask + (size_t)b * NTOT * NQW;

    unsigned long long key[NQW];
    #pragma unroll
    for (int s = 0; s < NQW; ++s) {
        int j = lane + 64 * s;
        if (j < NTOT) {
            float sc = ssrc[j];                       // coalesced
            key[s] = ((unsigned long long)orderable(sc) << 32)
                   | (unsigned long long)(0xFFFFFFFFu - (unsigned int)j);
        } else {
            key[s] = 0ull;
        }
    }

    float* osc = nms_score + ((size_t)b * NCLS + c) * TOPK;
    int*   oid = nms_idx   + ((size_t)b * NCLS + c) * TOPK;

    // initial wave argmax (u64 packed: max key = max score, tie -> lowest j)
    unsigned long long m = 0ull;
    #pragma unroll
    for (int s = 0; s < NQW; ++s) m = (key[s] > m) ? key[s] : m;
    #pragma unroll
    for (int off = 32; off > 0; off >>= 1) {
        unsigned long long o = __shfl_xor(m, off);
        m = (o > m) ? o : m;
    }

    for (int k = 0; k < TOPK; ++k) {
        if (m == 0ull) {   // all suppressed: rest is (-inf, 0)
            for (int k2 = k + lane; k2 < TOPK; k2 += 64) { osc[k2] = -INFINITY; oid[k2] = 0; }
            break;
        }
        unsigned int wi = 0xFFFFFFFFu - (unsigned int)m;
        if (lane == 0) { osc[k] = unorderable((unsigned int)(m >> 32)); oid[k] = (int)wi; }
        if (k == TOPK - 1) break;

        const unsigned long long* row = mbase + (size_t)wi * NQW;
        unsigned long long nm = 0ull;
        #pragma unroll
        for (int s = 0; s < NQW; ++s) {
            unsigned long long q = row[s];            // broadcast load (1 txn)
            bool sup = (((q >> lane) & 1ull) != 0ull) |
                       ((unsigned int)(lane + 64 * s) == wi);
            key[s] = sup ? 0ull : key[s];
            nm = (key[s] > nm) ? key[s] : nm;
        }
        m = nm;
        #pragma unroll
        for (int off = 32; off > 0; off >>= 1) {
            unsigned long long o = __shfl_xor(m, off);
            m = (o > m) ? o : m;
        }
    }
}

// ---- round-3 fused NMS kept as fallback for small ws_size ----
__device__ __forceinline__ void block_argmax(
        float v, int bi, float* pv, int* pi, int t, int buf,
        float& wv, int& wi) {
    #pragma unroll
    for (int off = 32; off > 0; off >>= 1) {
        float ov = __shfl_down(v, off);
        int   oi = __shfl_down(bi, off);
        if (ov > v || (ov == v && oi < bi)) { v = ov; bi = oi; }
    }
    if ((t & 63) == 0) { pv[buf * 4 + (t >> 6)] = v; pi[buf * 4 + (t >> 6)] = bi; }
    __syncthreads();
    wv = pv[buf * 4]; wi = pi[buf * 4];
    #pragma unroll
    for (int w = 1; w < 4; ++w) {
        float ov = pv[buf * 4 + w]; int oi = pi[buf * 4 + w];
        if (ov > wv || (ov == wv && oi < wi)) { wv = ov; wi = oi; }
    }
}

__global__ __launch_bounds__(256) void nms_kernel_fallback(
        const float* __restrict__ boxes_all, const float* __restrict__ scores_t,
        float* __restrict__ nms_score, int* __restrict__ nms_idx) {
    int b = blockIdx.x / NCLS, c = blockIdx.x % NCLS;
    __shared__ float4 sbox[NTOT];
    __shared__ float  pv[8];
    __shared__ int    pi[8];
    int t = threadIdx.x;

    const float4* bsrc = (const float4*)boxes_all + (size_t)b * NTOT;
    const float*  ssrc = scores_t + ((size_t)b * NCLS + c) * NTOT;

    float  sc[10];
    float4 bx[10];
    #pragma unroll
    for (int s = 0; s < 10; ++s) {
        int j = t + s * 256;
        if (j < NTOT) {
            float4 bj = bsrc[j];
            sbox[j] = bj;
            bx[s] = bj;
            sc[s] = ssrc[j];
        } else {
            bx[s] = make_float4(0.f, 0.f, 0.f, 0.f);
            sc[s] = -INFINITY;
        }
    }
    __syncthreads();

    float* osc = nms_score + ((size_t)b * NCLS + c) * TOPK;
    int*   oid = nms_idx   + ((size_t)b * NCLS + c) * TOPK;

    float v = -INFINITY; int bi = 0x7FFFFFFF;
    #pragma unroll
    for (int s = 0; s < 10; ++s) {
        int j = t + s * 256;
        if (sc[s] > v) { v = sc[s]; bi = j; }
    }
    float wv; int wi;
    block_argmax(v, bi, pv, pi, t, 0, wv, wi);
    int buf = 1;

    for (int k = 0; k < TOPK; ++k) {
        if (wv == -INFINITY) {
            for (int k2 = k + t; k2 < TOPK; k2 += 256) { osc[k2] = -INFINITY; oid[k2] = 0; }
            break;
        }
        if (t == 0) { osc[k] = wv; oid[k] = wi; }
        if (k == TOPK - 1) break;

        float4 wb = sbox[wi];
        float a1 = (wb.z - wb.x) * (wb.w - wb.y);
        float v2 = -INFINITY; int bi2 = 0x7FFFFFFF;
        #pragma unroll
        for (int s = 0; s < 10; ++s) {
            int j = t + s * 256;
            float4 bj = bx[s];
            float yy1 = fmaxf(wb.x, bj.x);
            float xx1 = fmaxf(wb.y, bj.y);
            float yy2 = fminf(wb.z, bj.z);
            float xx2 = fminf(wb.w, bj.w);
            float inter = fmaxf(yy2 - yy1, 0.f) * fmaxf(xx2 - xx1, 0.f);
            float a2 = (bj.z - bj.x) * (bj.w - bj.y);
            float iou = inter / (a1 + a2 - inter + 1e-9f);
            if (iou > 0.5f || j == wi) sc[s] = -INFINITY;
            if (sc[s] > v2) { v2 = sc[s]; bi2 = j; }
        }
        block_argmax(v2, bi2, pv, pi, t, buf, wv, wi);
        buf ^= 1;
    }
}

// ============================================================
// Kernel 4: per-batch global top-100 = bitonic sort of 2048 u64
// keys (score desc, flat-idx asc via ~f packing), then emit rows.
// ============================================================
__global__ __launch_bounds__(256) void final_sort_kernel(
        const float* __restrict__ nms_score, const int* __restrict__ nms_idx,
        const float* __restrict__ boxes_all, float* __restrict__ out) {
    int b = blockIdx.x, t = threadIdx.x;
    __shared__ unsigned long long sk[2048];    // 16384 B

    for (int f = t; f < 2048; f += 256) {
        unsigned long long kk = 0ull;
        if (f < 2000) {
            float s = nms_score[(size_t)b * 2000 + f];
            float v = isfinite(s) ? s : -1.0f;
            kk = ((unsigned long long)orderable(v) << 32)
               | (unsigned long long)(0xFFFFFFFFu - (unsigned int)f);
        }
        sk[f] = kk;
    }
    __syncthreads();

    // bitonic sort ascending (pad keys 0 sink to front); distinct keys.
    for (int k2 = 2; k2 <= 2048; k2 <<= 1) {
        for (int j2 = k2 >> 1; j2 > 0; j2 >>= 1) {
            for (int i = t; i < 2048; i += 256) {
                int l = i ^ j2;
                if (l > i) {
                    bool asc = ((i & k2) == 0);
                    unsigned long long a = sk[i], bb2 = sk[l];
                    if ((a > bb2) == asc) { sk[i] = bb2; sk[l] = a; }
                }
            }
            __syncthreads();
        }
    }

    if (t < TOPK) {
        unsigned long long kk = sk[2047 - t];      // t-th largest
        float v = unorderable((unsigned int)(kk >> 32));
        int fi = (int)(0xFFFFFFFFu - (unsigned int)kk);
        float* o = out + ((size_t)b * TOPK + t) * 6;
        if (v > 0.3f) {
            int bidx = nms_idx[(size_t)b * 2000 + fi];
            float4 bxw = ((const float4*)boxes_all)[(size_t)b * NTOT + bidx];
            o[0] = bxw.x; o[1] = bxw.y; o[2] = bxw.z; o[3] = bxw.w;
            o[4] = v; o[5] = (float)(fi / TOPK);
        } else {
            o[0] = 0.f; o[1] = 0.f; o[2] = 0.f; o[3] = 0.f; o[4] = 0.f; o[5] = 0.f;
        }
    }
}

extern "C" void kernel_launch(void* const* d_in, const int* in_sizes, int n_in,
                              void* d_out, int out_size, void* d_ws, size_t ws_size,
                              hipStream_t stream) {
    (void)out_size;
    const float* cls[3] = {nullptr, nullptr, nullptr};
    const float* bbx[3] = {nullptr, nullptr, nullptr};
    for (int i = 0; i < n_in; ++i) {
        const float* p = (const float*)d_in[i];
        switch (in_sizes[i]) {
            case 16 * 6400 * 20: cls[0] = p; break;
            case 16 * 6400 * 32: bbx[0] = p; break;
            case 16 * 1600 * 20: cls[1] = p; break;
            case 16 * 1600 * 32: bbx[1] = p; break;
            case 16 *  400 * 20: cls[2] = p; break;
            case 16 *  400 * 32: bbx[2] = p; break;
            default: break;  // origin_shapes (unused by reference)
        }
    }

    char* w = (char*)d_ws;
    int*   sel_idx    = (int*)(w);                       // 128000 B (round to 131072)
    float* boxes_all  = (float*)(w + 131072);            // 614400 B
    float* scores_t   = (float*)(w + 745472);            // 3072000 B
    unsigned int* keys0 = (unsigned int*)(w + 745472);           // aliased (dies pre-decode)
    unsigned int* keys1 = (unsigned int*)(w + 745472 + 409600);
    float* nms_score  = (float*)(w + 3817472);           // 128000 B
    int*   nms_idx    = (int*)(w + 3945472);             // 128000 B
    unsigned long long* mask = (unsigned long long*)(w + 4073472);  // 11673600 B
    const size_t need_mask = 4073472ull + (size_t)BATCH * NTOT * NQW * 8ull;  // 15747072
    bool use_mask = ws_size >= need_mask;

    hipLaunchKernelGGL(compute_keys_kernel, dim3((BATCH * (N0 + N1) + 255) / 256), dim3(256), 0, stream,
                       cls[0], cls[1], keys0, keys1);
    hipLaunchKernelGGL(radix_select_kernel, dim3(32), dim3(256), 0, stream,
                       keys0, keys1, sel_idx);
    hipLaunchKernelGGL(decode_kernel, dim3((BATCH * NTOT + 255) / 256), dim3(256), 0, stream,
                       cls[0], cls[1], cls[2], bbx[0], bbx[1], bbx[2],
                       sel_idx, boxes_all, scores_t);
    if (use_mask) {
        hipLaunchKernelGGL(iou_mask_kernel, dim3(BATCH * 40), dim3(256), 0, stream,
                           boxes_all, mask);
        hipLaunchKernelGGL(nms_wave_kernel, dim3(BATCH * NCLS), dim3(64), 0, stream,
                           scores_t, mask, nms_score, nms_idx);
    } else {
        hipLaunchKernelGGL(nms_kernel_fallback, dim3(BATCH * NCLS), dim3(256), 0, stream,
                           boxes_all, scores_t, nms_score, nms_idx);
    }
    hipLaunchKernelGGL(final_sort_kernel, dim3(BATCH), dim3(256), 0, stream,
                       nms_score, nms_idx, boxes_all, (float*)d_out);
}

// Round 5
// 482.521 us; speedup vs baseline: 1.0419x; 1.0419x over previous
//
#include <hip/hip_runtime.h>
#include <math.h>

#define BATCH 16
#define NCLS 20
#define TOPK 100
#define NPRE 1000
#define NTOT 2400
#define NBINS 8
#define N0 6400
#define N1 1600
#define NQW 38           // qwords per mask row (2432 bits >= 2400)
#define PFQW (NTOT * NQW / NCLS)   // 4560 qwords: per-class prefetch slice

// ---- order-preserving float->uint map (ascending) ----
__device__ __forceinline__ unsigned int orderable(float x) {
    unsigned int u = __float_as_uint(x);
    return (u & 0x80000000u) ? ~u : (u | 0x80000000u);
}
__device__ __forceinline__ float unorderable(unsigned int k) {
    return __uint_as_float((k & 0x80000000u) ? (k ^ 0x80000000u) : ~k);
}

// ============================================================
// Kernel 0: per-anchor key = orderable(max_c logit).
// ============================================================
__global__ __launch_bounds__(256) void compute_keys_kernel(
        const float* __restrict__ cls0, const float* __restrict__ cls1,
        unsigned int* __restrict__ keys0, unsigned int* __restrict__ keys1) {
    int tg = blockIdx.x * 256 + threadIdx.x;
    const float* p;
    unsigned int* dst;
    if (tg < BATCH * N0) {
        p = cls0 + (size_t)tg * NCLS;
        dst = keys0 + tg;
    } else {
        int a = tg - BATCH * N0;
        if (a >= BATCH * N1) return;
        p = cls1 + (size_t)a * NCLS;
        dst = keys1 + a;
    }
    const float4* p4 = (const float4*)p;
    float m = -INFINITY;
    #pragma unroll
    for (int q = 0; q < 5; ++q) {
        float4 v = p4[q];
        m = fmaxf(m, fmaxf(fmaxf(v.x, v.y), fmaxf(v.z, v.w)));
    }
    *dst = orderable(m);
}

// ============================================================
// Kernel 1: per (batch, level) exact top-1000 radix select.
// ============================================================
__global__ __launch_bounds__(256) void radix_select_kernel(
        const unsigned int* __restrict__ keys0, const unsigned int* __restrict__ keys1,
        int* __restrict__ sel_idx) {
    int bid = blockIdx.x;            // 0..31
    int b = bid >> 1;
    int lvl = bid & 1;
    int n = (lvl == 0) ? N0 : N1;
    const unsigned int* gk = (lvl == 0 ? keys0 : keys1) + (size_t)b * n;

    __shared__ unsigned int skey[N0];
    __shared__ unsigned int hist[256];
    __shared__ unsigned int sfxA[257], sfxB[257];
    __shared__ int eq[256];
    __shared__ unsigned int s_prefix, s_kk, s_cnt, s_eqcnt;
    int t = threadIdx.x;

    for (int a = t; a < n; a += 256) skey[a] = gk[a];
    if (t == 0) {
        s_kk = NPRE; s_prefix = 0u; s_cnt = 0u; s_eqcnt = 0u;
        sfxA[256] = 0u; sfxB[256] = 0u;
    }
    __syncthreads();

    for (int pass = 0; pass < 4; ++pass) {
        int shift = 24 - 8 * pass;
        hist[t] = 0u;
        __syncthreads();
        unsigned int prefix = s_prefix, kk = s_kk;
        for (int a = t; a < n; a += 256) {
            unsigned int u = skey[a];
            if (pass == 0 || (u >> (shift + 8)) == prefix)
                atomicAdd(&hist[(u >> shift) & 255u], 1u);
        }
        __syncthreads();
        sfxA[t] = hist[t];
        __syncthreads();
        unsigned int* src = sfxA; unsigned int* dst = sfxB;
        #pragma unroll
        for (int step = 1; step < 256; step <<= 1) {
            int idx = t + step; if (idx > 256) idx = 256;
            dst[t] = src[t] + src[idx];
            __syncthreads();
            unsigned int* tmp = src; src = dst; dst = tmp;
        }
        unsigned int Sd = src[t];
        unsigned int Sd1 = src[t + 1];
        if (Sd >= kk && Sd1 < kk) {
            s_prefix = (prefix << 8) | (unsigned int)t;
            s_kk = kk - Sd1;
        }
        __syncthreads();
    }

    unsigned int T = s_prefix;
    int* out = sel_idx + b * 2000 + lvl * 1000;
    for (int a = t; a < n; a += 256) {
        unsigned int u = skey[a];
        if (u > T) {
            unsigned int pos = atomicAdd(&s_cnt, 1u);
            out[pos] = a;
        } else if (u == T) {
            unsigned int p = atomicAdd(&s_eqcnt, 1u);
            if (p < 256u) eq[p] = a;
        }
    }
    __syncthreads();
    if (t == 0) {
        unsigned int pos = s_cnt;
        unsigned int rem = s_kk;
        unsigned int cnt = s_eqcnt;
        if (cnt <= 256u) {
            for (unsigned int i = 1; i < cnt; ++i) {
                int key = eq[i]; int j2 = (int)i - 1;
                while (j2 >= 0 && eq[j2] > key) { eq[j2 + 1] = eq[j2]; --j2; }
                eq[j2 + 1] = key;
            }
            for (unsigned int i = 0; i < rem; ++i) out[pos + i] = eq[i];
        } else {
            for (int a = 0; a < n && rem > 0u; ++a)
                if (skey[a] == T) { out[pos++] = a; --rem; }
        }
    }
}

// ============================================================
// Kernel 2: decode scores (sigmoid, transposed [b][c][j]) + DFL boxes.
// ============================================================
__global__ __launch_bounds__(256) void decode_kernel(
        const float* __restrict__ cls0, const float* __restrict__ cls1, const float* __restrict__ cls2,
        const float* __restrict__ bb0,  const float* __restrict__ bb1,  const float* __restrict__ bb2,
        const int* __restrict__ sel_idx,
        float* __restrict__ boxes_all, float* __restrict__ scores_t) {
    int tg = blockIdx.x * blockDim.x + threadIdx.x;
    if (tg >= BATCH * NTOT) return;
    int b = tg / NTOT, j = tg % NTOT;

    const float* cls; const float* bb; int a, w; float stride;
    if (j < 1000) {
        a = sel_idx[b * 2000 + j]; w = 80; stride = 8.f;
        cls = cls0 + ((size_t)b * N0 + a) * NCLS;
        bb  = bb0  + ((size_t)b * N0 + a) * 32;
    } else if (j < 2000) {
        a = sel_idx[b * 2000 + j]; w = 40; stride = 16.f;
        cls = cls1 + ((size_t)b * N1 + a) * NCLS;
        bb  = bb1  + ((size_t)b * N1 + a) * 32;
    } else {
        a = j - 2000; w = 20; stride = 32.f;
        cls = cls2 + ((size_t)b * 400 + a) * NCLS;
        bb  = bb2  + ((size_t)b * 400 + a) * 32;
    }

    float cl[20];
    {
        const float4* c4 = (const float4*)cls;
        #pragma unroll
        for (int q = 0; q < 5; ++q) *(float4*)&cl[q * 4] = c4[q];
    }
    float bl[32];
    {
        const float4* b4 = (const float4*)bb;
        #pragma unroll
        for (int q = 0; q < 8; ++q) *(float4*)&bl[q * 4] = b4[q];
    }

    #pragma unroll
    for (int c = 0; c < NCLS; ++c)
        scores_t[((size_t)b * NCLS + c) * NTOT + j] = 1.f / (1.f + expf(-cl[c]));

    float d[4];
    #pragma unroll
    for (int s = 0; s < 4; ++s) {
        const float* l = &bl[s * NBINS];
        float m = l[0];
        #pragma unroll
        for (int k = 1; k < NBINS; ++k) m = fmaxf(m, l[k]);
        float e[NBINS], sum = 0.f;
        #pragma unroll
        for (int k = 0; k < NBINS; ++k) { e[k] = expf(l[k] - m); sum += e[k]; }
        float acc = 0.f;
        #pragma unroll
        for (int k = 0; k < NBINS; ++k) acc += (e[k] / sum) * (float)k;
        d[s] = acc * stride;
    }
    float cy = ((float)(a / w) + 0.5f) * stride;
    float cx = ((float)(a % w) + 0.5f) * stride;
    float* bx = boxes_all + ((size_t)b * NTOT + j) * 4;
    bx[0] = fminf(fmaxf(cy - d[0], 0.f), 640.f);   // y1
    bx[1] = fminf(fmaxf(cx - d[1], 0.f), 640.f);   // x1
    bx[2] = fminf(fmaxf(cy + d[2], 0.f), 640.f);   // y2
    bx[3] = fminf(fmaxf(cx + d[3], 0.f), 640.f);   // x2
}

// ============================================================
// Kernel 2b: per-batch all-pairs IoU suppression bitmask.
// XCD swizzle: b = blockIdx % 16 so batch b's blocks land on XCD b%8
// (heuristic XCD = blockIdx % 8) -> mask rows written into that L2.
// ============================================================
__global__ __launch_bounds__(256) void iou_mask_kernel(
        const float* __restrict__ boxes_all, unsigned long long* __restrict__ mask) {
    int bid = blockIdx.x;
    int b = bid % BATCH;                     // XCD-swizzled mapping
    int rem = bid / BATCH;                   // 0..39
    int stripe = rem >> 2;
    int r = rem & 3;
    int q0 = (r < 3) ? r * 10 : 29;          // {0,10,20,29}
    int q1 = q0 + ((r >= 2) ? 9 : 10);       // {10,20,29,38}

    __shared__ float4 sbox[NTOT];            // 38400 B
    const float4* bsrc = (const float4*)boxes_all + (size_t)b * NTOT;
    int t = threadIdx.x;
    for (int j = t; j < NTOT; j += 256) sbox[j] = bsrc[j];
    __syncthreads();

    int i = stripe * 256 + t;
    if (i >= NTOT) return;
    float4 bi = sbox[i];
    float a1 = (bi.z - bi.x) * (bi.w - bi.y);
    unsigned long long* row = mask + ((size_t)b * NTOT + i) * NQW;

    for (int qw = q0; qw < q1; ++qw) {
        unsigned long long m = 0ull;
        int jbase = qw * 64;
        for (int tt = 0; tt < 64; ++tt) {
            int j = jbase + tt;
            if (j < NTOT) {
                float4 bj = sbox[j];                       // broadcast (same j all lanes)
                float yy1 = fmaxf(bi.x, bj.x);
                float xx1 = fmaxf(bi.y, bj.y);
                float yy2 = fminf(bi.z, bj.z);
                float xx2 = fminf(bi.w, bj.w);
                float inter = fmaxf(yy2 - yy1, 0.f) * fmaxf(xx2 - xx1, 0.f);
                float a2 = (bj.z - bj.x) * (bj.w - bj.y);
                float iou = inter / (a1 + a2 - inter + 1e-9f);
                if (iou > 0.5f) m |= (1ull << tt);
            }
        }
        row[qw] = m;
    }
}

// ============================================================
// Kernel 3: greedy NMS, ONE WAVE per (batch, class).
// XCD swizzle: b = blockIdx % 16 -> reader waves of batch b land on
// the same XCD whose L2 the writer warmed. Each class-wave also bulk-
// prefetches its disjoint 1/20 slice of the batch mask so first-touch
// misses are pipelined BW, not serial-chain latency.
// ============================================================
__global__ __launch_bounds__(64) void nms_wave_kernel(
        const float* __restrict__ scores_t, const unsigned long long* __restrict__ mask,
        float* __restrict__ nms_score, int* __restrict__ nms_idx,
        unsigned long long* __restrict__ pf_sink) {
    int blk = blockIdx.x;
    int b = blk % BATCH, c = blk / BATCH;    // XCD-swizzled mapping
    int lane = threadIdx.x;
    const float* ssrc = scores_t + ((size_t)b * NCLS + c) * NTOT;
    const unsigned long long* mbase = mask + (size_t)b * NTOT * NQW;

    // ---- bulk prefetch of this class's slice of the batch mask ----
    {
        const unsigned long long* pf = mbase + (size_t)c * PFQW;
        unsigned long long acc = 0ull;
        for (int s = lane; s < PFQW; s += 64) acc ^= pf[s];
        if (lane == 0) pf_sink[blk] = acc;   // defeat DCE
    }

    unsigned long long key[NQW];
    #pragma unroll
    for (int s = 0; s < NQW; ++s) {
        int j = lane + 64 * s;
        if (j < NTOT) {
            float sc = ssrc[j];                       // coalesced
            key[s] = ((unsigned long long)orderable(sc) << 32)
                   | (unsigned long long)(0xFFFFFFFFu - (unsigned int)j);
        } else {
            key[s] = 0ull;
        }
    }

    float* osc = nms_score + ((size_t)b * NCLS + c) * TOPK;
    int*   oid = nms_idx   + ((size_t)b * NCLS + c) * TOPK;

    // initial wave argmax (u64 packed: max key = max score, tie -> lowest j)
    unsigned long long m = 0ull;
    #pragma unroll
    for (int s = 0; s < NQW; ++s) m = (key[s] > m) ? key[s] : m;
    #pragma unroll
    for (int off = 32; off > 0; off >>= 1) {
        unsigned long long o = __shfl_xor(m, off);
        m = (o > m) ? o : m;
    }

    for (int k = 0; k < TOPK; ++k) {
        if (m == 0ull) {   // all suppressed: rest is (-inf, 0)
            for (int k2 = k + lane; k2 < TOPK; k2 += 64) { osc[k2] = -INFINITY; oid[k2] = 0; }
            break;
        }
        unsigned int wi = 0xFFFFFFFFu - (unsigned int)m;
        if (lane == 0) { osc[k] = unorderable((unsigned int)(m >> 32)); oid[k] = (int)wi; }
        if (k == TOPK - 1) break;

        const unsigned long long* row = mbase + (size_t)wi * NQW;
        unsigned long long nm = 0ull;
        #pragma unroll
        for (int s = 0; s < NQW; ++s) {
            unsigned long long q = row[s];            // broadcast load (L2-warm)
            bool sup = (((q >> lane) & 1ull) != 0ull) |
                       ((unsigned int)(lane + 64 * s) == wi);
            key[s] = sup ? 0ull : key[s];
            nm = (key[s] > nm) ? key[s] : nm;
        }
        m = nm;
        #pragma unroll
        for (int off = 32; off > 0; off >>= 1) {
            unsigned long long o = __shfl_xor(m, off);
            m = (o > m) ? o : m;
        }
    }
}

// ---- round-3 fused NMS kept as fallback for small ws_size ----
__device__ __forceinline__ void block_argmax(
        float v, int bi, float* pv, int* pi, int t, int buf,
        float& wv, int& wi) {
    #pragma unroll
    for (int off = 32; off > 0; off >>= 1) {
        float ov = __shfl_down(v, off);
        int   oi = __shfl_down(bi, off);
        if (ov > v || (ov == v && oi < bi)) { v = ov; bi = oi; }
    }
    if ((t & 63) == 0) { pv[buf * 4 + (t >> 6)] = v; pi[buf * 4 + (t >> 6)] = bi; }
    __syncthreads();
    wv = pv[buf * 4]; wi = pi[buf * 4];
    #pragma unroll
    for (int w = 1; w < 4; ++w) {
        float ov = pv[buf * 4 + w]; int oi = pi[buf * 4 + w];
        if (ov > wv || (ov == wv && oi < wi)) { wv = ov; wi = oi; }
    }
}

__global__ __launch_bounds__(256) void nms_kernel_fallback(
        const float* __restrict__ boxes_all, const float* __restrict__ scores_t,
        float* __restrict__ nms_score, int* __restrict__ nms_idx) {
    int b = blockIdx.x / NCLS, c = blockIdx.x % NCLS;
    __shared__ float4 sbox[NTOT];
    __shared__ float  pv[8];
    __shared__ int    pi[8];
    int t = threadIdx.x;

    const float4* bsrc = (const float4*)boxes_all + (size_t)b * NTOT;
    const float*  ssrc = scores_t + ((size_t)b * NCLS + c) * NTOT;

    float  sc[10];
    float4 bx[10];
    #pragma unroll
    for (int s = 0; s < 10; ++s) {
        int j = t + s * 256;
        if (j < NTOT) {
            float4 bj = bsrc[j];
            sbox[j] = bj;
            bx[s] = bj;
            sc[s] = ssrc[j];
        } else {
            bx[s] = make_float4(0.f, 0.f, 0.f, 0.f);
            sc[s] = -INFINITY;
        }
    }
    __syncthreads();

    float* osc = nms_score + ((size_t)b * NCLS + c) * TOPK;
    int*   oid = nms_idx   + ((size_t)b * NCLS + c) * TOPK;

    float v = -INFINITY; int bi = 0x7FFFFFFF;
    #pragma unroll
    for (int s = 0; s < 10; ++s) {
        int j = t + s * 256;
        if (sc[s] > v) { v = sc[s]; bi = j; }
    }
    float wv; int wi;
    block_argmax(v, bi, pv, pi, t, 0, wv, wi);
    int buf = 1;

    for (int k = 0; k < TOPK; ++k) {
        if (wv == -INFINITY) {
            for (int k2 = k + t; k2 < TOPK; k2 += 256) { osc[k2] = -INFINITY; oid[k2] = 0; }
            break;
        }
        if (t == 0) { osc[k] = wv; oid[k] = wi; }
        if (k == TOPK - 1) break;

        float4 wb = sbox[wi];
        float a1 = (wb.z - wb.x) * (wb.w - wb.y);
        float v2 = -INFINITY; int bi2 = 0x7FFFFFFF;
        #pragma unroll
        for (int s = 0; s < 10; ++s) {
            int j = t + s * 256;
            float4 bj = bx[s];
            float yy1 = fmaxf(wb.x, bj.x);
            float xx1 = fmaxf(wb.y, bj.y);
            float yy2 = fminf(wb.z, bj.z);
            float xx2 = fminf(wb.w, bj.w);
            float inter = fmaxf(yy2 - yy1, 0.f) * fmaxf(xx2 - xx1, 0.f);
            float a2 = (bj.z - bj.x) * (bj.w - bj.y);
            float iou = inter / (a1 + a2 - inter + 1e-9f);
            if (iou > 0.5f || j == wi) sc[s] = -INFINITY;
            if (sc[s] > v2) { v2 = sc[s]; bi2 = j; }
        }
        block_argmax(v2, bi2, pv, pi, t, buf, wv, wi);
        buf ^= 1;
    }
}

// ============================================================
// Kernel 4: per-batch global top-100 = bitonic sort of 2048 u64 keys.
// ============================================================
__global__ __launch_bounds__(256) void final_sort_kernel(
        const float* __restrict__ nms_score, const int* __restrict__ nms_idx,
        const float* __restrict__ boxes_all, float* __restrict__ out) {
    int b = blockIdx.x, t = threadIdx.x;
    __shared__ unsigned long long sk[2048];    // 16384 B

    for (int f = t; f < 2048; f += 256) {
        unsigned long long kk = 0ull;
        if (f < 2000) {
            float s = nms_score[(size_t)b * 2000 + f];
            float v = isfinite(s) ? s : -1.0f;
            kk = ((unsigned long long)orderable(v) << 32)
               | (unsigned long long)(0xFFFFFFFFu - (unsigned int)f);
        }
        sk[f] = kk;
    }
    __syncthreads();

    for (int k2 = 2; k2 <= 2048; k2 <<= 1) {
        for (int j2 = k2 >> 1; j2 > 0; j2 >>= 1) {
            for (int i = t; i < 2048; i += 256) {
                int l = i ^ j2;
                if (l > i) {
                    bool asc = ((i & k2) == 0);
                    unsigned long long a = sk[i], bb2 = sk[l];
                    if ((a > bb2) == asc) { sk[i] = bb2; sk[l] = a; }
                }
            }
            __syncthreads();
        }
    }

    if (t < TOPK) {
        unsigned long long kk = sk[2047 - t];      // t-th largest
        float v = unorderable((unsigned int)(kk >> 32));
        int fi = (int)(0xFFFFFFFFu - (unsigned int)kk);
        float* o = out + ((size_t)b * TOPK + t) * 6;
        if (v > 0.3f) {
            int bidx = nms_idx[(size_t)b * 2000 + fi];
            float4 bxw = ((const float4*)boxes_all)[(size_t)b * NTOT + bidx];
            o[0] = bxw.x; o[1] = bxw.y; o[2] = bxw.z; o[3] = bxw.w;
            o[4] = v; o[5] = (float)(fi / TOPK);
        } else {
            o[0] = 0.f; o[1] = 0.f; o[2] = 0.f; o[3] = 0.f; o[4] = 0.f; o[5] = 0.f;
        }
    }
}

extern "C" void kernel_launch(void* const* d_in, const int* in_sizes, int n_in,
                              void* d_out, int out_size, void* d_ws, size_t ws_size,
                              hipStream_t stream) {
    (void)out_size;
    const float* cls[3] = {nullptr, nullptr, nullptr};
    const float* bbx[3] = {nullptr, nullptr, nullptr};
    for (int i = 0; i < n_in; ++i) {
        const float* p = (const float*)d_in[i];
        switch (in_sizes[i]) {
            case 16 * 6400 * 20: cls[0] = p; break;
            case 16 * 6400 * 32: bbx[0] = p; break;
            case 16 * 1600 * 20: cls[1] = p; break;
            case 16 * 1600 * 32: bbx[1] = p; break;
            case 16 *  400 * 20: cls[2] = p; break;
            case 16 *  400 * 32: bbx[2] = p; break;
            default: break;  // origin_shapes (unused by reference)
        }
    }

    char* w = (char*)d_ws;
    int*   sel_idx    = (int*)(w);                       // 128000 B used
    unsigned long long* pf_sink = (unsigned long long*)(w + 128320);  // 2560 B (dead hole, 8B-aligned)
    float* boxes_all  = (float*)(w + 131072);            // 614400 B
    float* scores_t   = (float*)(w + 745472);            // 3072000 B
    unsigned int* keys0 = (unsigned int*)(w + 745472);           // aliased (dies pre-decode)
    unsigned int* keys1 = (unsigned int*)(w + 745472 + 409600);
    float* nms_score  = (float*)(w + 3817472);           // 128000 B
    int*   nms_idx    = (int*)(w + 3945472);             // 128000 B
    unsigned long long* mask = (unsigned long long*)(w + 4073472);  // 11673600 B
    const size_t need_mask = 4073472ull + (size_t)BATCH * NTOT * NQW * 8ull;  // 15747072
    bool use_mask = ws_size >= need_mask;

    hipLaunchKernelGGL(compute_keys_kernel, dim3((BATCH * (N0 + N1) + 255) / 256), dim3(256), 0, stream,
                       cls[0], cls[1], keys0, keys1);
    hipLaunchKernelGGL(radix_select_kernel, dim3(32), dim3(256), 0, stream,
                       keys0, keys1, sel_idx);
    hipLaunchKernelGGL(decode_kernel, dim3((BATCH * NTOT + 255) / 256), dim3(256), 0, stream,
                       cls[0], cls[1], cls[2], bbx[0], bbx[1], bbx[2],
                       sel_idx, boxes_all, scores_t);
    if (use_mask) {
        hipLaunchKernelGGL(iou_mask_kernel, dim3(BATCH * 40), dim3(256), 0, stream,
                           boxes_all, mask);
        hipLaunchKernelGGL(nms_wave_kernel, dim3(BATCH * NCLS), dim3(64), 0, stream,
                           scores_t, mask, nms_score, nms_idx, pf_sink);
    } else {
        hipLaunchKernelGGL(nms_kernel_fallback, dim3(BATCH * NCLS), dim3(256), 0, stream,
                           boxes_all, scores_t, nms_score, nms_idx);
    }
    hipLaunchKernelGGL(final_sort_kernel, dim3(BATCH), dim3(256), 0, stream,
                       nms_score, nms_idx, boxes_all, (float*)d_out);
}

// Round 6
// 427.107 us; speedup vs baseline: 1.1771x; 1.1297x over previous
//
#include <hip/hip_runtime.h>
#include <math.h>

#define BATCH 16
#define NCLS 20
#define TOPK 100
#define NPRE 1000
#define NTOT 2400
#define NBINS 8
#define N0 6400
#define N1 1600
#define NSLOT 38         // 64 lanes x 38 slots = 2432 >= 2400

// Exact replication of RN(inter/denom) > 0.5f for positive finite floats:
// RN(x) > 0.5 <=> x > 0.5 + 2^-25 (midpoint; tie-to-even rounds DOWN to 0.5).
// (double)denom * MID is exact (24+26 = 50 significand bits < 53).
#define MID05 0.50000002980232238769531250

// ---- order-preserving float->uint map (ascending) ----
__device__ __forceinline__ unsigned int orderable(float x) {
    unsigned int u = __float_as_uint(x);
    return (u & 0x80000000u) ? ~u : (u | 0x80000000u);
}
__device__ __forceinline__ float unorderable(unsigned int k) {
    return __uint_as_float((k & 0x80000000u) ? (k ^ 0x80000000u) : ~k);
}

// ============================================================
// Kernel 0: per-anchor key = orderable(max_c logit).
// ============================================================
__global__ __launch_bounds__(256) void compute_keys_kernel(
        const float* __restrict__ cls0, const float* __restrict__ cls1,
        unsigned int* __restrict__ keys0, unsigned int* __restrict__ keys1) {
    int tg = blockIdx.x * 256 + threadIdx.x;
    const float* p;
    unsigned int* dst;
    if (tg < BATCH * N0) {
        p = cls0 + (size_t)tg * NCLS;
        dst = keys0 + tg;
    } else {
        int a = tg - BATCH * N0;
        if (a >= BATCH * N1) return;
        p = cls1 + (size_t)a * NCLS;
        dst = keys1 + a;
    }
    const float4* p4 = (const float4*)p;
    float m = -INFINITY;
    #pragma unroll
    for (int q = 0; q < 5; ++q) {
        float4 v = p4[q];
        m = fmaxf(m, fmaxf(fmaxf(v.x, v.y), fmaxf(v.z, v.w)));
    }
    *dst = orderable(m);
}

// ============================================================
// Kernel 1: per (batch, level) exact top-1000 radix select.
// ============================================================
__global__ __launch_bounds__(256) void radix_select_kernel(
        const unsigned int* __restrict__ keys0, const unsigned int* __restrict__ keys1,
        int* __restrict__ sel_idx) {
    int bid = blockIdx.x;            // 0..31
    int b = bid >> 1;
    int lvl = bid & 1;
    int n = (lvl == 0) ? N0 : N1;
    const unsigned int* gk = (lvl == 0 ? keys0 : keys1) + (size_t)b * n;

    __shared__ unsigned int skey[N0];
    __shared__ unsigned int hist[256];
    __shared__ unsigned int sfxA[257], sfxB[257];
    __shared__ int eq[256];
    __shared__ unsigned int s_prefix, s_kk, s_cnt, s_eqcnt;
    int t = threadIdx.x;

    for (int a = t; a < n; a += 256) skey[a] = gk[a];
    if (t == 0) {
        s_kk = NPRE; s_prefix = 0u; s_cnt = 0u; s_eqcnt = 0u;
        sfxA[256] = 0u; sfxB[256] = 0u;
    }
    __syncthreads();

    for (int pass = 0; pass < 4; ++pass) {
        int shift = 24 - 8 * pass;
        hist[t] = 0u;
        __syncthreads();
        unsigned int prefix = s_prefix, kk = s_kk;
        for (int a = t; a < n; a += 256) {
            unsigned int u = skey[a];
            if (pass == 0 || (u >> (shift + 8)) == prefix)
                atomicAdd(&hist[(u >> shift) & 255u], 1u);
        }
        __syncthreads();
        sfxA[t] = hist[t];
        __syncthreads();
        unsigned int* src = sfxA; unsigned int* dst = sfxB;
        #pragma unroll
        for (int step = 1; step < 256; step <<= 1) {
            int idx = t + step; if (idx > 256) idx = 256;
            dst[t] = src[t] + src[idx];
            __syncthreads();
            unsigned int* tmp = src; src = dst; dst = tmp;
        }
        unsigned int Sd = src[t];
        unsigned int Sd1 = src[t + 1];
        if (Sd >= kk && Sd1 < kk) {
            s_prefix = (prefix << 8) | (unsigned int)t;
            s_kk = kk - Sd1;
        }
        __syncthreads();
    }

    unsigned int T = s_prefix;
    int* out = sel_idx + b * 2000 + lvl * 1000;
    for (int a = t; a < n; a += 256) {
        unsigned int u = skey[a];
        if (u > T) {
            unsigned int pos = atomicAdd(&s_cnt, 1u);
            out[pos] = a;
        } else if (u == T) {
            unsigned int p = atomicAdd(&s_eqcnt, 1u);
            if (p < 256u) eq[p] = a;
        }
    }
    __syncthreads();
    if (t == 0) {
        unsigned int pos = s_cnt;
        unsigned int rem = s_kk;
        unsigned int cnt = s_eqcnt;
        if (cnt <= 256u) {
            for (unsigned int i = 1; i < cnt; ++i) {
                int key = eq[i]; int j2 = (int)i - 1;
                while (j2 >= 0 && eq[j2] > key) { eq[j2 + 1] = eq[j2]; --j2; }
                eq[j2 + 1] = key;
            }
            for (unsigned int i = 0; i < rem; ++i) out[pos + i] = eq[i];
        } else {
            for (int a = 0; a < n && rem > 0u; ++a)
                if (skey[a] == T) { out[pos++] = a; --rem; }
        }
    }
}

// ============================================================
// Kernel 2: decode scores (sigmoid, transposed [b][c][j]) + DFL boxes.
// ============================================================
__global__ __launch_bounds__(256) void decode_kernel(
        const float* __restrict__ cls0, const float* __restrict__ cls1, const float* __restrict__ cls2,
        const float* __restrict__ bb0,  const float* __restrict__ bb1,  const float* __restrict__ bb2,
        const int* __restrict__ sel_idx,
        float* __restrict__ boxes_all, float* __restrict__ scores_t) {
    int tg = blockIdx.x * blockDim.x + threadIdx.x;
    if (tg >= BATCH * NTOT) return;
    int b = tg / NTOT, j = tg % NTOT;

    const float* cls; const float* bb; int a, w; float stride;
    if (j < 1000) {
        a = sel_idx[b * 2000 + j]; w = 80; stride = 8.f;
        cls = cls0 + ((size_t)b * N0 + a) * NCLS;
        bb  = bb0  + ((size_t)b * N0 + a) * 32;
    } else if (j < 2000) {
        a = sel_idx[b * 2000 + j]; w = 40; stride = 16.f;
        cls = cls1 + ((size_t)b * N1 + a) * NCLS;
        bb  = bb1  + ((size_t)b * N1 + a) * 32;
    } else {
        a = j - 2000; w = 20; stride = 32.f;
        cls = cls2 + ((size_t)b * 400 + a) * NCLS;
        bb  = bb2  + ((size_t)b * 400 + a) * 32;
    }

    float cl[20];
    {
        const float4* c4 = (const float4*)cls;
        #pragma unroll
        for (int q = 0; q < 5; ++q) *(float4*)&cl[q * 4] = c4[q];
    }
    float bl[32];
    {
        const float4* b4 = (const float4*)bb;
        #pragma unroll
        for (int q = 0; q < 8; ++q) *(float4*)&bl[q * 4] = b4[q];
    }

    #pragma unroll
    for (int c = 0; c < NCLS; ++c)
        scores_t[((size_t)b * NCLS + c) * NTOT + j] = 1.f / (1.f + expf(-cl[c]));

    float d[4];
    #pragma unroll
    for (int s = 0; s < 4; ++s) {
        const float* l = &bl[s * NBINS];
        float m = l[0];
        #pragma unroll
        for (int k = 1; k < NBINS; ++k) m = fmaxf(m, l[k]);
        float e[NBINS], sum = 0.f;
        #pragma unroll
        for (int k = 0; k < NBINS; ++k) { e[k] = expf(l[k] - m); sum += e[k]; }
        float acc = 0.f;
        #pragma unroll
        for (int k = 0; k < NBINS; ++k) acc += (e[k] / sum) * (float)k;
        d[s] = acc * stride;
    }
    float cy = ((float)(a / w) + 0.5f) * stride;
    float cx = ((float)(a % w) + 0.5f) * stride;
    float* bx = boxes_all + ((size_t)b * NTOT + j) * 4;
    bx[0] = fminf(fmaxf(cy - d[0], 0.f), 640.f);   // y1
    bx[1] = fminf(fmaxf(cx - d[1], 0.f), 640.f);   // x1
    bx[2] = fminf(fmaxf(cy + d[2], 0.f), 640.f);   // y2
    bx[3] = fminf(fmaxf(cx + d[3], 0.f), 640.f);   // x2
}

// ============================================================
// Kernel 3: greedy NMS, ONE WAVE per (batch, class).
// Keys (u64 score|~idx) + areas in registers; boxes in LDS.
// IoU recomputed per iteration (VALU issue-bound, zero global
// memory in the serial chain). No barriers; butterfly reduce.
// Division replaced by exact double-mul comparison (see MID05).
// ============================================================
__global__ __launch_bounds__(64, 1) void nms_wave_iou_kernel(
        const float* __restrict__ boxes_all, const float* __restrict__ scores_t,
        float* __restrict__ nms_score, int* __restrict__ nms_idx) {
    int blk = blockIdx.x;
    int b = blk / NCLS, c = blk % NCLS;
    int lane = threadIdx.x;
    __shared__ float4 sbox[NTOT];          // 38400 B

    const float4* bsrc = (const float4*)boxes_all + (size_t)b * NTOT;
    const float*  ssrc = scores_t + ((size_t)b * NCLS + c) * NTOT;

    unsigned long long key[NSLOT];
    float a2r[NSLOT];
    #pragma unroll
    for (int s = 0; s < NSLOT; ++s) {
        int j = lane + 64 * s;
        if (j < NTOT) {
            float4 bj = bsrc[j];              // coalesced
            sbox[j] = bj;
            a2r[s] = (bj.z - bj.x) * (bj.w - bj.y);
            float sc = ssrc[j];               // coalesced
            key[s] = ((unsigned long long)orderable(sc) << 32)
                   | (unsigned long long)(0xFFFFFFFFu - (unsigned int)j);
        } else {
            a2r[s] = 0.f;
            key[s] = 0ull;
        }
    }
    __syncthreads();   // single-wave: compiles to an LDS drain; cheap

    float* osc = nms_score + ((size_t)b * NCLS + c) * TOPK;
    int*   oid = nms_idx   + ((size_t)b * NCLS + c) * TOPK;

    // initial max (4 independent accumulator chains, then butterfly)
    unsigned long long m;
    {
        unsigned long long m0 = 0, m1 = 0, m2 = 0, m3 = 0;
        #pragma unroll
        for (int s = 0; s < NSLOT; s += 4) {
            m0 = (key[s] > m0) ? key[s] : m0;
            if (s + 1 < NSLOT) m1 = (key[s+1] > m1) ? key[s+1] : m1;
            if (s + 2 < NSLOT) m2 = (key[s+2] > m2) ? key[s+2] : m2;
            if (s + 3 < NSLOT) m3 = (key[s+3] > m3) ? key[s+3] : m3;
        }
        m0 = (m1 > m0) ? m1 : m0;
        m2 = (m3 > m2) ? m3 : m2;
        m = (m2 > m0) ? m2 : m0;
        #pragma unroll
        for (int off = 32; off > 0; off >>= 1) {
            unsigned long long o = __shfl_xor(m, off);
            m = (o > m) ? o : m;
        }
    }

    for (int k = 0; k < TOPK; ++k) {
        if (m == 0ull) {   // all suppressed: rest is (-inf, 0)
            for (int k2 = k + lane; k2 < TOPK; k2 += 64) { osc[k2] = -INFINITY; oid[k2] = 0; }
            break;
        }
        unsigned int wi = 0xFFFFFFFFu - (unsigned int)m;
        if (lane == 0) { osc[k] = unorderable((unsigned int)(m >> 32)); oid[k] = (int)wi; }
        if (k == TOPK - 1) break;

        float4 wb = sbox[wi];                 // LDS broadcast (one b128)
        float a1 = (wb.z - wb.x) * (wb.w - wb.y);

        unsigned long long n0 = 0, n1 = 0, n2 = 0, n3 = 0;
        #pragma unroll
        for (int s = 0; s < NSLOT; ++s) {
            int j = lane + 64 * s;
            float4 bj = sbox[j < NTOT ? j : 0];   // own-slot LDS read (loop-invariant addr)
            float yy1 = fmaxf(wb.x, bj.x);
            float xx1 = fmaxf(wb.y, bj.y);
            float yy2 = fminf(wb.z, bj.z);
            float xx2 = fminf(wb.w, bj.w);
            float inter = fmaxf(yy2 - yy1, 0.f) * fmaxf(xx2 - xx1, 0.f);
            float denom = a1 + a2r[s] - inter + 1e-9f;
            bool sup = ((double)inter > MID05 * (double)denom) | (j == (int)wi);
            key[s] = sup ? 0ull : key[s];
            unsigned long long ks = key[s];
            if ((s & 3) == 0) n0 = (ks > n0) ? ks : n0;
            else if ((s & 3) == 1) n1 = (ks > n1) ? ks : n1;
            else if ((s & 3) == 2) n2 = (ks > n2) ? ks : n2;
            else n3 = (ks > n3) ? ks : n3;
        }
        n0 = (n1 > n0) ? n1 : n0;
        n2 = (n3 > n2) ? n3 : n2;
        m = (n2 > n0) ? n2 : n0;
        #pragma unroll
        for (int off = 32; off > 0; off >>= 1) {
            unsigned long long o = __shfl_xor(m, off);
            m = (o > m) ? o : m;
        }
    }
}

// ============================================================
// Kernel 4: per-batch global top-100 = bitonic sort of 2048 u64 keys.
// ============================================================
__global__ __launch_bounds__(256) void final_sort_kernel(
        const float* __restrict__ nms_score, const int* __restrict__ nms_idx,
        const float* __restrict__ boxes_all, float* __restrict__ out) {
    int b = blockIdx.x, t = threadIdx.x;
    __shared__ unsigned long long sk[2048];    // 16384 B

    for (int f = t; f < 2048; f += 256) {
        unsigned long long kk = 0ull;
        if (f < 2000) {
            float s = nms_score[(size_t)b * 2000 + f];
            float v = isfinite(s) ? s : -1.0f;
            kk = ((unsigned long long)orderable(v) << 32)
               | (unsigned long long)(0xFFFFFFFFu - (unsigned int)f);
        }
        sk[f] = kk;
    }
    __syncthreads();

    for (int k2 = 2; k2 <= 2048; k2 <<= 1) {
        for (int j2 = k2 >> 1; j2 > 0; j2 >>= 1) {
            for (int i = t; i < 2048; i += 256) {
                int l = i ^ j2;
                if (l > i) {
                    bool asc = ((i & k2) == 0);
                    unsigned long long a = sk[i], bb2 = sk[l];
                    if ((a > bb2) == asc) { sk[i] = bb2; sk[l] = a; }
                }
            }
            __syncthreads();
        }
    }

    if (t < TOPK) {
        unsigned long long kk = sk[2047 - t];      // t-th largest
        float v = unorderable((unsigned int)(kk >> 32));
        int fi = (int)(0xFFFFFFFFu - (unsigned int)kk);
        float* o = out + ((size_t)b * TOPK + t) * 6;
        if (v > 0.3f) {
            int bidx = nms_idx[(size_t)b * 2000 + fi];
            float4 bxw = ((const float4*)boxes_all)[(size_t)b * NTOT + bidx];
            o[0] = bxw.x; o[1] = bxw.y; o[2] = bxw.z; o[3] = bxw.w;
            o[4] = v; o[5] = (float)(fi / TOPK);
        } else {
            o[0] = 0.f; o[1] = 0.f; o[2] = 0.f; o[3] = 0.f; o[4] = 0.f; o[5] = 0.f;
        }
    }
}

extern "C" void kernel_launch(void* const* d_in, const int* in_sizes, int n_in,
                              void* d_out, int out_size, void* d_ws, size_t ws_size,
                              hipStream_t stream) {
    (void)out_size; (void)ws_size;
    const float* cls[3] = {nullptr, nullptr, nullptr};
    const float* bbx[3] = {nullptr, nullptr, nullptr};
    for (int i = 0; i < n_in; ++i) {
        const float* p = (const float*)d_in[i];
        switch (in_sizes[i]) {
            case 16 * 6400 * 20: cls[0] = p; break;
            case 16 * 6400 * 32: bbx[0] = p; break;
            case 16 * 1600 * 20: cls[1] = p; break;
            case 16 * 1600 * 32: bbx[1] = p; break;
            case 16 *  400 * 20: cls[2] = p; break;
            case 16 *  400 * 32: bbx[2] = p; break;
            default: break;  // origin_shapes (unused by reference)
        }
    }

    char* w = (char*)d_ws;
    int*   sel_idx    = (int*)(w);                       // 128000 B used
    float* boxes_all  = (float*)(w + 131072);            // 614400 B
    float* scores_t   = (float*)(w + 745472);            // 3072000 B
    unsigned int* keys0 = (unsigned int*)(w + 745472);           // aliased (dies pre-decode)
    unsigned int* keys1 = (unsigned int*)(w + 745472 + 409600);
    float* nms_score  = (float*)(w + 3817472);           // 128000 B
    int*   nms_idx    = (int*)(w + 3945472);             // 128000 B -> total 4073472 B

    hipLaunchKernelGGL(compute_keys_kernel, dim3((BATCH * (N0 + N1) + 255) / 256), dim3(256), 0, stream,
                       cls[0], cls[1], keys0, keys1);
    hipLaunchKernelGGL(radix_select_kernel, dim3(32), dim3(256), 0, stream,
                       keys0, keys1, sel_idx);
    hipLaunchKernelGGL(decode_kernel, dim3((BATCH * NTOT + 255) / 256), dim3(256), 0, stream,
                       cls[0], cls[1], cls[2], bbx[0], bbx[1], bbx[2],
                       sel_idx, boxes_all, scores_t);
    hipLaunchKernelGGL(nms_wave_iou_kernel, dim3(BATCH * NCLS), dim3(64), 0, stream,
                       boxes_all, scores_t, nms_score, nms_idx);
    hipLaunchKernelGGL(final_sort_kernel, dim3(BATCH), dim3(256), 0, stream,
                       nms_score, nms_idx, boxes_all, (float*)d_out);
}

// Round 7
// 418.760 us; speedup vs baseline: 1.2005x; 1.0199x over previous
//
#include <hip/hip_runtime.h>
#include <math.h>

#define BATCH 16
#define NCLS 20
#define TOPK 100
#define NPRE 1000
#define NTOT 2400
#define NBINS 8
#define N0 6400
#define N1 1600
#define NSLOT 38         // 64 lanes x 38 slots = 2432 >= 2400

// Exact replication of RN(inter/denom) > 0.5f for positive finite floats:
// RN(x) > 0.5 <=> x > 0.5 + 2^-25 (midpoint; tie-to-even rounds DOWN to 0.5).
// (double)denom * MID is exact (24+26 = 50 significand bits < 53).
#define MID05 0.50000002980232238769531250

// ---- order-preserving float->uint map (ascending) ----
__device__ __forceinline__ unsigned int orderable(float x) {
    unsigned int u = __float_as_uint(x);
    return (u & 0x80000000u) ? ~u : (u | 0x80000000u);
}
__device__ __forceinline__ float unorderable(unsigned int k) {
    return __uint_as_float((k & 0x80000000u) ? (k ^ 0x80000000u) : ~k);
}

// ============================================================
// Kernel 0: per-anchor key = orderable(max_c logit).
// ============================================================
__global__ __launch_bounds__(256) void compute_keys_kernel(
        const float* __restrict__ cls0, const float* __restrict__ cls1,
        unsigned int* __restrict__ keys0, unsigned int* __restrict__ keys1) {
    int tg = blockIdx.x * 256 + threadIdx.x;
    const float* p;
    unsigned int* dst;
    if (tg < BATCH * N0) {
        p = cls0 + (size_t)tg * NCLS;
        dst = keys0 + tg;
    } else {
        int a = tg - BATCH * N0;
        if (a >= BATCH * N1) return;
        p = cls1 + (size_t)a * NCLS;
        dst = keys1 + a;
    }
    const float4* p4 = (const float4*)p;
    float m = -INFINITY;
    #pragma unroll
    for (int q = 0; q < 5; ++q) {
        float4 v = p4[q];
        m = fmaxf(m, fmaxf(fmaxf(v.x, v.y), fmaxf(v.z, v.w)));
    }
    *dst = orderable(m);
}

// ============================================================
// Kernel 1: per (batch, level) exact top-1000 radix select.
// ============================================================
__global__ __launch_bounds__(256) void radix_select_kernel(
        const unsigned int* __restrict__ keys0, const unsigned int* __restrict__ keys1,
        int* __restrict__ sel_idx) {
    int bid = blockIdx.x;            // 0..31
    int b = bid >> 1;
    int lvl = bid & 1;
    int n = (lvl == 0) ? N0 : N1;
    const unsigned int* gk = (lvl == 0 ? keys0 : keys1) + (size_t)b * n;

    __shared__ unsigned int skey[N0];
    __shared__ unsigned int hist[256];
    __shared__ unsigned int sfxA[257], sfxB[257];
    __shared__ int eq[256];
    __shared__ unsigned int s_prefix, s_kk, s_cnt, s_eqcnt;
    int t = threadIdx.x;

    for (int a = t; a < n; a += 256) skey[a] = gk[a];
    if (t == 0) {
        s_kk = NPRE; s_prefix = 0u; s_cnt = 0u; s_eqcnt = 0u;
        sfxA[256] = 0u; sfxB[256] = 0u;
    }
    __syncthreads();

    for (int pass = 0; pass < 4; ++pass) {
        int shift = 24 - 8 * pass;
        hist[t] = 0u;
        __syncthreads();
        unsigned int prefix = s_prefix, kk = s_kk;
        for (int a = t; a < n; a += 256) {
            unsigned int u = skey[a];
            if (pass == 0 || (u >> (shift + 8)) == prefix)
                atomicAdd(&hist[(u >> shift) & 255u], 1u);
        }
        __syncthreads();
        sfxA[t] = hist[t];
        __syncthreads();
        unsigned int* src = sfxA; unsigned int* dst = sfxB;
        #pragma unroll
        for (int step = 1; step < 256; step <<= 1) {
            int idx = t + step; if (idx > 256) idx = 256;
            dst[t] = src[t] + src[idx];
            __syncthreads();
            unsigned int* tmp = src; src = dst; dst = tmp;
        }
        unsigned int Sd = src[t];
        unsigned int Sd1 = src[t + 1];
        if (Sd >= kk && Sd1 < kk) {
            s_prefix = (prefix << 8) | (unsigned int)t;
            s_kk = kk - Sd1;
        }
        __syncthreads();
    }

    unsigned int T = s_prefix;
    int* out = sel_idx + b * 2000 + lvl * 1000;
    for (int a = t; a < n; a += 256) {
        unsigned int u = skey[a];
        if (u > T) {
            unsigned int pos = atomicAdd(&s_cnt, 1u);
            out[pos] = a;
        } else if (u == T) {
            unsigned int p = atomicAdd(&s_eqcnt, 1u);
            if (p < 256u) eq[p] = a;
        }
    }
    __syncthreads();
    if (t == 0) {
        unsigned int pos = s_cnt;
        unsigned int rem = s_kk;
        unsigned int cnt = s_eqcnt;
        if (cnt <= 256u) {
            for (unsigned int i = 1; i < cnt; ++i) {
                int key = eq[i]; int j2 = (int)i - 1;
                while (j2 >= 0 && eq[j2] > key) { eq[j2 + 1] = eq[j2]; --j2; }
                eq[j2 + 1] = key;
            }
            for (unsigned int i = 0; i < rem; ++i) out[pos + i] = eq[i];
        } else {
            for (int a = 0; a < n && rem > 0u; ++a)
                if (skey[a] == T) { out[pos++] = a; --rem; }
        }
    }
}

// ============================================================
// Kernel 2: decode scores (sigmoid, transposed [b][c][j]) + DFL boxes.
// ============================================================
__global__ __launch_bounds__(256) void decode_kernel(
        const float* __restrict__ cls0, const float* __restrict__ cls1, const float* __restrict__ cls2,
        const float* __restrict__ bb0,  const float* __restrict__ bb1,  const float* __restrict__ bb2,
        const int* __restrict__ sel_idx,
        float* __restrict__ boxes_all, float* __restrict__ scores_t) {
    int tg = blockIdx.x * blockDim.x + threadIdx.x;
    if (tg >= BATCH * NTOT) return;
    int b = tg / NTOT, j = tg % NTOT;

    const float* cls; const float* bb; int a, w; float stride;
    if (j < 1000) {
        a = sel_idx[b * 2000 + j]; w = 80; stride = 8.f;
        cls = cls0 + ((size_t)b * N0 + a) * NCLS;
        bb  = bb0  + ((size_t)b * N0 + a) * 32;
    } else if (j < 2000) {
        a = sel_idx[b * 2000 + j]; w = 40; stride = 16.f;
        cls = cls1 + ((size_t)b * N1 + a) * NCLS;
        bb  = bb1  + ((size_t)b * N1 + a) * 32;
    } else {
        a = j - 2000; w = 20; stride = 32.f;
        cls = cls2 + ((size_t)b * 400 + a) * NCLS;
        bb  = bb2  + ((size_t)b * 400 + a) * 32;
    }

    float cl[20];
    {
        const float4* c4 = (const float4*)cls;
        #pragma unroll
        for (int q = 0; q < 5; ++q) *(float4*)&cl[q * 4] = c4[q];
    }
    float bl[32];
    {
        const float4* b4 = (const float4*)bb;
        #pragma unroll
        for (int q = 0; q < 8; ++q) *(float4*)&bl[q * 4] = b4[q];
    }

    #pragma unroll
    for (int c = 0; c < NCLS; ++c)
        scores_t[((size_t)b * NCLS + c) * NTOT + j] = 1.f / (1.f + expf(-cl[c]));

    float d[4];
    #pragma unroll
    for (int s = 0; s < 4; ++s) {
        const float* l = &bl[s * NBINS];
        float m = l[0];
        #pragma unroll
        for (int k = 1; k < NBINS; ++k) m = fmaxf(m, l[k]);
        float e[NBINS], sum = 0.f;
        #pragma unroll
        for (int k = 0; k < NBINS; ++k) { e[k] = expf(l[k] - m); sum += e[k]; }
        float acc = 0.f;
        #pragma unroll
        for (int k = 0; k < NBINS; ++k) acc += (e[k] / sum) * (float)k;
        d[s] = acc * stride;
    }
    float cy = ((float)(a / w) + 0.5f) * stride;
    float cx = ((float)(a % w) + 0.5f) * stride;
    float* bx = boxes_all + ((size_t)b * NTOT + j) * 4;
    bx[0] = fminf(fmaxf(cy - d[0], 0.f), 640.f);   // y1
    bx[1] = fminf(fmaxf(cx - d[1], 0.f), 640.f);   // x1
    bx[2] = fminf(fmaxf(cy + d[2], 0.f), 640.f);   // y2
    bx[3] = fminf(fmaxf(cx + d[3], 0.f), 640.f);   // x2
}

// ============================================================
// Kernel 3: greedy NMS, ONE WAVE per (batch, class).
// ALL per-slot state (boxes, areas, score keys) in REGISTERS —
// ~228 VGPRs, allowed by __launch_bounds__(64,1) (512/wave budget).
// LDS holds one box copy only for the winner broadcast (1 ds_read
// per iteration). Zero global memory and zero per-slot LDS in the
// 100-iteration serial chain -> pure VALU issue-bound.
// u64 sort key built inline: (orderable(score)<<32) | ~j. Scores are
// sigmoid>0 so live keys have the top bit set; all-dead <=> top bit
// clear (no sentinel cndmask needed). Tie -> lowest j, exact.
// ============================================================
__global__ __launch_bounds__(64, 1) void nms_wave_reg_kernel(
        const float* __restrict__ boxes_all, const float* __restrict__ scores_t,
        float* __restrict__ nms_score, int* __restrict__ nms_idx) {
    int blk = blockIdx.x;
    int b = blk / NCLS, c = blk % NCLS;
    int lane = threadIdx.x;
    __shared__ float4 sbox[NTOT];          // 38400 B (winner broadcast only)

    const float4* bsrc = (const float4*)boxes_all + (size_t)b * NTOT;
    const float*  ssrc = scores_t + ((size_t)b * NCLS + c) * NTOT;

    float4       bx[NSLOT];       // 152 VGPR
    float        a2r[NSLOT];      //  38 VGPR
    unsigned int key[NSLOT];      //  38 VGPR; 0 = dead
    #pragma unroll
    for (int s = 0; s < NSLOT; ++s) {
        int j = lane + 64 * s;
        if (j < NTOT) {
            float4 bj = bsrc[j];              // coalesced
            sbox[j] = bj;
            bx[s] = bj;
            a2r[s] = (bj.z - bj.x) * (bj.w - bj.y);
            key[s] = orderable(ssrc[j]);      // >= 0x80000000 (score > 0)
        } else {
            bx[s] = make_float4(0.f, 0.f, 0.f, 0.f);
            a2r[s] = 0.f;
            key[s] = 0u;
        }
    }
    __syncthreads();   // single wave: just an LDS drain

    float* osc = nms_score + ((size_t)b * NCLS + c) * TOPK;
    int*   oid = nms_idx   + ((size_t)b * NCLS + c) * TOPK;

    // initial max (4 independent chains, then butterfly)
    unsigned long long m;
    {
        unsigned long long m0 = 0, m1 = 0, m2 = 0, m3 = 0;
        #pragma unroll
        for (int s = 0; s < NSLOT; ++s) {
            int j = lane + 64 * s;
            unsigned long long kk = ((unsigned long long)key[s] << 32)
                                  | (unsigned int)~j;
            if ((s & 3) == 0)      m0 = (kk > m0) ? kk : m0;
            else if ((s & 3) == 1) m1 = (kk > m1) ? kk : m1;
            else if ((s & 3) == 2) m2 = (kk > m2) ? kk : m2;
            else                   m3 = (kk > m3) ? kk : m3;
        }
        m0 = (m1 > m0) ? m1 : m0;
        m2 = (m3 > m2) ? m3 : m2;
        m = (m2 > m0) ? m2 : m0;
        #pragma unroll
        for (int off = 32; off > 0; off >>= 1) {
            unsigned long long o = __shfl_xor(m, off);
            m = (o > m) ? o : m;
        }
    }

    for (int k = 0; k < TOPK; ++k) {
        if ((long long)m >= 0) {   // top bit clear: all live keys gone
            for (int k2 = k + lane; k2 < TOPK; k2 += 64) { osc[k2] = -INFINITY; oid[k2] = 0; }
            break;
        }
        unsigned int wi = ~(unsigned int)m;       // recover winner j
        if (lane == 0) { osc[k] = unorderable((unsigned int)(m >> 32)); oid[k] = (int)wi; }
        if (k == TOPK - 1) break;

        float4 wb = sbox[wi];                     // one LDS broadcast b128
        float a1 = (wb.z - wb.x) * (wb.w - wb.y);

        unsigned long long n0 = 0, n1 = 0, n2 = 0, n3 = 0;
        #pragma unroll
        for (int s = 0; s < NSLOT; ++s) {
            int j = lane + 64 * s;
            float4 bj = bx[s];                    // registers
            float yy1 = fmaxf(wb.x, bj.x);
            float xx1 = fmaxf(wb.y, bj.y);
            float yy2 = fminf(wb.z, bj.z);
            float xx2 = fminf(wb.w, bj.w);
            float inter = fmaxf(yy2 - yy1, 0.f) * fmaxf(xx2 - xx1, 0.f);
            float denom = a1 + a2r[s] - inter + 1e-9f;
            bool sup = ((double)inter > MID05 * (double)denom) || (j == (int)wi);
            key[s] = sup ? 0u : key[s];
            unsigned long long kk = ((unsigned long long)key[s] << 32)
                                  | (unsigned int)~j;
            if ((s & 3) == 0)      n0 = (kk > n0) ? kk : n0;
            else if ((s & 3) == 1) n1 = (kk > n1) ? kk : n1;
            else if ((s & 3) == 2) n2 = (kk > n2) ? kk : n2;
            else                   n3 = (kk > n3) ? kk : n3;
        }
        n0 = (n1 > n0) ? n1 : n0;
        n2 = (n3 > n2) ? n3 : n2;
        m = (n2 > n0) ? n2 : n0;
        #pragma unroll
        for (int off = 32; off > 0; off >>= 1) {
            unsigned long long o = __shfl_xor(m, off);
            m = (o > m) ? o : m;
        }
    }
}

// ============================================================
// Kernel 4: per-batch global top-100 = bitonic sort of 2048 u64 keys.
// ============================================================
__global__ __launch_bounds__(256) void final_sort_kernel(
        const float* __restrict__ nms_score, const int* __restrict__ nms_idx,
        const float* __restrict__ boxes_all, float* __restrict__ out) {
    int b = blockIdx.x, t = threadIdx.x;
    __shared__ unsigned long long sk[2048];    // 16384 B

    for (int f = t; f < 2048; f += 256) {
        unsigned long long kk = 0ull;
        if (f < 2000) {
            float s = nms_score[(size_t)b * 2000 + f];
            float v = isfinite(s) ? s : -1.0f;
            kk = ((unsigned long long)orderable(v) << 32)
               | (unsigned long long)(0xFFFFFFFFu - (unsigned int)f);
        }
        sk[f] = kk;
    }
    __syncthreads();

    for (int k2 = 2; k2 <= 2048; k2 <<= 1) {
        for (int j2 = k2 >> 1; j2 > 0; j2 >>= 1) {
            for (int i = t; i < 2048; i += 256) {
                int l = i ^ j2;
                if (l > i) {
                    bool asc = ((i & k2) == 0);
                    unsigned long long a = sk[i], bb2 = sk[l];
                    if ((a > bb2) == asc) { sk[i] = bb2; sk[l] = a; }
                }
            }
            __syncthreads();
        }
    }

    if (t < TOPK) {
        unsigned long long kk = sk[2047 - t];      // t-th largest
        float v = unorderable((unsigned int)(kk >> 32));
        int fi = (int)(0xFFFFFFFFu - (unsigned int)kk);
        float* o = out + ((size_t)b * TOPK + t) * 6;
        if (v > 0.3f) {
            int bidx = nms_idx[(size_t)b * 2000 + fi];
            float4 bxw = ((const float4*)boxes_all)[(size_t)b * NTOT + bidx];
            o[0] = bxw.x; o[1] = bxw.y; o[2] = bxw.z; o[3] = bxw.w;
            o[4] = v; o[5] = (float)(fi / TOPK);
        } else {
            o[0] = 0.f; o[1] = 0.f; o[2] = 0.f; o[3] = 0.f; o[4] = 0.f; o[5] = 0.f;
        }
    }
}

extern "C" void kernel_launch(void* const* d_in, const int* in_sizes, int n_in,
                              void* d_out, int out_size, void* d_ws, size_t ws_size,
                              hipStream_t stream) {
    (void)out_size; (void)ws_size;
    const float* cls[3] = {nullptr, nullptr, nullptr};
    const float* bbx[3] = {nullptr, nullptr, nullptr};
    for (int i = 0; i < n_in; ++i) {
        const float* p = (const float*)d_in[i];
        switch (in_sizes[i]) {
            case 16 * 6400 * 20: cls[0] = p; break;
            case 16 * 6400 * 32: bbx[0] = p; break;
            case 16 * 1600 * 20: cls[1] = p; break;
            case 16 * 1600 * 32: bbx[1] = p; break;
            case 16 *  400 * 20: cls[2] = p; break;
            case 16 *  400 * 32: bbx[2] = p; break;
            default: break;  // origin_shapes (unused by reference)
        }
    }

    char* w = (char*)d_ws;
    int*   sel_idx    = (int*)(w);                       // 128000 B used
    float* boxes_all  = (float*)(w + 131072);            // 614400 B
    float* scores_t   = (float*)(w + 745472);            // 3072000 B
    unsigned int* keys0 = (unsigned int*)(w + 745472);           // aliased (dies pre-decode)
    unsigned int* keys1 = (unsigned int*)(w + 745472 + 409600);
    float* nms_score  = (float*)(w + 3817472);           // 128000 B
    int*   nms_idx    = (int*)(w + 3945472);             // 128000 B -> total 4073472 B

    hipLaunchKernelGGL(compute_keys_kernel, dim3((BATCH * (N0 + N1) + 255) / 256), dim3(256), 0, stream,
                       cls[0], cls[1], keys0, keys1);
    hipLaunchKernelGGL(radix_select_kernel, dim3(32), dim3(256), 0, stream,
                       keys0, keys1, sel_idx);
    hipLaunchKernelGGL(decode_kernel, dim3((BATCH * NTOT + 255) / 256), dim3(256), 0, stream,
                       cls[0], cls[1], cls[2], bbx[0], bbx[1], bbx[2],
                       sel_idx, boxes_all, scores_t);
    hipLaunchKernelGGL(nms_wave_reg_kernel, dim3(BATCH * NCLS), dim3(64), 0, stream,
                       boxes_all, scores_t, nms_score, nms_idx);
    hipLaunchKernelGGL(final_sort_kernel, dim3(BATCH), dim3(256), 0, stream,
                       nms_score, nms_idx, boxes_all, (float*)d_out);
}

// Round 8
// 328.255 us; speedup vs baseline: 1.5315x; 1.2757x over previous
//
#include <hip/hip_runtime.h>
#include <math.h>

#define BATCH 16
#define NCLS 20
#define TOPK 100
#define NPRE 1000
#define NTOT 2400
#define NBINS 8
#define N0 6400
#define N1 1600
#define NCHUNK 38        // 38 chunks x 64 = 2432 >= 2400
#define SORTN 4096       // bitonic pad

// Exact replication of RN(inter/denom) > 0.5f for positive finite floats:
// RN(x) > 0.5 <=> x > 0.5 + 2^-25 (midpoint; tie-to-even rounds DOWN to 0.5).
// (double)denom * MID05 is exact (24+26 = 50 significand bits < 53).
#define MID05 0.50000002980232238769531250

// ---- order-preserving float->uint map (ascending) ----
__device__ __forceinline__ unsigned int orderable(float x) {
    unsigned int u = __float_as_uint(x);
    return (u & 0x80000000u) ? ~u : (u | 0x80000000u);
}
__device__ __forceinline__ float unorderable(unsigned int k) {
    return __uint_as_float((k & 0x80000000u) ? (k ^ 0x80000000u) : ~k);
}

// ============================================================
// Kernel 0: per-anchor key = orderable(max_c logit).
// ============================================================
__global__ __launch_bounds__(256) void compute_keys_kernel(
        const float* __restrict__ cls0, const float* __restrict__ cls1,
        unsigned int* __restrict__ keys0, unsigned int* __restrict__ keys1) {
    int tg = blockIdx.x * 256 + threadIdx.x;
    const float* p;
    unsigned int* dst;
    if (tg < BATCH * N0) {
        p = cls0 + (size_t)tg * NCLS;
        dst = keys0 + tg;
    } else {
        int a = tg - BATCH * N0;
        if (a >= BATCH * N1) return;
        p = cls1 + (size_t)a * NCLS;
        dst = keys1 + a;
    }
    const float4* p4 = (const float4*)p;
    float m = -INFINITY;
    #pragma unroll
    for (int q = 0; q < 5; ++q) {
        float4 v = p4[q];
        m = fmaxf(m, fmaxf(fmaxf(v.x, v.y), fmaxf(v.z, v.w)));
    }
    *dst = orderable(m);
}

// ============================================================
// Kernel 1: per (batch, level) exact top-1000 radix select.
// ============================================================
__global__ __launch_bounds__(256) void radix_select_kernel(
        const unsigned int* __restrict__ keys0, const unsigned int* __restrict__ keys1,
        int* __restrict__ sel_idx) {
    int bid = blockIdx.x;            // 0..31
    int b = bid >> 1;
    int lvl = bid & 1;
    int n = (lvl == 0) ? N0 : N1;
    const unsigned int* gk = (lvl == 0 ? keys0 : keys1) + (size_t)b * n;

    __shared__ unsigned int skey[N0];
    __shared__ unsigned int hist[256];
    __shared__ unsigned int sfxA[257], sfxB[257];
    __shared__ int eq[256];
    __shared__ unsigned int s_prefix, s_kk, s_cnt, s_eqcnt;
    int t = threadIdx.x;

    for (int a = t; a < n; a += 256) skey[a] = gk[a];
    if (t == 0) {
        s_kk = NPRE; s_prefix = 0u; s_cnt = 0u; s_eqcnt = 0u;
        sfxA[256] = 0u; sfxB[256] = 0u;
    }
    __syncthreads();

    for (int pass = 0; pass < 4; ++pass) {
        int shift = 24 - 8 * pass;
        hist[t] = 0u;
        __syncthreads();
        unsigned int prefix = s_prefix, kk = s_kk;
        for (int a = t; a < n; a += 256) {
            unsigned int u = skey[a];
            if (pass == 0 || (u >> (shift + 8)) == prefix)
                atomicAdd(&hist[(u >> shift) & 255u], 1u);
        }
        __syncthreads();
        sfxA[t] = hist[t];
        __syncthreads();
        unsigned int* src = sfxA; unsigned int* dst = sfxB;
        #pragma unroll
        for (int step = 1; step < 256; step <<= 1) {
            int idx = t + step; if (idx > 256) idx = 256;
            dst[t] = src[t] + src[idx];
            __syncthreads();
            unsigned int* tmp = src; src = dst; dst = tmp;
        }
        unsigned int Sd = src[t];
        unsigned int Sd1 = src[t + 1];
        if (Sd >= kk && Sd1 < kk) {
            s_prefix = (prefix << 8) | (unsigned int)t;
            s_kk = kk - Sd1;
        }
        __syncthreads();
    }

    unsigned int T = s_prefix;
    int* out = sel_idx + b * 2000 + lvl * 1000;
    for (int a = t; a < n; a += 256) {
        unsigned int u = skey[a];
        if (u > T) {
            unsigned int pos = atomicAdd(&s_cnt, 1u);
            out[pos] = a;
        } else if (u == T) {
            unsigned int p = atomicAdd(&s_eqcnt, 1u);
            if (p < 256u) eq[p] = a;
        }
    }
    __syncthreads();
    if (t == 0) {
        unsigned int pos = s_cnt;
        unsigned int rem = s_kk;
        unsigned int cnt = s_eqcnt;
        if (cnt <= 256u) {
            for (unsigned int i = 1; i < cnt; ++i) {
                int key = eq[i]; int j2 = (int)i - 1;
                while (j2 >= 0 && eq[j2] > key) { eq[j2 + 1] = eq[j2]; --j2; }
                eq[j2 + 1] = key;
            }
            for (unsigned int i = 0; i < rem; ++i) out[pos + i] = eq[i];
        } else {
            for (int a = 0; a < n && rem > 0u; ++a)
                if (skey[a] == T) { out[pos++] = a; --rem; }
        }
    }
}

// ============================================================
// Kernel 2: decode scores (sigmoid, transposed [b][c][j]) + DFL boxes.
// ============================================================
__global__ __launch_bounds__(256) void decode_kernel(
        const float* __restrict__ cls0, const float* __restrict__ cls1, const float* __restrict__ cls2,
        const float* __restrict__ bb0,  const float* __restrict__ bb1,  const float* __restrict__ bb2,
        const int* __restrict__ sel_idx,
        float* __restrict__ boxes_all, float* __restrict__ scores_t) {
    int tg = blockIdx.x * blockDim.x + threadIdx.x;
    if (tg >= BATCH * NTOT) return;
    int b = tg / NTOT, j = tg % NTOT;

    const float* cls; const float* bb; int a, w; float stride;
    if (j < 1000) {
        a = sel_idx[b * 2000 + j]; w = 80; stride = 8.f;
        cls = cls0 + ((size_t)b * N0 + a) * NCLS;
        bb  = bb0  + ((size_t)b * N0 + a) * 32;
    } else if (j < 2000) {
        a = sel_idx[b * 2000 + j]; w = 40; stride = 16.f;
        cls = cls1 + ((size_t)b * N1 + a) * NCLS;
        bb  = bb1  + ((size_t)b * N1 + a) * 32;
    } else {
        a = j - 2000; w = 20; stride = 32.f;
        cls = cls2 + ((size_t)b * 400 + a) * NCLS;
        bb  = bb2  + ((size_t)b * 400 + a) * 32;
    }

    float cl[20];
    {
        const float4* c4 = (const float4*)cls;
        #pragma unroll
        for (int q = 0; q < 5; ++q) *(float4*)&cl[q * 4] = c4[q];
    }
    float bl[32];
    {
        const float4* b4 = (const float4*)bb;
        #pragma unroll
        for (int q = 0; q < 8; ++q) *(float4*)&bl[q * 4] = b4[q];
    }

    #pragma unroll
    for (int c = 0; c < NCLS; ++c)
        scores_t[((size_t)b * NCLS + c) * NTOT + j] = 1.f / (1.f + expf(-cl[c]));

    float d[4];
    #pragma unroll
    for (int s = 0; s < 4; ++s) {
        const float* l = &bl[s * NBINS];
        float m = l[0];
        #pragma unroll
        for (int k = 1; k < NBINS; ++k) m = fmaxf(m, l[k]);
        float e[NBINS], sum = 0.f;
        #pragma unroll
        for (int k = 0; k < NBINS; ++k) { e[k] = expf(l[k] - m); sum += e[k]; }
        float acc = 0.f;
        #pragma unroll
        for (int k = 0; k < NBINS; ++k) acc += (e[k] / sum) * (float)k;
        d[s] = acc * stride;
    }
    float cy = ((float)(a / w) + 0.5f) * stride;
    float cx = ((float)(a % w) + 0.5f) * stride;
    float* bx = boxes_all + ((size_t)b * NTOT + j) * 4;
    bx[0] = fminf(fmaxf(cy - d[0], 0.f), 640.f);   // y1
    bx[1] = fminf(fmaxf(cx - d[1], 0.f), 640.f);   // x1
    bx[2] = fminf(fmaxf(cy + d[2], 0.f), 640.f);   // y2
    bx[3] = fminf(fmaxf(cx + d[3], 0.f), 640.f);   // x2
}

// ============================================================
// Kernel 3a: per (batch,class) full descending sort of the 2400
// score keys (u64: orderable(score)<<32 | ~idx) via in-LDS bitonic.
// Massively parallel — removes the per-iteration argmax entirely.
// ============================================================
__global__ __launch_bounds__(256) void class_sort_kernel(
        const float* __restrict__ scores_t, unsigned long long* __restrict__ sorted) {
    int blk = blockIdx.x;                 // b*NCLS + c
    int t = threadIdx.x;
    __shared__ unsigned long long sk[SORTN];   // 32768 B

    const float* ssrc = scores_t + (size_t)blk * NTOT;
    for (int f = t; f < SORTN; f += 256) {
        unsigned long long kk = 0ull;
        if (f < NTOT)
            kk = ((unsigned long long)orderable(ssrc[f]) << 32)
               | (unsigned long long)(unsigned int)~f;
        sk[f] = kk;
    }
    __syncthreads();

    for (int k2 = 2; k2 <= SORTN; k2 <<= 1) {
        for (int j2 = k2 >> 1; j2 > 0; j2 >>= 1) {
            for (int i = t; i < SORTN; i += 256) {
                int l = i ^ j2;
                if (l > i) {
                    bool asc = ((i & k2) == 0);
                    unsigned long long a = sk[i], bb2 = sk[l];
                    if ((a > bb2) == asc) { sk[i] = bb2; sk[l] = a; }
                }
            }
            __syncthreads();
        }
    }

    // write top 2432 in DESCENDING order (coalesced)
    unsigned long long* dst = sorted + (size_t)blk * (NCHUNK * 64);
    for (int i = t; i < NCHUNK * 64; i += 256) dst[i] = sk[SORTN - 1 - i];
}

// ============================================================
// Kernel 3b: chunked greedy NMS, ONE WAVE per (batch, class).
// Exact greedy semantics: process candidates in (score desc, idx asc)
// order; accept iff not suppressed by an earlier-ACCEPTED box.
// Per 64-candidate chunk: suppression vs accepted list (LDS broadcast)
// + 64x64 in-chunk bitmask + ballot-loop resolution (~1 ballot per
// accepted). Typical random data: ~2 chunks total instead of 100
// serial argmax iterations. Worst case 38 chunks (still bounded).
// ============================================================
__global__ __launch_bounds__(64) void nms_chunk_kernel(
        const float* __restrict__ boxes_all, const unsigned long long* __restrict__ sorted,
        float* __restrict__ nms_score, int* __restrict__ nms_idx) {
    int blk = blockIdx.x;
    int b = blk / NCLS;
    int lane = threadIdx.x;
    __shared__ float4 abox[TOPK];     // accepted boxes, indexed by output pos
    __shared__ float4 cbox[64];       // current chunk boxes

    const float4* bsrc = (const float4*)boxes_all + (size_t)b * NTOT;
    const unsigned long long* skeys = sorted + (size_t)blk * (NCHUNK * 64);
    float* osc = nms_score + (size_t)blk * TOPK;
    int*   oid = nms_idx   + (size_t)blk * TOPK;

    int outPos = 0;
    for (int chunk = 0; chunk < NCHUNK && outPos < TOPK; ++chunk) {
        unsigned long long key = skeys[chunk * 64 + lane];   // coalesced
        bool live = (key != 0ull);                            // padding = 0
        unsigned int j = ~(unsigned int)key;
        float sc = unorderable((unsigned int)(key >> 32));
        float4 bj = live ? bsrc[j] : make_float4(0.f, 0.f, 0.f, 0.f);
        cbox[lane] = bj;
        float amine = (bj.z - bj.x) * (bj.w - bj.y);

        // suppression vs accepted-so-far (LDS broadcast loop)
        bool sup = !live;
        for (int t2 = 0; t2 < outPos; ++t2) {
            float4 wb = abox[t2];
            float a1 = (wb.z - wb.x) * (wb.w - wb.y);
            float yy1 = fmaxf(wb.x, bj.x);
            float xx1 = fmaxf(wb.y, bj.y);
            float yy2 = fminf(wb.z, bj.z);
            float xx2 = fminf(wb.w, bj.w);
            float inter = fmaxf(yy2 - yy1, 0.f) * fmaxf(xx2 - xx1, 0.f);
            float denom = a1 + amine - inter + 1e-9f;
            sup = sup || ((double)inter > MID05 * (double)denom);
        }

        // in-chunk suppression bits from earlier (higher-ranked) lanes
        unsigned long long supmask = 0ull;
        #pragma unroll 8
        for (int j2 = 0; j2 < 64; ++j2) {
            float4 wb = cbox[j2];                            // broadcast
            float a1 = (wb.z - wb.x) * (wb.w - wb.y);
            float yy1 = fmaxf(wb.x, bj.x);
            float xx1 = fmaxf(wb.y, bj.y);
            float yy2 = fminf(wb.z, bj.z);
            float xx2 = fminf(wb.w, bj.w);
            float inter = fmaxf(yy2 - yy1, 0.f) * fmaxf(xx2 - xx1, 0.f);
            float denom = a1 + amine - inter + 1e-9f;
            bool s2 = ((double)inter > MID05 * (double)denom);
            if (s2 && j2 < lane) supmask |= (1ull << j2);
        }

        // serial in-chunk resolution: accept lowest remaining candidate,
        // remove everyone it suppresses (one ballot per accepted)
        unsigned long long cand = __ballot(!sup);
        unsigned long long accbits = 0ull;
        while (cand) {
            int i = __builtin_ctzll(cand);
            accbits |= (1ull << i);
            cand &= ~(1ull << i);
            unsigned long long row = __ballot((supmask >> i) & 1ull);
            cand &= ~row;
        }

        int nAcc = (int)__builtin_popcountll(accbits);
        int avail = TOPK - outPos;
        bool mine = (accbits >> lane) & 1ull;
        int myrank = (int)__builtin_popcountll(accbits & ((1ull << lane) - 1ull));
        if (mine && myrank < avail) {
            int pos = outPos + myrank;
            osc[pos] = sc;
            oid[pos] = (int)j;
            abox[pos] = bj;
        }
        outPos += (nAcc < avail) ? nAcc : avail;
        __builtin_amdgcn_s_waitcnt(0);   // drain LDS writes before next chunk reads
    }

    for (int k2 = outPos + lane; k2 < TOPK; k2 += 64) { osc[k2] = -INFINITY; oid[k2] = 0; }
}

// ============================================================
// Kernel 4: per-batch global top-100 = bitonic sort of 2048 u64 keys.
// ============================================================
__global__ __launch_bounds__(256) void final_sort_kernel(
        const float* __restrict__ nms_score, const int* __restrict__ nms_idx,
        const float* __restrict__ boxes_all, float* __restrict__ out) {
    int b = blockIdx.x, t = threadIdx.x;
    __shared__ unsigned long long sk[2048];    // 16384 B

    for (int f = t; f < 2048; f += 256) {
        unsigned long long kk = 0ull;
        if (f < 2000) {
            float s = nms_score[(size_t)b * 2000 + f];
            float v = isfinite(s) ? s : -1.0f;
            kk = ((unsigned long long)orderable(v) << 32)
               | (unsigned long long)(0xFFFFFFFFu - (unsigned int)f);
        }
        sk[f] = kk;
    }
    __syncthreads();

    for (int k2 = 2; k2 <= 2048; k2 <<= 1) {
        for (int j2 = k2 >> 1; j2 > 0; j2 >>= 1) {
            for (int i = t; i < 2048; i += 256) {
                int l = i ^ j2;
                if (l > i) {
                    bool asc = ((i & k2) == 0);
                    unsigned long long a = sk[i], bb2 = sk[l];
                    if ((a > bb2) == asc) { sk[i] = bb2; sk[l] = a; }
                }
            }
            __syncthreads();
        }
    }

    if (t < TOPK) {
        unsigned long long kk = sk[2047 - t];      // t-th largest
        float v = unorderable((unsigned int)(kk >> 32));
        int fi = (int)(0xFFFFFFFFu - (unsigned int)kk);
        float* o = out + ((size_t)b * TOPK + t) * 6;
        if (v > 0.3f) {
            int bidx = nms_idx[(size_t)b * 2000 + fi];
            float4 bxw = ((const float4*)boxes_all)[(size_t)b * NTOT + bidx];
            o[0] = bxw.x; o[1] = bxw.y; o[2] = bxw.z; o[3] = bxw.w;
            o[4] = v; o[5] = (float)(fi / TOPK);
        } else {
            o[0] = 0.f; o[1] = 0.f; o[2] = 0.f; o[3] = 0.f; o[4] = 0.f; o[5] = 0.f;
        }
    }
}

extern "C" void kernel_launch(void* const* d_in, const int* in_sizes, int n_in,
                              void* d_out, int out_size, void* d_ws, size_t ws_size,
                              hipStream_t stream) {
    (void)out_size; (void)ws_size;
    const float* cls[3] = {nullptr, nullptr, nullptr};
    const float* bbx[3] = {nullptr, nullptr, nullptr};
    for (int i = 0; i < n_in; ++i) {
        const float* p = (const float*)d_in[i];
        switch (in_sizes[i]) {
            case 16 * 6400 * 20: cls[0] = p; break;
            case 16 * 6400 * 32: bbx[0] = p; break;
            case 16 * 1600 * 20: cls[1] = p; break;
            case 16 * 1600 * 32: bbx[1] = p; break;
            case 16 *  400 * 20: cls[2] = p; break;
            case 16 *  400 * 32: bbx[2] = p; break;
            default: break;  // origin_shapes (unused by reference)
        }
    }

    char* w = (char*)d_ws;
    int*   sel_idx    = (int*)(w);                       // 128000 B used
    float* boxes_all  = (float*)(w + 131072);            // 614400 B
    float* scores_t   = (float*)(w + 745472);            // 3072000 B
    unsigned int* keys0 = (unsigned int*)(w + 745472);           // aliased (dies pre-decode)
    unsigned int* keys1 = (unsigned int*)(w + 745472 + 409600);
    float* nms_score  = (float*)(w + 3817472);           // 128000 B
    int*   nms_idx    = (int*)(w + 3945472);             // 128000 B
    unsigned long long* sorted = (unsigned long long*)(w + 4073472); // 320*2432*8 = 6225920 B
    // total 10299392 B (ws proven >= 15.7 MB in rounds 4-5)

    hipLaunchKernelGGL(compute_keys_kernel, dim3((BATCH * (N0 + N1) + 255) / 256), dim3(256), 0, stream,
                       cls[0], cls[1], keys0, keys1);
    hipLaunchKernelGGL(radix_select_kernel, dim3(32), dim3(256), 0, stream,
                       keys0, keys1, sel_idx);
    hipLaunchKernelGGL(decode_kernel, dim3((BATCH * NTOT + 255) / 256), dim3(256), 0, stream,
                       cls[0], cls[1], cls[2], bbx[0], bbx[1], bbx[2],
                       sel_idx, boxes_all, scores_t);
    hipLaunchKernelGGL(class_sort_kernel, dim3(BATCH * NCLS), dim3(256), 0, stream,
                       scores_t, sorted);
    hipLaunchKernelGGL(nms_chunk_kernel, dim3(BATCH * NCLS), dim3(64), 0, stream,
                       boxes_all, sorted, nms_score, nms_idx);
    hipLaunchKernelGGL(final_sort_kernel, dim3(BATCH), dim3(256), 0, stream,
                       nms_score, nms_idx, boxes_all, (float*)d_out);
}

// Round 9
// 205.280 us; speedup vs baseline: 2.4490x; 1.5991x over previous
//
#include <hip/hip_runtime.h>
#include <math.h>

#define BATCH 16
#define NCLS 20
#define TOPK 100
#define NPRE 1000
#define NTOT 2400
#define NBINS 8
#define N0 6400
#define N1 1600
#define SSEL 256         // candidates selected+sorted per (b,c); 4 chunks of 64

// Exact replication of RN(inter/denom) > 0.5f for positive finite floats:
// RN(x) > 0.5 <=> x > 0.5 + 2^-25 (midpoint; tie-to-even rounds DOWN to 0.5).
// (double)denom * MID05 is exact (24+26 = 50 significand bits < 53).
#define MID05 0.50000002980232238769531250

// ---- order-preserving float->uint map (ascending) ----
__device__ __forceinline__ unsigned int orderable(float x) {
    unsigned int u = __float_as_uint(x);
    return (u & 0x80000000u) ? ~u : (u | 0x80000000u);
}
__device__ __forceinline__ float unorderable(unsigned int k) {
    return __uint_as_float((k & 0x80000000u) ? (k ^ 0x80000000u) : ~k);
}

// ============================================================
// Kernel 0: per-anchor key = orderable(max_c logit).
// ============================================================
__global__ __launch_bounds__(256) void compute_keys_kernel(
        const float* __restrict__ cls0, const float* __restrict__ cls1,
        unsigned int* __restrict__ keys0, unsigned int* __restrict__ keys1) {
    int tg = blockIdx.x * 256 + threadIdx.x;
    const float* p;
    unsigned int* dst;
    if (tg < BATCH * N0) {
        p = cls0 + (size_t)tg * NCLS;
        dst = keys0 + tg;
    } else {
        int a = tg - BATCH * N0;
        if (a >= BATCH * N1) return;
        p = cls1 + (size_t)a * NCLS;
        dst = keys1 + a;
    }
    const float4* p4 = (const float4*)p;
    float m = -INFINITY;
    #pragma unroll
    for (int q = 0; q < 5; ++q) {
        float4 v = p4[q];
        m = fmaxf(m, fmaxf(fmaxf(v.x, v.y), fmaxf(v.z, v.w)));
    }
    *dst = orderable(m);
}

// ============================================================
// Kernel 1: per (batch, level) exact top-1000 radix select.
// ============================================================
__global__ __launch_bounds__(256) void radix_select_kernel(
        const unsigned int* __restrict__ keys0, const unsigned int* __restrict__ keys1,
        int* __restrict__ sel_idx) {
    int bid = blockIdx.x;            // 0..31
    int b = bid >> 1;
    int lvl = bid & 1;
    int n = (lvl == 0) ? N0 : N1;
    const unsigned int* gk = (lvl == 0 ? keys0 : keys1) + (size_t)b * n;

    __shared__ unsigned int skey[N0];
    __shared__ unsigned int hist[256];
    __shared__ unsigned int sfxA[257], sfxB[257];
    __shared__ int eq[256];
    __shared__ unsigned int s_prefix, s_kk, s_cnt, s_eqcnt;
    int t = threadIdx.x;

    for (int a = t; a < n; a += 256) skey[a] = gk[a];
    if (t == 0) {
        s_kk = NPRE; s_prefix = 0u; s_cnt = 0u; s_eqcnt = 0u;
        sfxA[256] = 0u; sfxB[256] = 0u;
    }
    __syncthreads();

    for (int pass = 0; pass < 4; ++pass) {
        int shift = 24 - 8 * pass;
        hist[t] = 0u;
        __syncthreads();
        unsigned int prefix = s_prefix, kk = s_kk;
        for (int a = t; a < n; a += 256) {
            unsigned int u = skey[a];
            if (pass == 0 || (u >> (shift + 8)) == prefix)
                atomicAdd(&hist[(u >> shift) & 255u], 1u);
        }
        __syncthreads();
        sfxA[t] = hist[t];
        __syncthreads();
        unsigned int* src = sfxA; unsigned int* dst = sfxB;
        #pragma unroll
        for (int step = 1; step < 256; step <<= 1) {
            int idx = t + step; if (idx > 256) idx = 256;
            dst[t] = src[t] + src[idx];
            __syncthreads();
            unsigned int* tmp = src; src = dst; dst = tmp;
        }
        unsigned int Sd = src[t];
        unsigned int Sd1 = src[t + 1];
        if (Sd >= kk && Sd1 < kk) {
            s_prefix = (prefix << 8) | (unsigned int)t;
            s_kk = kk - Sd1;
        }
        __syncthreads();
    }

    unsigned int T = s_prefix;
    int* out = sel_idx + b * 2000 + lvl * 1000;
    for (int a = t; a < n; a += 256) {
        unsigned int u = skey[a];
        if (u > T) {
            unsigned int pos = atomicAdd(&s_cnt, 1u);
            out[pos] = a;
        } else if (u == T) {
            unsigned int p = atomicAdd(&s_eqcnt, 1u);
            if (p < 256u) eq[p] = a;
        }
    }
    __syncthreads();
    if (t == 0) {
        unsigned int pos = s_cnt;
        unsigned int rem = s_kk;
        unsigned int cnt = s_eqcnt;
        if (cnt <= 256u) {
            for (unsigned int i = 1; i < cnt; ++i) {
                int key = eq[i]; int j2 = (int)i - 1;
                while (j2 >= 0 && eq[j2] > key) { eq[j2 + 1] = eq[j2]; --j2; }
                eq[j2 + 1] = key;
            }
            for (unsigned int i = 0; i < rem; ++i) out[pos + i] = eq[i];
        } else {
            for (int a = 0; a < n && rem > 0u; ++a)
                if (skey[a] == T) { out[pos++] = a; --rem; }
        }
    }
}

// ============================================================
// Kernel 2: decode scores (sigmoid, transposed [b][c][j]) + DFL boxes.
// ============================================================
__global__ __launch_bounds__(256) void decode_kernel(
        const float* __restrict__ cls0, const float* __restrict__ cls1, const float* __restrict__ cls2,
        const float* __restrict__ bb0,  const float* __restrict__ bb1,  const float* __restrict__ bb2,
        const int* __restrict__ sel_idx,
        float* __restrict__ boxes_all, float* __restrict__ scores_t) {
    int tg = blockIdx.x * blockDim.x + threadIdx.x;
    if (tg >= BATCH * NTOT) return;
    int b = tg / NTOT, j = tg % NTOT;

    const float* cls; const float* bb; int a, w; float stride;
    if (j < 1000) {
        a = sel_idx[b * 2000 + j]; w = 80; stride = 8.f;
        cls = cls0 + ((size_t)b * N0 + a) * NCLS;
        bb  = bb0  + ((size_t)b * N0 + a) * 32;
    } else if (j < 2000) {
        a = sel_idx[b * 2000 + j]; w = 40; stride = 16.f;
        cls = cls1 + ((size_t)b * N1 + a) * NCLS;
        bb  = bb1  + ((size_t)b * N1 + a) * 32;
    } else {
        a = j - 2000; w = 20; stride = 32.f;
        cls = cls2 + ((size_t)b * 400 + a) * NCLS;
        bb  = bb2  + ((size_t)b * 400 + a) * 32;
    }

    float cl[20];
    {
        const float4* c4 = (const float4*)cls;
        #pragma unroll
        for (int q = 0; q < 5; ++q) *(float4*)&cl[q * 4] = c4[q];
    }
    float bl[32];
    {
        const float4* b4 = (const float4*)bb;
        #pragma unroll
        for (int q = 0; q < 8; ++q) *(float4*)&bl[q * 4] = b4[q];
    }

    #pragma unroll
    for (int c = 0; c < NCLS; ++c)
        scores_t[((size_t)b * NCLS + c) * NTOT + j] = 1.f / (1.f + expf(-cl[c]));

    float d[4];
    #pragma unroll
    for (int s = 0; s < 4; ++s) {
        const float* l = &bl[s * NBINS];
        float m = l[0];
        #pragma unroll
        for (int k = 1; k < NBINS; ++k) m = fmaxf(m, l[k]);
        float e[NBINS], sum = 0.f;
        #pragma unroll
        for (int k = 0; k < NBINS; ++k) { e[k] = expf(l[k] - m); sum += e[k]; }
        float acc = 0.f;
        #pragma unroll
        for (int k = 0; k < NBINS; ++k) acc += (e[k] / sum) * (float)k;
        d[s] = acc * stride;
    }
    float cy = ((float)(a / w) + 0.5f) * stride;
    float cx = ((float)(a % w) + 0.5f) * stride;
    float* bx = boxes_all + ((size_t)b * NTOT + j) * 4;
    bx[0] = fminf(fmaxf(cy - d[0], 0.f), 640.f);   // y1
    bx[1] = fminf(fmaxf(cx - d[1], 0.f), 640.f);   // x1
    bx[2] = fminf(fmaxf(cy + d[2], 0.f), 640.f);   // y2
    bx[3] = fminf(fmaxf(cx + d[3], 0.f), 640.f);   // x2
}

// ============================================================
// Kernel 3: fused per-(batch,class) NMS. One 256-thread block:
//   phase 1: radix-select top-SSEL=256 score keys (exact, with
//            lowest-index tie handling), compact, bitonic-sort 256.
//   phase 2: wave 0 runs chunked greedy (4 chunks of 64, ballot
//            resolution) — exact greedy semantics.
//   phase 3: block-wide serial-argmax fallback if 256 candidates
//            didn't yield 100 accepts (never on random data; exact).
// ============================================================
__global__ __launch_bounds__(256) void class_nms_kernel(
        const float* __restrict__ boxes_all, const float* __restrict__ scores_t,
        float* __restrict__ nms_score, int* __restrict__ nms_idx) {
    int blk = blockIdx.x;                 // b*NCLS + c
    int b = blk / NCLS;
    int t = threadIdx.x;

    __shared__ unsigned int skey[NTOT];          // 9600 B
    __shared__ unsigned int hist[256];
    __shared__ unsigned int sfxA[257], sfxB[257];
    __shared__ int eq[128];
    __shared__ unsigned int s_prefix, s_kk, s_cnt, s_eqcnt;
    __shared__ unsigned long long sorted[SSEL];  // 2048 B
    __shared__ float4 abox[TOPK];                // 1600 B
    __shared__ float4 cbox[64];
    __shared__ int s_outPos;
    __shared__ unsigned long long s_m;

    const float*  ssrc = scores_t + (size_t)blk * NTOT;
    const float4* bsrc = (const float4*)boxes_all + (size_t)b * NTOT;
    float* osc = nms_score + (size_t)blk * TOPK;
    int*   oid = nms_idx   + (size_t)blk * TOPK;

    for (int j = t; j < NTOT; j += 256) skey[j] = orderable(ssrc[j]);
    if (t == 0) {
        s_kk = SSEL; s_prefix = 0u; s_cnt = 0u; s_eqcnt = 0u;
        sfxA[256] = 0u; sfxB[256] = 0u; s_outPos = 0;
    }
    __syncthreads();

    // ---- phase 1a: 4-pass radix select for the SSEL-th largest key ----
    for (int pass = 0; pass < 4; ++pass) {
        int shift = 24 - 8 * pass;
        hist[t] = 0u;
        __syncthreads();
        unsigned int prefix = s_prefix, kk = s_kk;
        for (int j = t; j < NTOT; j += 256) {
            unsigned int u = skey[j];
            if (pass == 0 || (u >> (shift + 8)) == prefix)
                atomicAdd(&hist[(u >> shift) & 255u], 1u);
        }
        __syncthreads();
        sfxA[t] = hist[t];
        __syncthreads();
        unsigned int* src = sfxA; unsigned int* dst = sfxB;
        #pragma unroll
        for (int step = 1; step < 256; step <<= 1) {
            int idx = t + step; if (idx > 256) idx = 256;
            dst[t] = src[t] + src[idx];
            __syncthreads();
            unsigned int* tmp = src; src = dst; dst = tmp;
        }
        unsigned int Sd = src[t];
        unsigned int Sd1 = src[t + 1];
        if (Sd >= kk && Sd1 < kk) {
            s_prefix = (prefix << 8) | (unsigned int)t;
            s_kk = kk - Sd1;
        }
        __syncthreads();
    }

    // ---- phase 1b: compact top-SSEL (ties -> lowest index, exact) ----
    unsigned int T = s_prefix;
    for (int j = t; j < NTOT; j += 256) {
        unsigned int u = skey[j];
        if (u > T) {
            unsigned int pos = atomicAdd(&s_cnt, 1u);
            sorted[pos] = ((unsigned long long)u << 32) | (unsigned int)~j;
        } else if (u == T) {
            unsigned int p = atomicAdd(&s_eqcnt, 1u);
            if (p < 128u) eq[p] = j;
        }
    }
    __syncthreads();
    if (t == 0) {
        unsigned int pos = s_cnt;
        unsigned int rem = s_kk;
        unsigned int cnt = s_eqcnt;
        if (cnt <= 128u) {
            for (unsigned int i = 1; i < cnt; ++i) {
                int key = eq[i]; int j2 = (int)i - 1;
                while (j2 >= 0 && eq[j2] > key) { eq[j2 + 1] = eq[j2]; --j2; }
                eq[j2 + 1] = key;
            }
            for (unsigned int i = 0; i < rem; ++i)
                sorted[pos + i] = ((unsigned long long)T << 32) | (unsigned int)~eq[i];
        } else {
            for (int j = 0; j < NTOT && rem > 0u; ++j)
                if (skey[j] == T) {
                    sorted[pos++] = ((unsigned long long)T << 32) | (unsigned int)~j;
                    --rem;
                }
        }
    }
    __syncthreads();

    // ---- phase 1c: bitonic sort 256 u64 ascending (1 elem/thread) ----
    for (int k2 = 2; k2 <= SSEL; k2 <<= 1) {
        for (int j2 = k2 >> 1; j2 > 0; j2 >>= 1) {
            int l = t ^ j2;
            if (l > t && t < SSEL) {
                bool asc = ((t & k2) == 0);
                unsigned long long a = sorted[t], bb2 = sorted[l];
                if ((a > bb2) == asc) { sorted[t] = bb2; sorted[l] = a; }
            }
            __syncthreads();
        }
    }

    // ---- phase 2: chunked greedy NMS on wave 0 (descending order) ----
    if (t < 64) {
        int lane = t;
        int outPos = 0;
        for (int chunk = 0; chunk < SSEL / 64 && outPos < TOPK; ++chunk) {
            unsigned long long key = sorted[SSEL - 1 - (chunk * 64 + lane)];
            unsigned int j = ~(unsigned int)key;
            float sc = unorderable((unsigned int)(key >> 32));
            float4 bj = bsrc[j];
            cbox[lane] = bj;
            float amine = (bj.z - bj.x) * (bj.w - bj.y);

            // suppression vs accepted-so-far
            bool sup = false;
            for (int t2 = 0; t2 < outPos; ++t2) {
                float4 wb = abox[t2];
                float a1 = (wb.z - wb.x) * (wb.w - wb.y);
                float yy1 = fmaxf(wb.x, bj.x);
                float xx1 = fmaxf(wb.y, bj.y);
                float yy2 = fminf(wb.z, bj.z);
                float xx2 = fminf(wb.w, bj.w);
                float inter = fmaxf(yy2 - yy1, 0.f) * fmaxf(xx2 - xx1, 0.f);
                float denom = a1 + amine - inter + 1e-9f;
                sup = sup || ((double)inter > MID05 * (double)denom);
            }

            // in-chunk suppression bits from earlier (higher-ranked) lanes
            unsigned long long supmask = 0ull;
            #pragma unroll 8
            for (int j2 = 0; j2 < 64; ++j2) {
                float4 wb = cbox[j2];
                float a1 = (wb.z - wb.x) * (wb.w - wb.y);
                float yy1 = fmaxf(wb.x, bj.x);
                float xx1 = fmaxf(wb.y, bj.y);
                float yy2 = fminf(wb.z, bj.z);
                float xx2 = fminf(wb.w, bj.w);
                float inter = fmaxf(yy2 - yy1, 0.f) * fmaxf(xx2 - xx1, 0.f);
                float denom = a1 + amine - inter + 1e-9f;
                bool s2 = ((double)inter > MID05 * (double)denom);
                if (s2 && j2 < lane) supmask |= (1ull << j2);
            }

            // serial in-chunk resolution (one ballot per accepted)
            unsigned long long cand = __ballot(!sup);
            unsigned long long accbits = 0ull;
            while (cand) {
                int i = __builtin_ctzll(cand);
                accbits |= (1ull << i);
                cand &= ~(1ull << i);
                unsigned long long row = __ballot((supmask >> i) & 1ull);
                cand &= ~row;
            }

            int nAcc = (int)__builtin_popcountll(accbits);
            int avail = TOPK - outPos;
            bool mine = (accbits >> lane) & 1ull;
            int myrank = (int)__builtin_popcountll(accbits & ((1ull << lane) - 1ull));
            if (mine && myrank < avail) {
                int pos = outPos + myrank;
                osc[pos] = sc;
                oid[pos] = (int)j;
                abox[pos] = bj;
            }
            outPos += (nAcc < avail) ? nAcc : avail;
            __builtin_amdgcn_s_waitcnt(0);   // drain LDS before next chunk reads
        }
        if (lane == 0) s_outPos = outPos;
    }
    __syncthreads();

    // ---- phase 3: fallback continuation (practically never taken) ----
    int outPos = s_outPos;
    if (outPos < TOPK) {
        // mark consumed (all SSEL sorted candidates) and accepted-suppressed
        if (t < SSEL) skey[~(unsigned int)sorted[t]] = 0u;
        __syncthreads();
        for (int j = t; j < NTOT; j += 256) {
            unsigned int u = skey[j];
            if (!u) continue;
            float4 bj = bsrc[j];
            float amine = (bj.z - bj.x) * (bj.w - bj.y);
            bool sup = false;
            for (int t2 = 0; t2 < outPos; ++t2) {
                float4 wb = abox[t2];
                float a1 = (wb.z - wb.x) * (wb.w - wb.y);
                float yy1 = fmaxf(wb.x, bj.x);
                float xx1 = fmaxf(wb.y, bj.y);
                float yy2 = fminf(wb.z, bj.z);
                float xx2 = fminf(wb.w, bj.w);
                float inter = fmaxf(yy2 - yy1, 0.f) * fmaxf(xx2 - xx1, 0.f);
                float denom = a1 + amine - inter + 1e-9f;
                sup = sup || ((double)inter > MID05 * (double)denom);
            }
            if (sup) skey[j] = 0u;
        }
        __syncthreads();
        while (outPos < TOPK) {
            if (t == 0) s_m = 0ull;
            __syncthreads();
            unsigned long long loc = 0ull;
            for (int j = t; j < NTOT; j += 256) {
                unsigned int u = skey[j];
                if (u) {
                    unsigned long long kk = ((unsigned long long)u << 32) | (unsigned int)~j;
                    loc = (kk > loc) ? kk : loc;
                }
            }
            atomicMax(&s_m, loc);
            __syncthreads();
            unsigned long long m = s_m;
            if ((long long)m >= 0) break;          // nothing live
            unsigned int wi = ~(unsigned int)m;
            float4 wb = bsrc[wi];
            if (t == 0) {
                osc[outPos] = unorderable((unsigned int)(m >> 32));
                oid[outPos] = (int)wi;
                skey[wi] = 0u;
            }
            __syncthreads();
            float a1 = (wb.z - wb.x) * (wb.w - wb.y);
            for (int j = t; j < NTOT; j += 256) {
                unsigned int u = skey[j];
                if (!u) continue;
                float4 bj = bsrc[j];
                float yy1 = fmaxf(wb.x, bj.x);
                float xx1 = fmaxf(wb.y, bj.y);
                float yy2 = fminf(wb.z, bj.z);
                float xx2 = fminf(wb.w, bj.w);
                float inter = fmaxf(yy2 - yy1, 0.f) * fmaxf(xx2 - xx1, 0.f);
                float a2 = (bj.z - bj.x) * (bj.w - bj.y);
                float denom = a1 + a2 - inter + 1e-9f;
                if ((double)inter > MID05 * (double)denom) skey[j] = 0u;
            }
            ++outPos;
            __syncthreads();
        }
    }

    for (int k2 = outPos + t; k2 < TOPK; k2 += 256) { osc[k2] = -INFINITY; oid[k2] = 0; }
}

// ============================================================
// Kernel 4: per-batch global top-100 = bitonic sort of 2048 u64 keys.
// ============================================================
__global__ __launch_bounds__(256) void final_sort_kernel(
        const float* __restrict__ nms_score, const int* __restrict__ nms_idx,
        const float* __restrict__ boxes_all, float* __restrict__ out) {
    int b = blockIdx.x, t = threadIdx.x;
    __shared__ unsigned long long sk[2048];    // 16384 B

    for (int f = t; f < 2048; f += 256) {
        unsigned long long kk = 0ull;
        if (f < 2000) {
            float s = nms_score[(size_t)b * 2000 + f];
            float v = isfinite(s) ? s : -1.0f;
            kk = ((unsigned long long)orderable(v) << 32)
               | (unsigned long long)(0xFFFFFFFFu - (unsigned int)f);
        }
        sk[f] = kk;
    }
    __syncthreads();

    for (int k2 = 2; k2 <= 2048; k2 <<= 1) {
        for (int j2 = k2 >> 1; j2 > 0; j2 >>= 1) {
            for (int i = t; i < 2048; i += 256) {
                int l = i ^ j2;
                if (l > i) {
                    bool asc = ((i & k2) == 0);
                    unsigned long long a = sk[i], bb2 = sk[l];
                    if ((a > bb2) == asc) { sk[i] = bb2; sk[l] = a; }
                }
            }
            __syncthreads();
        }
    }

    if (t < TOPK) {
        unsigned long long kk = sk[2047 - t];      // t-th largest
        float v = unorderable((unsigned int)(kk >> 32));
        int fi = (int)(0xFFFFFFFFu - (unsigned int)kk);
        float* o = out + ((size_t)b * TOPK + t) * 6;
        if (v > 0.3f) {
            int bidx = nms_idx[(size_t)b * 2000 + fi];
            float4 bxw = ((const float4*)boxes_all)[(size_t)b * NTOT + bidx];
            o[0] = bxw.x; o[1] = bxw.y; o[2] = bxw.z; o[3] = bxw.w;
            o[4] = v; o[5] = (float)(fi / TOPK);
        } else {
            o[0] = 0.f; o[1] = 0.f; o[2] = 0.f; o[3] = 0.f; o[4] = 0.f; o[5] = 0.f;
        }
    }
}

extern "C" void kernel_launch(void* const* d_in, const int* in_sizes, int n_in,
                              void* d_out, int out_size, void* d_ws, size_t ws_size,
                              hipStream_t stream) {
    (void)out_size; (void)ws_size;
    const float* cls[3] = {nullptr, nullptr, nullptr};
    const float* bbx[3] = {nullptr, nullptr, nullptr};
    for (int i = 0; i < n_in; ++i) {
        const float* p = (const float*)d_in[i];
        switch (in_sizes[i]) {
            case 16 * 6400 * 20: cls[0] = p; break;
            case 16 * 6400 * 32: bbx[0] = p; break;
            case 16 * 1600 * 20: cls[1] = p; break;
            case 16 * 1600 * 32: bbx[1] = p; break;
            case 16 *  400 * 20: cls[2] = p; break;
            case 16 *  400 * 32: bbx[2] = p; break;
            default: break;  // origin_shapes (unused by reference)
        }
    }

    char* w = (char*)d_ws;
    int*   sel_idx    = (int*)(w);                       // 128000 B used
    float* boxes_all  = (float*)(w + 131072);            // 614400 B
    float* scores_t   = (float*)(w + 745472);            // 3072000 B
    unsigned int* keys0 = (unsigned int*)(w + 745472);           // aliased (dies pre-decode)
    unsigned int* keys1 = (unsigned int*)(w + 745472 + 409600);
    float* nms_score  = (float*)(w + 3817472);           // 128000 B
    int*   nms_idx    = (int*)(w + 3945472);             // 128000 B -> total 4073472 B

    hipLaunchKernelGGL(compute_keys_kernel, dim3((BATCH * (N0 + N1) + 255) / 256), dim3(256), 0, stream,
                       cls[0], cls[1], keys0, keys1);
    hipLaunchKernelGGL(radix_select_kernel, dim3(32), dim3(256), 0, stream,
                       keys0, keys1, sel_idx);
    hipLaunchKernelGGL(decode_kernel, dim3((BATCH * NTOT + 255) / 256), dim3(256), 0, stream,
                       cls[0], cls[1], cls[2], bbx[0], bbx[1], bbx[2],
                       sel_idx, boxes_all, scores_t);
    hipLaunchKernelGGL(class_nms_kernel, dim3(BATCH * NCLS), dim3(256), 0, stream,
                       boxes_all, scores_t, nms_score, nms_idx);
    hipLaunchKernelGGL(final_sort_kernel, dim3(BATCH), dim3(256), 0, stream,
                       nms_score, nms_idx, boxes_all, (float*)d_out);
}

// Round 10
// 156.168 us; speedup vs baseline: 3.2192x; 1.3145x over previous
//
#include <hip/hip_runtime.h>
#include <math.h>

#define BATCH 16
#define NCLS 20
#define TOPK 100
#define NPRE 1000
#define NTOT 2400
#define NBINS 8
#define N0 6400
#define N1 1600
#define SSEL 256         // candidates selected+sorted per (b,c); 4 chunks of 64

// Exact replication of RN(inter/denom) > 0.5f for positive finite floats:
// RN(x) > 0.5 <=> x > 0.5 + 2^-25 (midpoint; tie-to-even rounds DOWN to 0.5).
// (double)denom * MID05 is exact (24+26 = 50 significand bits < 53).
#define MID05 0.50000002980232238769531250

// ---- order-preserving float->uint map (ascending) ----
__device__ __forceinline__ unsigned int orderable(float x) {
    unsigned int u = __float_as_uint(x);
    return (u & 0x80000000u) ? ~u : (u | 0x80000000u);
}
__device__ __forceinline__ float unorderable(unsigned int k) {
    return __uint_as_float((k & 0x80000000u) ? (k ^ 0x80000000u) : ~k);
}

// ============================================================
// Kernel 0: per-anchor key = orderable(max_c logit).
// ============================================================
__global__ __launch_bounds__(256) void compute_keys_kernel(
        const float* __restrict__ cls0, const float* __restrict__ cls1,
        unsigned int* __restrict__ keys0, unsigned int* __restrict__ keys1) {
    int tg = blockIdx.x * 256 + threadIdx.x;
    const float* p;
    unsigned int* dst;
    if (tg < BATCH * N0) {
        p = cls0 + (size_t)tg * NCLS;
        dst = keys0 + tg;
    } else {
        int a = tg - BATCH * N0;
        if (a >= BATCH * N1) return;
        p = cls1 + (size_t)a * NCLS;
        dst = keys1 + a;
    }
    const float4* p4 = (const float4*)p;
    float m = -INFINITY;
    #pragma unroll
    for (int q = 0; q < 5; ++q) {
        float4 v = p4[q];
        m = fmaxf(m, fmaxf(fmaxf(v.x, v.y), fmaxf(v.z, v.w)));
    }
    *dst = orderable(m);
}

// ============================================================
// Kernel 1: per (batch, level) exact top-1000 radix select.
// ============================================================
__global__ __launch_bounds__(256) void radix_select_kernel(
        const unsigned int* __restrict__ keys0, const unsigned int* __restrict__ keys1,
        int* __restrict__ sel_idx) {
    int bid = blockIdx.x;            // 0..31
    int b = bid >> 1;
    int lvl = bid & 1;
    int n = (lvl == 0) ? N0 : N1;
    const unsigned int* gk = (lvl == 0 ? keys0 : keys1) + (size_t)b * n;

    __shared__ unsigned int skey[N0];
    __shared__ unsigned int hist[256];
    __shared__ unsigned int sfxA[257], sfxB[257];
    __shared__ int eq[256];
    __shared__ unsigned int s_prefix, s_kk, s_cnt, s_eqcnt;
    int t = threadIdx.x;

    for (int a = t; a < n; a += 256) skey[a] = gk[a];
    if (t == 0) {
        s_kk = NPRE; s_prefix = 0u; s_cnt = 0u; s_eqcnt = 0u;
        sfxA[256] = 0u; sfxB[256] = 0u;
    }
    __syncthreads();

    for (int pass = 0; pass < 4; ++pass) {
        int shift = 24 - 8 * pass;
        hist[t] = 0u;
        __syncthreads();
        unsigned int prefix = s_prefix, kk = s_kk;
        for (int a = t; a < n; a += 256) {
            unsigned int u = skey[a];
            if (pass == 0 || (u >> (shift + 8)) == prefix)
                atomicAdd(&hist[(u >> shift) & 255u], 1u);
        }
        __syncthreads();
        sfxA[t] = hist[t];
        __syncthreads();
        unsigned int* src = sfxA; unsigned int* dst = sfxB;
        #pragma unroll
        for (int step = 1; step < 256; step <<= 1) {
            int idx = t + step; if (idx > 256) idx = 256;
            dst[t] = src[t] + src[idx];
            __syncthreads();
            unsigned int* tmp = src; src = dst; dst = tmp;
        }
        unsigned int Sd = src[t];
        unsigned int Sd1 = src[t + 1];
        if (Sd >= kk && Sd1 < kk) {
            s_prefix = (prefix << 8) | (unsigned int)t;
            s_kk = kk - Sd1;
        }
        __syncthreads();
    }

    unsigned int T = s_prefix;
    int* out = sel_idx + b * 2000 + lvl * 1000;
    for (int a = t; a < n; a += 256) {
        unsigned int u = skey[a];
        if (u > T) {
            unsigned int pos = atomicAdd(&s_cnt, 1u);
            out[pos] = a;
        } else if (u == T) {
            unsigned int p = atomicAdd(&s_eqcnt, 1u);
            if (p < 256u) eq[p] = a;
        }
    }
    __syncthreads();
    if (t == 0) {
        unsigned int pos = s_cnt;
        unsigned int rem = s_kk;
        unsigned int cnt = s_eqcnt;
        if (cnt <= 256u) {
            for (unsigned int i = 1; i < cnt; ++i) {
                int key = eq[i]; int j2 = (int)i - 1;
                while (j2 >= 0 && eq[j2] > key) { eq[j2 + 1] = eq[j2]; --j2; }
                eq[j2 + 1] = key;
            }
            for (unsigned int i = 0; i < rem; ++i) out[pos + i] = eq[i];
        } else {
            for (int a = 0; a < n && rem > 0u; ++a)
                if (skey[a] == T) { out[pos++] = a; --rem; }
        }
    }
}

// ============================================================
// Kernel 2: decode scores (sigmoid, transposed [b][c][j]) + DFL boxes.
// ============================================================
__global__ __launch_bounds__(256) void decode_kernel(
        const float* __restrict__ cls0, const float* __restrict__ cls1, const float* __restrict__ cls2,
        const float* __restrict__ bb0,  const float* __restrict__ bb1,  const float* __restrict__ bb2,
        const int* __restrict__ sel_idx,
        float* __restrict__ boxes_all, float* __restrict__ scores_t) {
    int tg = blockIdx.x * blockDim.x + threadIdx.x;
    if (tg >= BATCH * NTOT) return;
    int b = tg / NTOT, j = tg % NTOT;

    const float* cls; const float* bb; int a, w; float stride;
    if (j < 1000) {
        a = sel_idx[b * 2000 + j]; w = 80; stride = 8.f;
        cls = cls0 + ((size_t)b * N0 + a) * NCLS;
        bb  = bb0  + ((size_t)b * N0 + a) * 32;
    } else if (j < 2000) {
        a = sel_idx[b * 2000 + j]; w = 40; stride = 16.f;
        cls = cls1 + ((size_t)b * N1 + a) * NCLS;
        bb  = bb1  + ((size_t)b * N1 + a) * 32;
    } else {
        a = j - 2000; w = 20; stride = 32.f;
        cls = cls2 + ((size_t)b * 400 + a) * NCLS;
        bb  = bb2  + ((size_t)b * 400 + a) * 32;
    }

    float cl[20];
    {
        const float4* c4 = (const float4*)cls;
        #pragma unroll
        for (int q = 0; q < 5; ++q) *(float4*)&cl[q * 4] = c4[q];
    }
    float bl[32];
    {
        const float4* b4 = (const float4*)bb;
        #pragma unroll
        for (int q = 0; q < 8; ++q) *(float4*)&bl[q * 4] = b4[q];
    }

    #pragma unroll
    for (int c = 0; c < NCLS; ++c)
        scores_t[((size_t)b * NCLS + c) * NTOT + j] = 1.f / (1.f + expf(-cl[c]));

    float d[4];
    #pragma unroll
    for (int s = 0; s < 4; ++s) {
        const float* l = &bl[s * NBINS];
        float m = l[0];
        #pragma unroll
        for (int k = 1; k < NBINS; ++k) m = fmaxf(m, l[k]);
        float e[NBINS], sum = 0.f;
        #pragma unroll
        for (int k = 0; k < NBINS; ++k) { e[k] = expf(l[k] - m); sum += e[k]; }
        float acc = 0.f;
        #pragma unroll
        for (int k = 0; k < NBINS; ++k) acc += (e[k] / sum) * (float)k;
        d[s] = acc * stride;
    }
    float cy = ((float)(a / w) + 0.5f) * stride;
    float cx = ((float)(a % w) + 0.5f) * stride;
    float* bx = boxes_all + ((size_t)b * NTOT + j) * 4;
    bx[0] = fminf(fmaxf(cy - d[0], 0.f), 640.f);   // y1
    bx[1] = fminf(fmaxf(cx - d[1], 0.f), 640.f);   // x1
    bx[2] = fminf(fmaxf(cy + d[2], 0.f), 640.f);   // y2
    bx[3] = fminf(fmaxf(cx + d[3], 0.f), 640.f);   // x2
}

// ============================================================
// Kernel 3: fused per-(batch,class) NMS (select 256 -> sort -> chunked
// greedy; exact fallback). Unchanged from round 9 (verified).
// ============================================================
__global__ __launch_bounds__(256) void class_nms_kernel(
        const float* __restrict__ boxes_all, const float* __restrict__ scores_t,
        float* __restrict__ nms_score, int* __restrict__ nms_idx) {
    int blk = blockIdx.x;                 // b*NCLS + c
    int b = blk / NCLS;
    int t = threadIdx.x;

    __shared__ unsigned int skey[NTOT];          // 9600 B
    __shared__ unsigned int hist[256];
    __shared__ unsigned int sfxA[257], sfxB[257];
    __shared__ int eq[128];
    __shared__ unsigned int s_prefix, s_kk, s_cnt, s_eqcnt;
    __shared__ unsigned long long sorted[SSEL];  // 2048 B
    __shared__ float4 abox[TOPK];                // 1600 B
    __shared__ float4 cbox[64];
    __shared__ int s_outPos;
    __shared__ unsigned long long s_m;

    const float*  ssrc = scores_t + (size_t)blk * NTOT;
    const float4* bsrc = (const float4*)boxes_all + (size_t)b * NTOT;
    float* osc = nms_score + (size_t)blk * TOPK;
    int*   oid = nms_idx   + (size_t)blk * TOPK;

    for (int j = t; j < NTOT; j += 256) skey[j] = orderable(ssrc[j]);
    if (t == 0) {
        s_kk = SSEL; s_prefix = 0u; s_cnt = 0u; s_eqcnt = 0u;
        sfxA[256] = 0u; sfxB[256] = 0u; s_outPos = 0;
    }
    __syncthreads();

    // ---- phase 1a: 4-pass radix select for the SSEL-th largest key ----
    for (int pass = 0; pass < 4; ++pass) {
        int shift = 24 - 8 * pass;
        hist[t] = 0u;
        __syncthreads();
        unsigned int prefix = s_prefix, kk = s_kk;
        for (int j = t; j < NTOT; j += 256) {
            unsigned int u = skey[j];
            if (pass == 0 || (u >> (shift + 8)) == prefix)
                atomicAdd(&hist[(u >> shift) & 255u], 1u);
        }
        __syncthreads();
        sfxA[t] = hist[t];
        __syncthreads();
        unsigned int* src = sfxA; unsigned int* dst = sfxB;
        #pragma unroll
        for (int step = 1; step < 256; step <<= 1) {
            int idx = t + step; if (idx > 256) idx = 256;
            dst[t] = src[t] + src[idx];
            __syncthreads();
            unsigned int* tmp = src; src = dst; dst = tmp;
        }
        unsigned int Sd = src[t];
        unsigned int Sd1 = src[t + 1];
        if (Sd >= kk && Sd1 < kk) {
            s_prefix = (prefix << 8) | (unsigned int)t;
            s_kk = kk - Sd1;
        }
        __syncthreads();
    }

    // ---- phase 1b: compact top-SSEL (ties -> lowest index, exact) ----
    unsigned int T = s_prefix;
    for (int j = t; j < NTOT; j += 256) {
        unsigned int u = skey[j];
        if (u > T) {
            unsigned int pos = atomicAdd(&s_cnt, 1u);
            sorted[pos] = ((unsigned long long)u << 32) | (unsigned int)~j;
        } else if (u == T) {
            unsigned int p = atomicAdd(&s_eqcnt, 1u);
            if (p < 128u) eq[p] = j;
        }
    }
    __syncthreads();
    if (t == 0) {
        unsigned int pos = s_cnt;
        unsigned int rem = s_kk;
        unsigned int cnt = s_eqcnt;
        if (cnt <= 128u) {
            for (unsigned int i = 1; i < cnt; ++i) {
                int key = eq[i]; int j2 = (int)i - 1;
                while (j2 >= 0 && eq[j2] > key) { eq[j2 + 1] = eq[j2]; --j2; }
                eq[j2 + 1] = key;
            }
            for (unsigned int i = 0; i < rem; ++i)
                sorted[pos + i] = ((unsigned long long)T << 32) | (unsigned int)~eq[i];
        } else {
            for (int j = 0; j < NTOT && rem > 0u; ++j)
                if (skey[j] == T) {
                    sorted[pos++] = ((unsigned long long)T << 32) | (unsigned int)~j;
                    --rem;
                }
        }
    }
    __syncthreads();

    // ---- phase 1c: bitonic sort 256 u64 ascending (1 elem/thread) ----
    for (int k2 = 2; k2 <= SSEL; k2 <<= 1) {
        for (int j2 = k2 >> 1; j2 > 0; j2 >>= 1) {
            int l = t ^ j2;
            if (l > t && t < SSEL) {
                bool asc = ((t & k2) == 0);
                unsigned long long a = sorted[t], bb2 = sorted[l];
                if ((a > bb2) == asc) { sorted[t] = bb2; sorted[l] = a; }
            }
            __syncthreads();
        }
    }

    // ---- phase 2: chunked greedy NMS on wave 0 (descending order) ----
    if (t < 64) {
        int lane = t;
        int outPos = 0;
        for (int chunk = 0; chunk < SSEL / 64 && outPos < TOPK; ++chunk) {
            unsigned long long key = sorted[SSEL - 1 - (chunk * 64 + lane)];
            unsigned int j = ~(unsigned int)key;
            float sc = unorderable((unsigned int)(key >> 32));
            float4 bj = bsrc[j];
            cbox[lane] = bj;
            float amine = (bj.z - bj.x) * (bj.w - bj.y);

            // suppression vs accepted-so-far
            bool sup = false;
            for (int t2 = 0; t2 < outPos; ++t2) {
                float4 wb = abox[t2];
                float a1 = (wb.z - wb.x) * (wb.w - wb.y);
                float yy1 = fmaxf(wb.x, bj.x);
                float xx1 = fmaxf(wb.y, bj.y);
                float yy2 = fminf(wb.z, bj.z);
                float xx2 = fminf(wb.w, bj.w);
                float inter = fmaxf(yy2 - yy1, 0.f) * fmaxf(xx2 - xx1, 0.f);
                float denom = a1 + amine - inter + 1e-9f;
                sup = sup || ((double)inter > MID05 * (double)denom);
            }

            // in-chunk suppression bits from earlier (higher-ranked) lanes
            unsigned long long supmask = 0ull;
            #pragma unroll 8
            for (int j2 = 0; j2 < 64; ++j2) {
                float4 wb = cbox[j2];
                float a1 = (wb.z - wb.x) * (wb.w - wb.y);
                float yy1 = fmaxf(wb.x, bj.x);
                float xx1 = fmaxf(wb.y, bj.y);
                float yy2 = fminf(wb.z, bj.z);
                float xx2 = fminf(wb.w, bj.w);
                float inter = fmaxf(yy2 - yy1, 0.f) * fmaxf(xx2 - xx1, 0.f);
                float denom = a1 + amine - inter + 1e-9f;
                bool s2 = ((double)inter > MID05 * (double)denom);
                if (s2 && j2 < lane) supmask |= (1ull << j2);
            }

            // serial in-chunk resolution (one ballot per accepted)
            unsigned long long cand = __ballot(!sup);
            unsigned long long accbits = 0ull;
            while (cand) {
                int i = __builtin_ctzll(cand);
                accbits |= (1ull << i);
                cand &= ~(1ull << i);
                unsigned long long row = __ballot((supmask >> i) & 1ull);
                cand &= ~row;
            }

            int nAcc = (int)__builtin_popcountll(accbits);
            int avail = TOPK - outPos;
            bool mine = (accbits >> lane) & 1ull;
            int myrank = (int)__builtin_popcountll(accbits & ((1ull << lane) - 1ull));
            if (mine && myrank < avail) {
                int pos = outPos + myrank;
                osc[pos] = sc;
                oid[pos] = (int)j;
                abox[pos] = bj;
            }
            outPos += (nAcc < avail) ? nAcc : avail;
            __builtin_amdgcn_s_waitcnt(0);   // drain LDS before next chunk reads
        }
        if (lane == 0) s_outPos = outPos;
    }
    __syncthreads();

    // ---- phase 3: fallback continuation (practically never taken) ----
    int outPos = s_outPos;
    if (outPos < TOPK) {
        if (t < SSEL) skey[~(unsigned int)sorted[t]] = 0u;
        __syncthreads();
        for (int j = t; j < NTOT; j += 256) {
            unsigned int u = skey[j];
            if (!u) continue;
            float4 bj = bsrc[j];
            float amine = (bj.z - bj.x) * (bj.w - bj.y);
            bool sup = false;
            for (int t2 = 0; t2 < outPos; ++t2) {
                float4 wb = abox[t2];
                float a1 = (wb.z - wb.x) * (wb.w - wb.y);
                float yy1 = fmaxf(wb.x, bj.x);
                float xx1 = fmaxf(wb.y, bj.y);
                float yy2 = fminf(wb.z, bj.z);
                float xx2 = fminf(wb.w, bj.w);
                float inter = fmaxf(yy2 - yy1, 0.f) * fmaxf(xx2 - xx1, 0.f);
                float denom = a1 + amine - inter + 1e-9f;
                sup = sup || ((double)inter > MID05 * (double)denom);
            }
            if (sup) skey[j] = 0u;
        }
        __syncthreads();
        while (outPos < TOPK) {
            if (t == 0) s_m = 0ull;
            __syncthreads();
            unsigned long long loc = 0ull;
            for (int j = t; j < NTOT; j += 256) {
                unsigned int u = skey[j];
                if (u) {
                    unsigned long long kk = ((unsigned long long)u << 32) | (unsigned int)~j;
                    loc = (kk > loc) ? kk : loc;
                }
            }
            atomicMax(&s_m, loc);
            __syncthreads();
            unsigned long long m = s_m;
            if ((long long)m >= 0) break;          // nothing live
            unsigned int wi = ~(unsigned int)m;
            float4 wb = bsrc[wi];
            if (t == 0) {
                osc[outPos] = unorderable((unsigned int)(m >> 32));
                oid[outPos] = (int)wi;
                skey[wi] = 0u;
            }
            __syncthreads();
            float a1 = (wb.z - wb.x) * (wb.w - wb.y);
            for (int j = t; j < NTOT; j += 256) {
                unsigned int u = skey[j];
                if (!u) continue;
                float4 bj = bsrc[j];
                float yy1 = fmaxf(wb.x, bj.x);
                float xx1 = fmaxf(wb.y, bj.y);
                float yy2 = fminf(wb.z, bj.z);
                float xx2 = fminf(wb.w, bj.w);
                float inter = fmaxf(yy2 - yy1, 0.f) * fmaxf(xx2 - xx1, 0.f);
                float a2 = (bj.z - bj.x) * (bj.w - bj.y);
                float denom = a1 + a2 - inter + 1e-9f;
                if ((double)inter > MID05 * (double)denom) skey[j] = 0u;
            }
            ++outPos;
            __syncthreads();
        }
    }

    for (int k2 = outPos + t; k2 < TOPK; k2 += 256) { osc[k2] = -INFINITY; oid[k2] = 0; }
}

// ============================================================
// Kernel 4: per-batch global top-100 via radix-select over 2000
// 32-bit score keys + compact + bitonic sort of only 128 u64 keys
// (exact (score desc, flat-idx asc) order; exact tie handling).
// Replaces the 2048-wide bitonic (66 passes -> 28 tiny passes).
// ============================================================
__global__ __launch_bounds__(256) void final_topk_kernel(
        const float* __restrict__ nms_score, const int* __restrict__ nms_idx,
        const float* __restrict__ boxes_all, float* __restrict__ out) {
    int b = blockIdx.x, t = threadIdx.x;
    __shared__ unsigned int fkey[2000];          // 8000 B
    __shared__ unsigned int hist[256];
    __shared__ unsigned int sfxA[257], sfxB[257];
    __shared__ int eq[128];
    __shared__ unsigned long long fk[128];       // 1024 B
    __shared__ unsigned int s_prefix, s_kk, s_cnt, s_eqcnt;

    for (int f = t; f < 2000; f += 256) {
        float s = nms_score[(size_t)b * 2000 + f];
        float v = isfinite(s) ? s : -1.0f;
        fkey[f] = orderable(v);
    }
    if (t == 0) {
        s_kk = TOPK; s_prefix = 0u; s_cnt = 0u; s_eqcnt = 0u;
        sfxA[256] = 0u; sfxB[256] = 0u;
    }
    if (t < 128) fk[t] = 0ull;
    __syncthreads();

    // ---- 4-pass radix select for the TOPK-th largest key ----
    for (int pass = 0; pass < 4; ++pass) {
        int shift = 24 - 8 * pass;
        hist[t] = 0u;
        __syncthreads();
        unsigned int prefix = s_prefix, kk = s_kk;
        for (int f = t; f < 2000; f += 256) {
            unsigned int u = fkey[f];
            if (pass == 0 || (u >> (shift + 8)) == prefix)
                atomicAdd(&hist[(u >> shift) & 255u], 1u);
        }
        __syncthreads();
        sfxA[t] = hist[t];
        __syncthreads();
        unsigned int* src = sfxA; unsigned int* dst = sfxB;
        #pragma unroll
        for (int step = 1; step < 256; step <<= 1) {
            int idx = t + step; if (idx > 256) idx = 256;
            dst[t] = src[t] + src[idx];
            __syncthreads();
            unsigned int* tmp = src; src = dst; dst = tmp;
        }
        unsigned int Sd = src[t];
        unsigned int Sd1 = src[t + 1];
        if (Sd >= kk && Sd1 < kk) {
            s_prefix = (prefix << 8) | (unsigned int)t;
            s_kk = kk - Sd1;
        }
        __syncthreads();
    }

    // ---- compact the exact top-TOPK as u64 keys (ties -> lowest idx) ----
    unsigned int T = s_prefix;
    for (int f = t; f < 2000; f += 256) {
        unsigned int u = fkey[f];
        if (u > T) {
            unsigned int pos = atomicAdd(&s_cnt, 1u);
            fk[pos] = ((unsigned long long)u << 32) | (unsigned int)~f;
        } else if (u == T) {
            unsigned int p = atomicAdd(&s_eqcnt, 1u);
            if (p < 128u) eq[p] = f;
        }
    }
    __syncthreads();
    if (t == 0) {
        unsigned int pos = s_cnt;                 // == TOPK - s_kk
        unsigned int rem = s_kk;
        unsigned int cnt = s_eqcnt;
        if (cnt <= 128u) {
            for (unsigned int i = 1; i < cnt; ++i) {
                int key = eq[i]; int j2 = (int)i - 1;
                while (j2 >= 0 && eq[j2] > key) { eq[j2 + 1] = eq[j2]; --j2; }
                eq[j2 + 1] = key;
            }
            for (unsigned int i = 0; i < rem; ++i)
                fk[pos + i] = ((unsigned long long)T << 32) | (unsigned int)~eq[i];
        } else {
            for (int f = 0; f < 2000 && rem > 0u; ++f)
                if (fkey[f] == T) {
                    fk[pos++] = ((unsigned long long)T << 32) | (unsigned int)~f;
                    --rem;
                }
        }
    }
    __syncthreads();

    // ---- bitonic sort 128 u64 ascending (zeros sink to front) ----
    for (int k2 = 2; k2 <= 128; k2 <<= 1) {
        for (int j2 = k2 >> 1; j2 > 0; j2 >>= 1) {
            if (t < 128) {
                int l = t ^ j2;
                if (l > t) {
                    bool asc = ((t & k2) == 0);
                    unsigned long long a = fk[t], bb2 = fk[l];
                    if ((a > bb2) == asc) { fk[t] = bb2; fk[l] = a; }
                }
            }
            __syncthreads();
        }
    }

    // ---- emit rows (same masking semantics as verified round-9 code) ----
    if (t < TOPK) {
        unsigned long long kk = fk[127 - t];       // t-th largest
        float v = unorderable((unsigned int)(kk >> 32));
        int fi = (int)~(unsigned int)kk;
        float* o = out + ((size_t)b * TOPK + t) * 6;
        if (v > 0.3f) {
            int bidx = nms_idx[(size_t)b * 2000 + fi];
            float4 bxw = ((const float4*)boxes_all)[(size_t)b * NTOT + bidx];
            o[0] = bxw.x; o[1] = bxw.y; o[2] = bxw.z; o[3] = bxw.w;
            o[4] = v; o[5] = (float)(fi / TOPK);
        } else {
            o[0] = 0.f; o[1] = 0.f; o[2] = 0.f; o[3] = 0.f; o[4] = 0.f; o[5] = 0.f;
        }
    }
}

extern "C" void kernel_launch(void* const* d_in, const int* in_sizes, int n_in,
                              void* d_out, int out_size, void* d_ws, size_t ws_size,
                              hipStream_t stream) {
    (void)out_size; (void)ws_size;
    const float* cls[3] = {nullptr, nullptr, nullptr};
    const float* bbx[3] = {nullptr, nullptr, nullptr};
    for (int i = 0; i < n_in; ++i) {
        const float* p = (const float*)d_in[i];
        switch (in_sizes[i]) {
            case 16 * 6400 * 20: cls[0] = p; break;
            case 16 * 6400 * 32: bbx[0] = p; break;
            case 16 * 1600 * 20: cls[1] = p; break;
            case 16 * 1600 * 32: bbx[1] = p; break;
            case 16 *  400 * 20: cls[2] = p; break;
            case 16 *  400 * 32: bbx[2] = p; break;
            default: break;  // origin_shapes (unused by reference)
        }
    }

    char* w = (char*)d_ws;
    int*   sel_idx    = (int*)(w);                       // 128000 B used
    float* boxes_all  = (float*)(w + 131072);            // 614400 B
    float* scores_t   = (float*)(w + 745472);            // 3072000 B
    unsigned int* keys0 = (unsigned int*)(w + 745472);           // aliased (dies pre-decode)
    unsigned int* keys1 = (unsigned int*)(w + 745472 + 409600);
    float* nms_score  = (float*)(w + 3817472);           // 128000 B
    int*   nms_idx    = (int*)(w + 3945472);             // 128000 B -> total 4073472 B

    hipLaunchKernelGGL(compute_keys_kernel, dim3((BATCH * (N0 + N1) + 255) / 256), dim3(256), 0, stream,
                       cls[0], cls[1], keys0, keys1);
    hipLaunchKernelGGL(radix_select_kernel, dim3(32), dim3(256), 0, stream,
                       keys0, keys1, sel_idx);
    hipLaunchKernelGGL(decode_kernel, dim3((BATCH * NTOT + 255) / 256), dim3(256), 0, stream,
                       cls[0], cls[1], cls[2], bbx[0], bbx[1], bbx[2],
                       sel_idx, boxes_all, scores_t);
    hipLaunchKernelGGL(class_nms_kernel, dim3(BATCH * NCLS), dim3(256), 0, stream,
                       boxes_all, scores_t, nms_score, nms_idx);
    hipLaunchKernelGGL(final_topk_kernel, dim3(BATCH), dim3(256), 0, stream,
                       nms_score, nms_idx, boxes_all, (float*)d_out);
}

// Round 11
// 153.478 us; speedup vs baseline: 3.2756x; 1.0175x over previous
//
#include <hip/hip_runtime.h>
#include <math.h>

#define BATCH 16
#define NCLS 20
#define TOPK 100
#define NPRE 1000
#define NTOT 2400
#define NBINS 8
#define N0 6400
#define N1 1600
#define SSEL 256         // candidates selected+sorted per (b,c); 4 chunks of 64

// Exact replication of RN(inter/denom) > 0.5f for positive finite floats:
// RN(x) > 0.5 <=> x > 0.5 + 2^-25 (midpoint; tie-to-even rounds DOWN to 0.5).
// (double)denom * MID05 is exact (24+26 = 50 significand bits < 53).
#define MID05 0.50000002980232238769531250

// ---- order-preserving float->uint map (ascending) ----
__device__ __forceinline__ unsigned int orderable(float x) {
    unsigned int u = __float_as_uint(x);
    return (u & 0x80000000u) ? ~u : (u | 0x80000000u);
}
__device__ __forceinline__ float unorderable(unsigned int k) {
    return __uint_as_float((k & 0x80000000u) ? (k ^ 0x80000000u) : ~k);
}

// ---- wave-0 suffix-scan digit selection (replaces 8-barrier Hillis-Steele).
// hist[256] ready; lane l owns bins 4l..4l+3. Identical arithmetic to the
// old scan: picks the unique digit d with sfx[d] >= kk > sfx[d+1]. ----
__device__ __forceinline__ void radix_pass_scan(
        const unsigned int* hist, unsigned int* s_prefix, unsigned int* s_kk,
        unsigned int prefix, unsigned int kk, int t) {
    if (t < 64) {
        uint4 h = *(const uint4*)&hist[t * 4];
        unsigned int s3 = h.w;
        unsigned int s2 = h.z + s3;
        unsigned int s1 = h.y + s2;
        unsigned int s0 = h.x + s1;          // lane-local suffix sums
        unsigned int S = s0;
        #pragma unroll
        for (int off = 1; off < 64; off <<= 1) {
            unsigned int o = __shfl_down(S, off);
            S += (t + off < 64) ? o : 0u;
        }
        unsigned int Sgt = S - s0;           // sum over lanes > t
        unsigned int F0 = s0 + Sgt, F1 = s1 + Sgt, F2 = s2 + Sgt, F3 = s3 + Sgt;
        if (F0 >= kk && F1 < kk)  { *s_prefix = (prefix << 8) | (unsigned int)(t * 4 + 0); *s_kk = kk - F1; }
        if (F1 >= kk && F2 < kk)  { *s_prefix = (prefix << 8) | (unsigned int)(t * 4 + 1); *s_kk = kk - F2; }
        if (F2 >= kk && F3 < kk)  { *s_prefix = (prefix << 8) | (unsigned int)(t * 4 + 2); *s_kk = kk - F3; }
        if (F3 >= kk && Sgt < kk) { *s_prefix = (prefix << 8) | (unsigned int)(t * 4 + 3); *s_kk = kk - Sgt; }
    }
}

// ---- bitonic merge strides jmax..1 via shfl_xor (intra-wave, no barriers).
// Same compare network/direction as the LDS version: ascending block iff
// (pos & k2)==0; upper element (bit j set) keeps max in ascending. ----
__device__ __forceinline__ unsigned long long bmerge_shfl(
        unsigned long long v, int t, int k2, int jmax) {
    for (int j2 = jmax; j2 > 0; j2 >>= 1) {
        unsigned long long o = __shfl_xor(v, j2);
        bool km = (((t & k2) == 0) == ((t & j2) != 0));
        v = km ? (v > o ? v : o) : (v < o ? v : o);
    }
    return v;
}

// ============================================================
// Kernel 0: per-anchor key = orderable(max_c logit).
// ============================================================
__global__ __launch_bounds__(256) void compute_keys_kernel(
        const float* __restrict__ cls0, const float* __restrict__ cls1,
        unsigned int* __restrict__ keys0, unsigned int* __restrict__ keys1) {
    int tg = blockIdx.x * 256 + threadIdx.x;
    const float* p;
    unsigned int* dst;
    if (tg < BATCH * N0) {
        p = cls0 + (size_t)tg * NCLS;
        dst = keys0 + tg;
    } else {
        int a = tg - BATCH * N0;
        if (a >= BATCH * N1) return;
        p = cls1 + (size_t)a * NCLS;
        dst = keys1 + a;
    }
    const float4* p4 = (const float4*)p;
    float m = -INFINITY;
    #pragma unroll
    for (int q = 0; q < 5; ++q) {
        float4 v = p4[q];
        m = fmaxf(m, fmaxf(fmaxf(v.x, v.y), fmaxf(v.z, v.w)));
    }
    *dst = orderable(m);
}

// ============================================================
// Kernel 1: per (batch, level) exact top-1000 radix select.
// Scan replaced by wave-0 shfl scan (3 barriers/pass vs 12).
// ============================================================
__global__ __launch_bounds__(256) void radix_select_kernel(
        const unsigned int* __restrict__ keys0, const unsigned int* __restrict__ keys1,
        int* __restrict__ sel_idx) {
    int bid = blockIdx.x;            // 0..31
    int b = bid >> 1;
    int lvl = bid & 1;
    int n = (lvl == 0) ? N0 : N1;
    const unsigned int* gk = (lvl == 0 ? keys0 : keys1) + (size_t)b * n;

    __shared__ unsigned int skey[N0];
    __shared__ __align__(16) unsigned int hist[256];
    __shared__ int eq[256];
    __shared__ unsigned int s_prefix, s_kk, s_cnt, s_eqcnt;
    int t = threadIdx.x;

    for (int a = t; a < n; a += 256) skey[a] = gk[a];
    if (t == 0) { s_kk = NPRE; s_prefix = 0u; s_cnt = 0u; s_eqcnt = 0u; }
    __syncthreads();

    for (int pass = 0; pass < 4; ++pass) {
        int shift = 24 - 8 * pass;
        unsigned int prefix = s_prefix, kk = s_kk;
        hist[t] = 0u;
        __syncthreads();
        for (int a = t; a < n; a += 256) {
            unsigned int u = skey[a];
            if (pass == 0 || (u >> (shift + 8)) == prefix)
                atomicAdd(&hist[(u >> shift) & 255u], 1u);
        }
        __syncthreads();
        radix_pass_scan(hist, &s_prefix, &s_kk, prefix, kk, t);
        __syncthreads();
    }

    unsigned int T = s_prefix;
    int* out = sel_idx + b * 2000 + lvl * 1000;
    for (int a = t; a < n; a += 256) {
        unsigned int u = skey[a];
        if (u > T) {
            unsigned int pos = atomicAdd(&s_cnt, 1u);
            out[pos] = a;
        } else if (u == T) {
            unsigned int p = atomicAdd(&s_eqcnt, 1u);
            if (p < 256u) eq[p] = a;
        }
    }
    __syncthreads();
    if (t == 0) {
        unsigned int pos = s_cnt;
        unsigned int rem = s_kk;
        unsigned int cnt = s_eqcnt;
        if (cnt <= 256u) {
            for (unsigned int i = 1; i < cnt; ++i) {
                int key = eq[i]; int j2 = (int)i - 1;
                while (j2 >= 0 && eq[j2] > key) { eq[j2 + 1] = eq[j2]; --j2; }
                eq[j2 + 1] = key;
            }
            for (unsigned int i = 0; i < rem; ++i) out[pos + i] = eq[i];
        } else {
            for (int a = 0; a < n && rem > 0u; ++a)
                if (skey[a] == T) { out[pos++] = a; --rem; }
        }
    }
}

// ============================================================
// Kernel 2: decode scores (sigmoid, transposed [b][c][j]) + DFL boxes.
// ============================================================
__global__ __launch_bounds__(256) void decode_kernel(
        const float* __restrict__ cls0, const float* __restrict__ cls1, const float* __restrict__ cls2,
        const float* __restrict__ bb0,  const float* __restrict__ bb1,  const float* __restrict__ bb2,
        const int* __restrict__ sel_idx,
        float* __restrict__ boxes_all, float* __restrict__ scores_t) {
    int tg = blockIdx.x * blockDim.x + threadIdx.x;
    if (tg >= BATCH * NTOT) return;
    int b = tg / NTOT, j = tg % NTOT;

    const float* cls; const float* bb; int a, w; float stride;
    if (j < 1000) {
        a = sel_idx[b * 2000 + j]; w = 80; stride = 8.f;
        cls = cls0 + ((size_t)b * N0 + a) * NCLS;
        bb  = bb0  + ((size_t)b * N0 + a) * 32;
    } else if (j < 2000) {
        a = sel_idx[b * 2000 + j]; w = 40; stride = 16.f;
        cls = cls1 + ((size_t)b * N1 + a) * NCLS;
        bb  = bb1  + ((size_t)b * N1 + a) * 32;
    } else {
        a = j - 2000; w = 20; stride = 32.f;
        cls = cls2 + ((size_t)b * 400 + a) * NCLS;
        bb  = bb2  + ((size_t)b * 400 + a) * 32;
    }

    float cl[20];
    {
        const float4* c4 = (const float4*)cls;
        #pragma unroll
        for (int q = 0; q < 5; ++q) *(float4*)&cl[q * 4] = c4[q];
    }
    float bl[32];
    {
        const float4* b4 = (const float4*)bb;
        #pragma unroll
        for (int q = 0; q < 8; ++q) *(float4*)&bl[q * 4] = b4[q];
    }

    #pragma unroll
    for (int c = 0; c < NCLS; ++c)
        scores_t[((size_t)b * NCLS + c) * NTOT + j] = 1.f / (1.f + expf(-cl[c]));

    float d[4];
    #pragma unroll
    for (int s = 0; s < 4; ++s) {
        const float* l = &bl[s * NBINS];
        float m = l[0];
        #pragma unroll
        for (int k = 1; k < NBINS; ++k) m = fmaxf(m, l[k]);
        float e[NBINS], sum = 0.f;
        #pragma unroll
        for (int k = 0; k < NBINS; ++k) { e[k] = expf(l[k] - m); sum += e[k]; }
        float acc = 0.f;
        #pragma unroll
        for (int k = 0; k < NBINS; ++k) acc += (e[k] / sum) * (float)k;
        d[s] = acc * stride;
    }
    float cy = ((float)(a / w) + 0.5f) * stride;
    float cx = ((float)(a % w) + 0.5f) * stride;
    float* bx = boxes_all + ((size_t)b * NTOT + j) * 4;
    bx[0] = fminf(fmaxf(cy - d[0], 0.f), 640.f);   // y1
    bx[1] = fminf(fmaxf(cx - d[1], 0.f), 640.f);   // x1
    bx[2] = fminf(fmaxf(cy + d[2], 0.f), 640.f);   // y2
    bx[3] = fminf(fmaxf(cx + d[3], 0.f), 640.f);   // x2
}

// ============================================================
// Kernel 3: fused per-(batch,class) NMS (select 256 -> sort -> chunked
// greedy; exact fallback). Scan + sort now shfl-based (low-barrier).
// ============================================================
__global__ __launch_bounds__(256) void class_nms_kernel(
        const float* __restrict__ boxes_all, const float* __restrict__ scores_t,
        float* __restrict__ nms_score, int* __restrict__ nms_idx) {
    int blk = blockIdx.x;                 // b*NCLS + c
    int b = blk / NCLS;
    int t = threadIdx.x;

    __shared__ unsigned int skey[NTOT];          // 9600 B
    __shared__ __align__(16) unsigned int hist[256];
    __shared__ int eq[128];
    __shared__ unsigned int s_prefix, s_kk, s_cnt, s_eqcnt;
    __shared__ unsigned long long sorted[SSEL];  // 2048 B
    __shared__ float4 abox[TOPK];                // 1600 B
    __shared__ float4 cbox[64];
    __shared__ int s_outPos;
    __shared__ unsigned long long s_m;

    const float*  ssrc = scores_t + (size_t)blk * NTOT;
    const float4* bsrc = (const float4*)boxes_all + (size_t)b * NTOT;
    float* osc = nms_score + (size_t)blk * TOPK;
    int*   oid = nms_idx   + (size_t)blk * TOPK;

    for (int j = t; j < NTOT; j += 256) skey[j] = orderable(ssrc[j]);
    if (t == 0) { s_kk = SSEL; s_prefix = 0u; s_cnt = 0u; s_eqcnt = 0u; s_outPos = 0; }
    __syncthreads();

    // ---- phase 1a: 4-pass radix select for the SSEL-th largest key ----
    for (int pass = 0; pass < 4; ++pass) {
        int shift = 24 - 8 * pass;
        unsigned int prefix = s_prefix, kk = s_kk;
        hist[t] = 0u;
        __syncthreads();
        for (int j = t; j < NTOT; j += 256) {
            unsigned int u = skey[j];
            if (pass == 0 || (u >> (shift + 8)) == prefix)
                atomicAdd(&hist[(u >> shift) & 255u], 1u);
        }
        __syncthreads();
        radix_pass_scan(hist, &s_prefix, &s_kk, prefix, kk, t);
        __syncthreads();
    }

    // ---- phase 1b: compact top-SSEL (ties -> lowest index, exact) ----
    unsigned int T = s_prefix;
    for (int j = t; j < NTOT; j += 256) {
        unsigned int u = skey[j];
        if (u > T) {
            unsigned int pos = atomicAdd(&s_cnt, 1u);
            sorted[pos] = ((unsigned long long)u << 32) | (unsigned int)~j;
        } else if (u == T) {
            unsigned int p = atomicAdd(&s_eqcnt, 1u);
            if (p < 128u) eq[p] = j;
        }
    }
    __syncthreads();
    if (t == 0) {
        unsigned int pos = s_cnt;
        unsigned int rem = s_kk;
        unsigned int cnt = s_eqcnt;
        if (cnt <= 128u) {
            for (unsigned int i = 1; i < cnt; ++i) {
                int key = eq[i]; int j2 = (int)i - 1;
                while (j2 >= 0 && eq[j2] > key) { eq[j2 + 1] = eq[j2]; --j2; }
                eq[j2 + 1] = key;
            }
            for (unsigned int i = 0; i < rem; ++i)
                sorted[pos + i] = ((unsigned long long)T << 32) | (unsigned int)~eq[i];
        } else {
            for (int j = 0; j < NTOT && rem > 0u; ++j)
                if (skey[j] == T) {
                    sorted[pos++] = ((unsigned long long)T << 32) | (unsigned int)~j;
                    --rem;
                }
        }
    }
    __syncthreads();

    // ---- phase 1c: bitonic sort 256 u64 ascending, shfl-based.
    // Strides <=32 via shfl_xor (no barriers); 64/128 via LDS. ----
    {
        unsigned long long v = sorted[t];
        #pragma unroll
        for (int k2 = 2; k2 <= 64; k2 <<= 1)
            v = bmerge_shfl(v, t, k2, k2 >> 1);
        sorted[t] = v;
        __syncthreads();
        // k2 = 128, j2 = 64
        {
            unsigned long long o = sorted[t ^ 64];
            bool km = (((t & 128) == 0) == ((t & 64) != 0));
            v = km ? (v > o ? v : o) : (v < o ? v : o);
            v = bmerge_shfl(v, t, 128, 32);
        }
        __syncthreads();          // all reads done
        sorted[t] = v;
        __syncthreads();
        // k2 = 256, j2 = 128 (ascending everywhere)
        {
            unsigned long long o = sorted[t ^ 128];
            bool km = ((t & 128) != 0);
            v = km ? (v > o ? v : o) : (v < o ? v : o);
        }
        __syncthreads();
        sorted[t] = v;
        __syncthreads();
        // k2 = 256, j2 = 64, then 32..1 via shfl
        {
            unsigned long long o = sorted[t ^ 64];
            bool km = ((t & 64) != 0);
            v = km ? (v > o ? v : o) : (v < o ? v : o);
            v = bmerge_shfl(v, t, 256, 32);
        }
        __syncthreads();
        sorted[t] = v;
        __syncthreads();
    }

    // ---- phase 2: chunked greedy NMS on wave 0 (descending order) ----
    if (t < 64) {
        int lane = t;
        int outPos = 0;
        for (int chunk = 0; chunk < SSEL / 64 && outPos < TOPK; ++chunk) {
            unsigned long long key = sorted[SSEL - 1 - (chunk * 64 + lane)];
            unsigned int j = ~(unsigned int)key;
            float sc = unorderable((unsigned int)(key >> 32));
            float4 bj = bsrc[j];
            cbox[lane] = bj;
            float amine = (bj.z - bj.x) * (bj.w - bj.y);

            // suppression vs accepted-so-far
            bool sup = false;
            for (int t2 = 0; t2 < outPos; ++t2) {
                float4 wb = abox[t2];
                float a1 = (wb.z - wb.x) * (wb.w - wb.y);
                float yy1 = fmaxf(wb.x, bj.x);
                float xx1 = fmaxf(wb.y, bj.y);
                float yy2 = fminf(wb.z, bj.z);
                float xx2 = fminf(wb.w, bj.w);
                float inter = fmaxf(yy2 - yy1, 0.f) * fmaxf(xx2 - xx1, 0.f);
                float denom = a1 + amine - inter + 1e-9f;
                sup = sup || ((double)inter > MID05 * (double)denom);
            }

            // in-chunk suppression bits from earlier (higher-ranked) lanes
            unsigned long long supmask = 0ull;
            #pragma unroll 8
            for (int j2 = 0; j2 < 64; ++j2) {
                float4 wb = cbox[j2];
                float a1 = (wb.z - wb.x) * (wb.w - wb.y);
                float yy1 = fmaxf(wb.x, bj.x);
                float xx1 = fmaxf(wb.y, bj.y);
                float yy2 = fminf(wb.z, bj.z);
                float xx2 = fminf(wb.w, bj.w);
                float inter = fmaxf(yy2 - yy1, 0.f) * fmaxf(xx2 - xx1, 0.f);
                float denom = a1 + amine - inter + 1e-9f;
                bool s2 = ((double)inter > MID05 * (double)denom);
                if (s2 && j2 < lane) supmask |= (1ull << j2);
            }

            // serial in-chunk resolution (one ballot per accepted)
            unsigned long long cand = __ballot(!sup);
            unsigned long long accbits = 0ull;
            while (cand) {
                int i = __builtin_ctzll(cand);
                accbits |= (1ull << i);
                cand &= ~(1ull << i);
                unsigned long long row = __ballot((supmask >> i) & 1ull);
                cand &= ~row;
            }

            int nAcc = (int)__builtin_popcountll(accbits);
            int avail = TOPK - outPos;
            bool mine = (accbits >> lane) & 1ull;
            int myrank = (int)__builtin_popcountll(accbits & ((1ull << lane) - 1ull));
            if (mine && myrank < avail) {
                int pos = outPos + myrank;
                osc[pos] = sc;
                oid[pos] = (int)j;
                abox[pos] = bj;
            }
            outPos += (nAcc < avail) ? nAcc : avail;
            __builtin_amdgcn_s_waitcnt(0);   // drain LDS before next chunk reads
        }
        if (lane == 0) s_outPos = outPos;
    }
    __syncthreads();

    // ---- phase 3: fallback continuation (practically never taken) ----
    int outPos = s_outPos;
    if (outPos < TOPK) {
        if (t < SSEL) skey[~(unsigned int)sorted[t]] = 0u;
        __syncthreads();
        for (int j = t; j < NTOT; j += 256) {
            unsigned int u = skey[j];
            if (!u) continue;
            float4 bj = bsrc[j];
            float amine = (bj.z - bj.x) * (bj.w - bj.y);
            bool sup = false;
            for (int t2 = 0; t2 < outPos; ++t2) {
                float4 wb = abox[t2];
                float a1 = (wb.z - wb.x) * (wb.w - wb.y);
                float yy1 = fmaxf(wb.x, bj.x);
                float xx1 = fmaxf(wb.y, bj.y);
                float yy2 = fminf(wb.z, bj.z);
                float xx2 = fminf(wb.w, bj.w);
                float inter = fmaxf(yy2 - yy1, 0.f) * fmaxf(xx2 - xx1, 0.f);
                float denom = a1 + amine - inter + 1e-9f;
                sup = sup || ((double)inter > MID05 * (double)denom);
            }
            if (sup) skey[j] = 0u;
        }
        __syncthreads();
        while (outPos < TOPK) {
            if (t == 0) s_m = 0ull;
            __syncthreads();
            unsigned long long loc = 0ull;
            for (int j = t; j < NTOT; j += 256) {
                unsigned int u = skey[j];
                if (u) {
                    unsigned long long kk = ((unsigned long long)u << 32) | (unsigned int)~j;
                    loc = (kk > loc) ? kk : loc;
                }
            }
            atomicMax(&s_m, loc);
            __syncthreads();
            unsigned long long m = s_m;
            if ((long long)m >= 0) break;          // nothing live
            unsigned int wi = ~(unsigned int)m;
            float4 wb = bsrc[wi];
            if (t == 0) {
                osc[outPos] = unorderable((unsigned int)(m >> 32));
                oid[outPos] = (int)wi;
                skey[wi] = 0u;
            }
            __syncthreads();
            float a1 = (wb.z - wb.x) * (wb.w - wb.y);
            for (int j = t; j < NTOT; j += 256) {
                unsigned int u = skey[j];
                if (!u) continue;
                float4 bj = bsrc[j];
                float yy1 = fmaxf(wb.x, bj.x);
                float xx1 = fmaxf(wb.y, bj.y);
                float yy2 = fminf(wb.z, bj.z);
                float xx2 = fminf(wb.w, bj.w);
                float inter = fmaxf(yy2 - yy1, 0.f) * fmaxf(xx2 - xx1, 0.f);
                float a2 = (bj.z - bj.x) * (bj.w - bj.y);
                float denom = a1 + a2 - inter + 1e-9f;
                if ((double)inter > MID05 * (double)denom) skey[j] = 0u;
            }
            ++outPos;
            __syncthreads();
        }
    }

    for (int k2 = outPos + t; k2 < TOPK; k2 += 256) { osc[k2] = -INFINITY; oid[k2] = 0; }
}

// ============================================================
// Kernel 4: per-batch global top-100 via radix-select over 2000
// 32-bit keys + compact + shfl-based bitonic sort of 128 u64 keys.
// ============================================================
__global__ __launch_bounds__(256) void final_topk_kernel(
        const float* __restrict__ nms_score, const int* __restrict__ nms_idx,
        const float* __restrict__ boxes_all, float* __restrict__ out) {
    int b = blockIdx.x, t = threadIdx.x;
    __shared__ unsigned int fkey[2000];          // 8000 B
    __shared__ __align__(16) unsigned int hist[256];
    __shared__ int eq[128];
    __shared__ unsigned long long fk[128];       // 1024 B
    __shared__ unsigned int s_prefix, s_kk, s_cnt, s_eqcnt;

    for (int f = t; f < 2000; f += 256) {
        float s = nms_score[(size_t)b * 2000 + f];
        float v = isfinite(s) ? s : -1.0f;
        fkey[f] = orderable(v);
    }
    if (t == 0) { s_kk = TOPK; s_prefix = 0u; s_cnt = 0u; s_eqcnt = 0u; }
    if (t < 128) fk[t] = 0ull;
    __syncthreads();

    // ---- 4-pass radix select for the TOPK-th largest key ----
    for (int pass = 0; pass < 4; ++pass) {
        int shift = 24 - 8 * pass;
        unsigned int prefix = s_prefix, kk = s_kk;
        hist[t] = 0u;
        __syncthreads();
        for (int f = t; f < 2000; f += 256) {
            unsigned int u = fkey[f];
            if (pass == 0 || (u >> (shift + 8)) == prefix)
                atomicAdd(&hist[(u >> shift) & 255u], 1u);
        }
        __syncthreads();
        radix_pass_scan(hist, &s_prefix, &s_kk, prefix, kk, t);
        __syncthreads();
    }

    // ---- compact the exact top-TOPK as u64 keys (ties -> lowest idx) ----
    unsigned int T = s_prefix;
    for (int f = t; f < 2000; f += 256) {
        unsigned int u = fkey[f];
        if (u > T) {
            unsigned int pos = atomicAdd(&s_cnt, 1u);
            fk[pos] = ((unsigned long long)u << 32) | (unsigned int)~f;
        } else if (u == T) {
            unsigned int p = atomicAdd(&s_eqcnt, 1u);
            if (p < 128u) eq[p] = f;
        }
    }
    __syncthreads();
    if (t == 0) {
        unsigned int pos = s_cnt;                 // == TOPK - s_kk
        unsigned int rem = s_kk;
        unsigned int cnt = s_eqcnt;
        if (cnt <= 128u) {
            for (unsigned int i = 1; i < cnt; ++i) {
                int key = eq[i]; int j2 = (int)i - 1;
                while (j2 >= 0 && eq[j2] > key) { eq[j2 + 1] = eq[j2]; --j2; }
                eq[j2 + 1] = key;
            }
            for (unsigned int i = 0; i < rem; ++i)
                fk[pos + i] = ((unsigned long long)T << 32) | (unsigned int)~eq[i];
        } else {
            for (int f = 0; f < 2000 && rem > 0u; ++f)
                if (fkey[f] == T) {
                    fk[pos++] = ((unsigned long long)T << 32) | (unsigned int)~f;
                    --rem;
                }
        }
    }
    __syncthreads();

    // ---- bitonic sort 128 u64 ascending, shfl-based (zeros sink) ----
    {
        unsigned long long v = (t < 128) ? fk[t] : 0ull;
        if (t < 128) {
            #pragma unroll
            for (int k2 = 2; k2 <= 64; k2 <<= 1)
                v = bmerge_shfl(v, t, k2, k2 >> 1);
            fk[t] = v;
        }
        __syncthreads();
        if (t < 128) {
            unsigned long long o = fk[t ^ 64];    // k2=128 (ascending), j2=64
            bool km = ((t & 64) != 0);
            v = km ? (v > o ? v : o) : (v < o ? v : o);
            v = bmerge_shfl(v, t, 128, 32);
        }
        __syncthreads();
        if (t < 128) fk[t] = v;
        __syncthreads();
    }

    // ---- emit rows (same masking semantics as verified round-10 code) ----
    if (t < TOPK) {
        unsigned long long kk = fk[127 - t];       // t-th largest
        float v = unorderable((unsigned int)(kk >> 32));
        int fi = (int)~(unsigned int)kk;
        float* o = out + ((size_t)b * TOPK + t) * 6;
        if (v > 0.3f) {
            int bidx = nms_idx[(size_t)b * 2000 + fi];
            float4 bxw = ((const float4*)boxes_all)[(size_t)b * NTOT + bidx];
            o[0] = bxw.x; o[1] = bxw.y; o[2] = bxw.z; o[3] = bxw.w;
            o[4] = v; o[5] = (float)(fi / TOPK);
        } else {
            o[0] = 0.f; o[1] = 0.f; o[2] = 0.f; o[3] = 0.f; o[4] = 0.f; o[5] = 0.f;
        }
    }
}

extern "C" void kernel_launch(void* const* d_in, const int* in_sizes, int n_in,
                              void* d_out, int out_size, void* d_ws, size_t ws_size,
                              hipStream_t stream) {
    (void)out_size; (void)ws_size;
    const float* cls[3] = {nullptr, nullptr, nullptr};
    const float* bbx[3] = {nullptr, nullptr, nullptr};
    for (int i = 0; i < n_in; ++i) {
        const float* p = (const float*)d_in[i];
        switch (in_sizes[i]) {
            case 16 * 6400 * 20: cls[0] = p; break;
            case 16 * 6400 * 32: bbx[0] = p; break;
            case 16 * 1600 * 20: cls[1] = p; break;
            case 16 * 1600 * 32: bbx[1] = p; break;
            case 16 *  400 * 20: cls[2] = p; break;
            case 16 *  400 * 32: bbx[2] = p; break;
            default: break;  // origin_shapes (unused by reference)
        }
    }

    char* w = (char*)d_ws;
    int*   sel_idx    = (int*)(w);                       // 128000 B used
    float* boxes_all  = (float*)(w + 131072);            // 614400 B
    float* scores_t   = (float*)(w + 745472);            // 3072000 B
    unsigned int* keys0 = (unsigned int*)(w + 745472);           // aliased (dies pre-decode)
    unsigned int* keys1 = (unsigned int*)(w + 745472 + 409600);
    float* nms_score  = (float*)(w + 3817472);           // 128000 B
    int*   nms_idx    = (int*)(w + 3945472);             // 128000 B -> total 4073472 B

    hipLaunchKernelGGL(compute_keys_kernel, dim3((BATCH * (N0 + N1) + 255) / 256), dim3(256), 0, stream,
                       cls[0], cls[1], keys0, keys1);
    hipLaunchKernelGGL(radix_select_kernel, dim3(32), dim3(256), 0, stream,
                       keys0, keys1, sel_idx);
    hipLaunchKernelGGL(decode_kernel, dim3((BATCH * NTOT + 255) / 256), dim3(256), 0, stream,
                       cls[0], cls[1], cls[2], bbx[0], bbx[1], bbx[2],
                       sel_idx, boxes_all, scores_t);
    hipLaunchKernelGGL(class_nms_kernel, dim3(BATCH * NCLS), dim3(256), 0, stream,
                       boxes_all, scores_t, nms_score, nms_idx);
    hipLaunchKernelGGL(final_topk_kernel, dim3(BATCH), dim3(256), 0, stream,
                       nms_score, nms_idx, boxes_all, (float*)d_out);
}

// Round 12
// 152.897 us; speedup vs baseline: 3.2881x; 1.0038x over previous
//
#include <hip/hip_runtime.h>
#include <math.h>

#define BATCH 16
#define NCLS 20
#define TOPK 100
#define NPRE 1000
#define NTOT 2400
#define NBINS 8
#define N0 6400
#define N1 1600
#define SSEL 256         // candidates selected+sorted per (b,c); 4 chunks of 64

// Exact replication of RN(inter/denom) > 0.5f for positive finite floats:
// RN(x) > 0.5 <=> x > 0.5 + 2^-25 (midpoint; tie-to-even rounds DOWN to 0.5).
// (double)denom * MID05 is exact (24+26 = 50 significand bits < 53).
#define MID05 0.50000002980232238769531250

// ---- order-preserving float->uint map (ascending) ----
__device__ __forceinline__ unsigned int orderable(float x) {
    unsigned int u = __float_as_uint(x);
    return (u & 0x80000000u) ? ~u : (u | 0x80000000u);
}
__device__ __forceinline__ float unorderable(unsigned int k) {
    return __uint_as_float((k & 0x80000000u) ? (k ^ 0x80000000u) : ~k);
}

// ---- wave-0 suffix-scan digit selection. hist[256] ready; lane l owns
// bins 4l..4l+3. Picks the unique digit d with sfx[d] >= kk > sfx[d+1]. ----
__device__ __forceinline__ void radix_pass_scan(
        const unsigned int* hist, unsigned int* s_prefix, unsigned int* s_kk,
        unsigned int prefix, unsigned int kk, int t) {
    if (t < 64) {
        uint4 h = *(const uint4*)&hist[t * 4];
        unsigned int s3 = h.w;
        unsigned int s2 = h.z + s3;
        unsigned int s1 = h.y + s2;
        unsigned int s0 = h.x + s1;          // lane-local suffix sums
        unsigned int S = s0;
        #pragma unroll
        for (int off = 1; off < 64; off <<= 1) {
            unsigned int o = __shfl_down(S, off);
            S += (t + off < 64) ? o : 0u;
        }
        unsigned int Sgt = S - s0;           // sum over lanes > t
        unsigned int F0 = s0 + Sgt, F1 = s1 + Sgt, F2 = s2 + Sgt, F3 = s3 + Sgt;
        if (F0 >= kk && F1 < kk)  { *s_prefix = (prefix << 8) | (unsigned int)(t * 4 + 0); *s_kk = kk - F1; }
        if (F1 >= kk && F2 < kk)  { *s_prefix = (prefix << 8) | (unsigned int)(t * 4 + 1); *s_kk = kk - F2; }
        if (F2 >= kk && F3 < kk)  { *s_prefix = (prefix << 8) | (unsigned int)(t * 4 + 2); *s_kk = kk - F3; }
        if (F3 >= kk && Sgt < kk) { *s_prefix = (prefix << 8) | (unsigned int)(t * 4 + 3); *s_kk = kk - Sgt; }
    }
}

// ---- bitonic merge strides jmax..1 via shfl_xor (intra-wave, no barriers) ----
__device__ __forceinline__ unsigned long long bmerge_shfl(
        unsigned long long v, int t, int k2, int jmax) {
    for (int j2 = jmax; j2 > 0; j2 >>= 1) {
        unsigned long long o = __shfl_xor(v, j2);
        bool km = (((t & k2) == 0) == ((t & j2) != 0));
        v = km ? (v > o ? v : o) : (v < o ? v : o);
    }
    return v;
}

// ============================================================
// Kernel 1: FUSED key-compute + top-1000 radix select.
// One 1024-thread block per (batch, level): keys from cls logits
// (identical fmax expression -> identical bits vs old compute_keys),
// then the verified 4-pass select + compact. Also zeroes the
// per-batch epilogue counters (block 0).
// ============================================================
__global__ __launch_bounds__(1024) void select_keys_kernel(
        const float* __restrict__ cls0, const float* __restrict__ cls1,
        int* __restrict__ sel_idx, int* __restrict__ cnt) {
    int bid = blockIdx.x;            // 0..31
    int b = bid >> 1;
    int lvl = bid & 1;
    int n = (lvl == 0) ? N0 : N1;
    const float* cls = (lvl == 0 ? cls0 : cls1) + (size_t)b * (size_t)n * NCLS;

    __shared__ unsigned int skey[N0];
    __shared__ __align__(16) unsigned int hist[256];
    __shared__ int eq[256];
    __shared__ unsigned int s_prefix, s_kk, s_cnt, s_eqcnt;
    int t = threadIdx.x;

    if (bid == 0 && t < BATCH) cnt[t] = 0;   // visible to class_nms via dispatch ordering

    for (int a = t; a < n; a += 1024) {
        const float4* p4 = (const float4*)(cls + (size_t)a * NCLS);
        float m = -INFINITY;
        #pragma unroll
        for (int q = 0; q < 5; ++q) {
            float4 v = p4[q];
            m = fmaxf(m, fmaxf(fmaxf(v.x, v.y), fmaxf(v.z, v.w)));
        }
        skey[a] = orderable(m);
    }
    if (t == 0) { s_kk = NPRE; s_prefix = 0u; s_cnt = 0u; s_eqcnt = 0u; }
    __syncthreads();

    for (int pass = 0; pass < 4; ++pass) {
        int shift = 24 - 8 * pass;
        unsigned int prefix = s_prefix, kk = s_kk;
        if (t < 256) hist[t] = 0u;
        __syncthreads();
        for (int a = t; a < n; a += 1024) {
            unsigned int u = skey[a];
            if (pass == 0 || (u >> (shift + 8)) == prefix)
                atomicAdd(&hist[(u >> shift) & 255u], 1u);
        }
        __syncthreads();
        radix_pass_scan(hist, &s_prefix, &s_kk, prefix, kk, t);
        __syncthreads();
    }

    unsigned int T = s_prefix;
    int* out = sel_idx + b * 2000 + lvl * 1000;
    for (int a = t; a < n; a += 1024) {
        unsigned int u = skey[a];
        if (u > T) {
            unsigned int pos = atomicAdd(&s_cnt, 1u);
            out[pos] = a;
        } else if (u == T) {
            unsigned int p = atomicAdd(&s_eqcnt, 1u);
            if (p < 256u) eq[p] = a;
        }
    }
    __syncthreads();
    if (t == 0) {
        unsigned int pos = s_cnt;
        unsigned int rem = s_kk;
        unsigned int cnt2 = s_eqcnt;
        if (cnt2 <= 256u) {
            for (unsigned int i = 1; i < cnt2; ++i) {
                int key = eq[i]; int j2 = (int)i - 1;
                while (j2 >= 0 && eq[j2] > key) { eq[j2 + 1] = eq[j2]; --j2; }
                eq[j2 + 1] = key;
            }
            for (unsigned int i = 0; i < rem; ++i) out[pos + i] = eq[i];
        } else {
            for (int a = 0; a < n && rem > 0u; ++a)
                if (skey[a] == T) { out[pos++] = a; --rem; }
        }
    }
}

// ============================================================
// Kernel 2: decode scores (sigmoid, transposed [b][c][j]) + DFL boxes.
// ============================================================
__global__ __launch_bounds__(256) void decode_kernel(
        const float* __restrict__ cls0, const float* __restrict__ cls1, const float* __restrict__ cls2,
        const float* __restrict__ bb0,  const float* __restrict__ bb1,  const float* __restrict__ bb2,
        const int* __restrict__ sel_idx,
        float* __restrict__ boxes_all, float* __restrict__ scores_t) {
    int tg = blockIdx.x * blockDim.x + threadIdx.x;
    if (tg >= BATCH * NTOT) return;
    int b = tg / NTOT, j = tg % NTOT;

    const float* cls; const float* bb; int a, w; float stride;
    if (j < 1000) {
        a = sel_idx[b * 2000 + j]; w = 80; stride = 8.f;
        cls = cls0 + ((size_t)b * N0 + a) * NCLS;
        bb  = bb0  + ((size_t)b * N0 + a) * 32;
    } else if (j < 2000) {
        a = sel_idx[b * 2000 + j]; w = 40; stride = 16.f;
        cls = cls1 + ((size_t)b * N1 + a) * NCLS;
        bb  = bb1  + ((size_t)b * N1 + a) * 32;
    } else {
        a = j - 2000; w = 20; stride = 32.f;
        cls = cls2 + ((size_t)b * 400 + a) * NCLS;
        bb  = bb2  + ((size_t)b * 400 + a) * 32;
    }

    float cl[20];
    {
        const float4* c4 = (const float4*)cls;
        #pragma unroll
        for (int q = 0; q < 5; ++q) *(float4*)&cl[q * 4] = c4[q];
    }
    float bl[32];
    {
        const float4* b4 = (const float4*)bb;
        #pragma unroll
        for (int q = 0; q < 8; ++q) *(float4*)&bl[q * 4] = b4[q];
    }

    #pragma unroll
    for (int c = 0; c < NCLS; ++c)
        scores_t[((size_t)b * NCLS + c) * NTOT + j] = 1.f / (1.f + expf(-cl[c]));

    float d[4];
    #pragma unroll
    for (int s = 0; s < 4; ++s) {
        const float* l = &bl[s * NBINS];
        float m = l[0];
        #pragma unroll
        for (int k = 1; k < NBINS; ++k) m = fmaxf(m, l[k]);
        float e[NBINS], sum = 0.f;
        #pragma unroll
        for (int k = 0; k < NBINS; ++k) { e[k] = expf(l[k] - m); sum += e[k]; }
        float acc = 0.f;
        #pragma unroll
        for (int k = 0; k < NBINS; ++k) acc += (e[k] / sum) * (float)k;
        d[s] = acc * stride;
    }
    float cy = ((float)(a / w) + 0.5f) * stride;
    float cx = ((float)(a % w) + 0.5f) * stride;
    float* bx = boxes_all + ((size_t)b * NTOT + j) * 4;
    bx[0] = fminf(fmaxf(cy - d[0], 0.f), 640.f);   // y1
    bx[1] = fminf(fmaxf(cx - d[1], 0.f), 640.f);   // x1
    bx[2] = fminf(fmaxf(cy + d[2], 0.f), 640.f);   // y2
    bx[3] = fminf(fmaxf(cx + d[3], 0.f), 640.f);   // x2
}

// ============================================================
// Kernel 3: fused per-(batch,class) NMS + last-block-per-batch
// final top-100 epilogue (device-scope atomic + threadfence).
// ============================================================
__global__ __launch_bounds__(256) void class_nms_kernel(
        const float* __restrict__ boxes_all, const float* __restrict__ scores_t,
        float* __restrict__ nms_score, int* __restrict__ nms_idx,
        int* __restrict__ cnt, float* __restrict__ outbuf) {
    int blk = blockIdx.x;                 // b*NCLS + c
    int b = blk / NCLS;
    int t = threadIdx.x;

    __shared__ unsigned int skey[NTOT];          // 9600 B (reused by epilogue)
    __shared__ __align__(16) unsigned int hist[256];
    __shared__ int eq[128];
    __shared__ unsigned int s_prefix, s_kk, s_cnt, s_eqcnt;
    __shared__ unsigned long long sorted[SSEL];  // 2048 B (reused as fk[128])
    __shared__ float4 abox[TOPK];                // 1600 B
    __shared__ float4 cbox[64];
    __shared__ int s_outPos;
    __shared__ unsigned long long s_m;
    __shared__ int s_last;

    const float*  ssrc = scores_t + (size_t)blk * NTOT;
    const float4* bsrc = (const float4*)boxes_all + (size_t)b * NTOT;
    float* osc = nms_score + (size_t)blk * TOPK;
    int*   oid = nms_idx   + (size_t)blk * TOPK;

    for (int j = t; j < NTOT; j += 256) skey[j] = orderable(ssrc[j]);
    if (t == 0) { s_kk = SSEL; s_prefix = 0u; s_cnt = 0u; s_eqcnt = 0u; s_outPos = 0; }
    __syncthreads();

    // ---- phase 1a: 4-pass radix select for the SSEL-th largest key ----
    for (int pass = 0; pass < 4; ++pass) {
        int shift = 24 - 8 * pass;
        unsigned int prefix = s_prefix, kk = s_kk;
        hist[t] = 0u;
        __syncthreads();
        for (int j = t; j < NTOT; j += 256) {
            unsigned int u = skey[j];
            if (pass == 0 || (u >> (shift + 8)) == prefix)
                atomicAdd(&hist[(u >> shift) & 255u], 1u);
        }
        __syncthreads();
        radix_pass_scan(hist, &s_prefix, &s_kk, prefix, kk, t);
        __syncthreads();
    }

    // ---- phase 1b: compact top-SSEL (ties -> lowest index, exact) ----
    unsigned int T = s_prefix;
    for (int j = t; j < NTOT; j += 256) {
        unsigned int u = skey[j];
        if (u > T) {
            unsigned int pos = atomicAdd(&s_cnt, 1u);
            sorted[pos] = ((unsigned long long)u << 32) | (unsigned int)~j;
        } else if (u == T) {
            unsigned int p = atomicAdd(&s_eqcnt, 1u);
            if (p < 128u) eq[p] = j;
        }
    }
    __syncthreads();
    if (t == 0) {
        unsigned int pos = s_cnt;
        unsigned int rem = s_kk;
        unsigned int cnt2 = s_eqcnt;
        if (cnt2 <= 128u) {
            for (unsigned int i = 1; i < cnt2; ++i) {
                int key = eq[i]; int j2 = (int)i - 1;
                while (j2 >= 0 && eq[j2] > key) { eq[j2 + 1] = eq[j2]; --j2; }
                eq[j2 + 1] = key;
            }
            for (unsigned int i = 0; i < rem; ++i)
                sorted[pos + i] = ((unsigned long long)T << 32) | (unsigned int)~eq[i];
        } else {
            for (int j = 0; j < NTOT && rem > 0u; ++j)
                if (skey[j] == T) {
                    sorted[pos++] = ((unsigned long long)T << 32) | (unsigned int)~j;
                    --rem;
                }
        }
    }
    __syncthreads();

    // ---- phase 1c: bitonic sort 256 u64 ascending, shfl-based ----
    {
        unsigned long long v = sorted[t];
        #pragma unroll
        for (int k2 = 2; k2 <= 64; k2 <<= 1)
            v = bmerge_shfl(v, t, k2, k2 >> 1);
        sorted[t] = v;
        __syncthreads();
        {
            unsigned long long o = sorted[t ^ 64];    // k2=128, j2=64
            bool km = (((t & 128) == 0) == ((t & 64) != 0));
            v = km ? (v > o ? v : o) : (v < o ? v : o);
            v = bmerge_shfl(v, t, 128, 32);
        }
        __syncthreads();
        sorted[t] = v;
        __syncthreads();
        {
            unsigned long long o = sorted[t ^ 128];   // k2=256, j2=128
            bool km = ((t & 128) != 0);
            v = km ? (v > o ? v : o) : (v < o ? v : o);
        }
        __syncthreads();
        sorted[t] = v;
        __syncthreads();
        {
            unsigned long long o = sorted[t ^ 64];    // k2=256, j2=64 .. 1
            bool km = ((t & 64) != 0);
            v = km ? (v > o ? v : o) : (v < o ? v : o);
            v = bmerge_shfl(v, t, 256, 32);
        }
        __syncthreads();
        sorted[t] = v;
        __syncthreads();
    }

    // ---- phase 2: chunked greedy NMS on wave 0 (descending order) ----
    if (t < 64) {
        int lane = t;
        int outPos = 0;
        for (int chunk = 0; chunk < SSEL / 64 && outPos < TOPK; ++chunk) {
            unsigned long long key = sorted[SSEL - 1 - (chunk * 64 + lane)];
            unsigned int j = ~(unsigned int)key;
            float sc = unorderable((unsigned int)(key >> 32));
            float4 bj = bsrc[j];
            cbox[lane] = bj;
            float amine = (bj.z - bj.x) * (bj.w - bj.y);

            bool sup = false;
            for (int t2 = 0; t2 < outPos; ++t2) {
                float4 wb = abox[t2];
                float a1 = (wb.z - wb.x) * (wb.w - wb.y);
                float yy1 = fmaxf(wb.x, bj.x);
                float xx1 = fmaxf(wb.y, bj.y);
                float yy2 = fminf(wb.z, bj.z);
                float xx2 = fminf(wb.w, bj.w);
                float inter = fmaxf(yy2 - yy1, 0.f) * fmaxf(xx2 - xx1, 0.f);
                float denom = a1 + amine - inter + 1e-9f;
                sup = sup || ((double)inter > MID05 * (double)denom);
            }

            unsigned long long supmask = 0ull;
            #pragma unroll 8
            for (int j2 = 0; j2 < 64; ++j2) {
                float4 wb = cbox[j2];
                float a1 = (wb.z - wb.x) * (wb.w - wb.y);
                float yy1 = fmaxf(wb.x, bj.x);
                float xx1 = fmaxf(wb.y, bj.y);
                float yy2 = fminf(wb.z, bj.z);
                float xx2 = fminf(wb.w, bj.w);
                float inter = fmaxf(yy2 - yy1, 0.f) * fmaxf(xx2 - xx1, 0.f);
                float denom = a1 + amine - inter + 1e-9f;
                bool s2 = ((double)inter > MID05 * (double)denom);
                if (s2 && j2 < lane) supmask |= (1ull << j2);
            }

            unsigned long long cand = __ballot(!sup);
            unsigned long long accbits = 0ull;
            while (cand) {
                int i = __builtin_ctzll(cand);
                accbits |= (1ull << i);
                cand &= ~(1ull << i);
                unsigned long long row = __ballot((supmask >> i) & 1ull);
                cand &= ~row;
            }

            int nAcc = (int)__builtin_popcountll(accbits);
            int avail = TOPK - outPos;
            bool mine = (accbits >> lane) & 1ull;
            int myrank = (int)__builtin_popcountll(accbits & ((1ull << lane) - 1ull));
            if (mine && myrank < avail) {
                int pos = outPos + myrank;
                osc[pos] = sc;
                oid[pos] = (int)j;
                abox[pos] = bj;
            }
            outPos += (nAcc < avail) ? nAcc : avail;
            __builtin_amdgcn_s_waitcnt(0);
        }
        if (lane == 0) s_outPos = outPos;
    }
    __syncthreads();

    // ---- phase 3: fallback continuation (practically never taken) ----
    int outPos = s_outPos;
    if (outPos < TOPK) {
        if (t < SSEL) skey[~(unsigned int)sorted[t]] = 0u;
        __syncthreads();
        for (int j = t; j < NTOT; j += 256) {
            unsigned int u = skey[j];
            if (!u) continue;
            float4 bj = bsrc[j];
            float amine = (bj.z - bj.x) * (bj.w - bj.y);
            bool sup = false;
            for (int t2 = 0; t2 < outPos; ++t2) {
                float4 wb = abox[t2];
                float a1 = (wb.z - wb.x) * (wb.w - wb.y);
                float yy1 = fmaxf(wb.x, bj.x);
                float xx1 = fmaxf(wb.y, bj.y);
                float yy2 = fminf(wb.z, bj.z);
                float xx2 = fminf(wb.w, bj.w);
                float inter = fmaxf(yy2 - yy1, 0.f) * fmaxf(xx2 - xx1, 0.f);
                float denom = a1 + amine - inter + 1e-9f;
                sup = sup || ((double)inter > MID05 * (double)denom);
            }
            if (sup) skey[j] = 0u;
        }
        __syncthreads();
        while (outPos < TOPK) {
            if (t == 0) s_m = 0ull;
            __syncthreads();
            unsigned long long loc = 0ull;
            for (int j = t; j < NTOT; j += 256) {
                unsigned int u = skey[j];
                if (u) {
                    unsigned long long kk = ((unsigned long long)u << 32) | (unsigned int)~j;
                    loc = (kk > loc) ? kk : loc;
                }
            }
            atomicMax(&s_m, loc);
            __syncthreads();
            unsigned long long m = s_m;
            if ((long long)m >= 0) break;
            unsigned int wi = ~(unsigned int)m;
            float4 wb = bsrc[wi];
            if (t == 0) {
                osc[outPos] = unorderable((unsigned int)(m >> 32));
                oid[outPos] = (int)wi;
                skey[wi] = 0u;
            }
            __syncthreads();
            float a1 = (wb.z - wb.x) * (wb.w - wb.y);
            for (int j = t; j < NTOT; j += 256) {
                unsigned int u = skey[j];
                if (!u) continue;
                float4 bj = bsrc[j];
                float yy1 = fmaxf(wb.x, bj.x);
                float xx1 = fmaxf(wb.y, bj.y);
                float yy2 = fminf(wb.z, bj.z);
                float xx2 = fminf(wb.w, bj.w);
                float inter = fmaxf(yy2 - yy1, 0.f) * fmaxf(xx2 - xx1, 0.f);
                float a2 = (bj.z - bj.x) * (bj.w - bj.y);
                float denom = a1 + a2 - inter + 1e-9f;
                if ((double)inter > MID05 * (double)denom) skey[j] = 0u;
            }
            ++outPos;
            __syncthreads();
        }
    }

    for (int k2 = outPos + t; k2 < TOPK; k2 += 256) { osc[k2] = -INFINITY; oid[k2] = 0; }

    // ---- epilogue gate: last block of this batch runs final top-100 ----
    __syncthreads();              // drains this block's global writes (vmcnt 0)
    if (t == 0) {
        __threadfence();          // L2 writeback: release our batch's slice
        int old = atomicAdd(&cnt[b], 1);       // device-scope
        s_last = (old == NCLS - 1) ? 1 : 0;
        if (s_last) __threadfence();           // acquire: invalidate stale caches
    }
    __syncthreads();
    if (!s_last) return;

    // ---- final top-100 (exact round-11 final_topk, LDS reused) ----
    for (int f = t; f < 2000; f += 256) {
        float s = nms_score[(size_t)b * 2000 + f];
        float v = isfinite(s) ? s : -1.0f;
        skey[f] = orderable(v);
    }
    if (t == 0) { s_kk = TOPK; s_prefix = 0u; s_cnt = 0u; s_eqcnt = 0u; }
    if (t < 128) sorted[t] = 0ull;
    __syncthreads();

    for (int pass = 0; pass < 4; ++pass) {
        int shift = 24 - 8 * pass;
        unsigned int prefix = s_prefix, kk = s_kk;
        hist[t] = 0u;
        __syncthreads();
        for (int f = t; f < 2000; f += 256) {
            unsigned int u = skey[f];
            if (pass == 0 || (u >> (shift + 8)) == prefix)
                atomicAdd(&hist[(u >> shift) & 255u], 1u);
        }
        __syncthreads();
        radix_pass_scan(hist, &s_prefix, &s_kk, prefix, kk, t);
        __syncthreads();
    }

    unsigned int Tf = s_prefix;
    for (int f = t; f < 2000; f += 256) {
        unsigned int u = skey[f];
        if (u > Tf) {
            unsigned int pos = atomicAdd(&s_cnt, 1u);
            sorted[pos] = ((unsigned long long)u << 32) | (unsigned int)~f;
        } else if (u == Tf) {
            unsigned int p = atomicAdd(&s_eqcnt, 1u);
            if (p < 128u) eq[p] = f;
        }
    }
    __syncthreads();
    if (t == 0) {
        unsigned int pos = s_cnt;
        unsigned int rem = s_kk;
        unsigned int cnt2 = s_eqcnt;
        if (cnt2 <= 128u) {
            for (unsigned int i = 1; i < cnt2; ++i) {
                int key = eq[i]; int j2 = (int)i - 1;
                while (j2 >= 0 && eq[j2] > key) { eq[j2 + 1] = eq[j2]; --j2; }
                eq[j2 + 1] = key;
            }
            for (unsigned int i = 0; i < rem; ++i)
                sorted[pos + i] = ((unsigned long long)Tf << 32) | (unsigned int)~eq[i];
        } else {
            for (int f = 0; f < 2000 && rem > 0u; ++f)
                if (skey[f] == Tf) {
                    sorted[pos++] = ((unsigned long long)Tf << 32) | (unsigned int)~f;
                    --rem;
                }
        }
    }
    __syncthreads();

    {   // bitonic sort 128 u64 ascending, shfl-based (zeros sink)
        unsigned long long v = (t < 128) ? sorted[t] : 0ull;
        if (t < 128) {
            #pragma unroll
            for (int k2 = 2; k2 <= 64; k2 <<= 1)
                v = bmerge_shfl(v, t, k2, k2 >> 1);
            sorted[t] = v;
        }
        __syncthreads();
        if (t < 128) {
            unsigned long long o = sorted[t ^ 64];    // k2=128, j2=64
            bool km = ((t & 64) != 0);
            v = km ? (v > o ? v : o) : (v < o ? v : o);
            v = bmerge_shfl(v, t, 128, 32);
        }
        __syncthreads();
        if (t < 128) sorted[t] = v;
        __syncthreads();
    }

    if (t < TOPK) {
        unsigned long long kk = sorted[127 - t];       // t-th largest
        float v = unorderable((unsigned int)(kk >> 32));
        int fi = (int)~(unsigned int)kk;
        float* o = outbuf + ((size_t)b * TOPK + t) * 6;
        if (v > 0.3f) {
            int bidx = nms_idx[(size_t)b * 2000 + fi];
            float4 bxw = ((const float4*)boxes_all)[(size_t)b * NTOT + bidx];
            o[0] = bxw.x; o[1] = bxw.y; o[2] = bxw.z; o[3] = bxw.w;
            o[4] = v; o[5] = (float)(fi / TOPK);
        } else {
            o[0] = 0.f; o[1] = 0.f; o[2] = 0.f; o[3] = 0.f; o[4] = 0.f; o[5] = 0.f;
        }
    }
}

extern "C" void kernel_launch(void* const* d_in, const int* in_sizes, int n_in,
                              void* d_out, int out_size, void* d_ws, size_t ws_size,
                              hipStream_t stream) {
    (void)out_size; (void)ws_size;
    const float* cls[3] = {nullptr, nullptr, nullptr};
    const float* bbx[3] = {nullptr, nullptr, nullptr};
    for (int i = 0; i < n_in; ++i) {
        const float* p = (const float*)d_in[i];
        switch (in_sizes[i]) {
            case 16 * 6400 * 20: cls[0] = p; break;
            case 16 * 6400 * 32: bbx[0] = p; break;
            case 16 * 1600 * 20: cls[1] = p; break;
            case 16 * 1600 * 32: bbx[1] = p; break;
            case 16 *  400 * 20: cls[2] = p; break;
            case 16 *  400 * 32: bbx[2] = p; break;
            default: break;  // origin_shapes (unused by reference)
        }
    }

    char* w = (char*)d_ws;
    int*   sel_idx    = (int*)(w);                       // 128000 B used
    float* boxes_all  = (float*)(w + 131072);            // 614400 B
    float* scores_t   = (float*)(w + 745472);            // 3072000 B
    float* nms_score  = (float*)(w + 3817472);           // 128000 B
    int*   nms_idx    = (int*)(w + 3945472);             // 128000 B
    int*   cnt        = (int*)(w + 4073472);             // 64 B -> total 4073536 B

    hipLaunchKernelGGL(select_keys_kernel, dim3(32), dim3(1024), 0, stream,
                       cls[0], cls[1], sel_idx, cnt);
    hipLaunchKernelGGL(decode_kernel, dim3((BATCH * NTOT + 255) / 256), dim3(256), 0, stream,
                       cls[0], cls[1], cls[2], bbx[0], bbx[1], bbx[2],
                       sel_idx, boxes_all, scores_t);
    hipLaunchKernelGGL(class_nms_kernel, dim3(BATCH * NCLS), dim3(256), 0, stream,
                       boxes_all, scores_t, nms_score, nms_idx, cnt, (float*)d_out);
}